// Round 6
// baseline (585.105 us; speedup 1.0000x reference)
//
#include <hip/hip_runtime.h>
#include <hip/hip_bf16.h>
#include <math.h>

// MixedAttentionLayer — R14: occupancy push on k_path1 (latency-bound per
// R13: VALU cut gave no speedup). Arena 50688->38912 (4 blocks/CU, exact
// 2-round schedule): xsh eliminated (stage x into qpsb, af regs, +1 barrier);
// scap eliminated (exp kept in registers; den via 16-lane shfl reduce +
// denp[32][4] partials; normalize after barrier). k_tail: aVb aliases Tsh
// (dead after aft regs loaded, +1 barrier) -> 34048 B.

constexpr int DD = 256;
constexpr int MM = 50;
constexpr float SCL = 0.0625f; // 256^-0.5

// ---- byte offsets in d_ws ----
constexpr size_t B_VPH = 0;
constexpr size_t B_QLH = (size_t)32 << 20;
constexpr size_t B_KLH = (size_t)64 << 20;
constexpr size_t B_E   = (size_t)96 << 20;
constexpr size_t B_SM  = (size_t)112 << 20;
constexpr size_t B_X   = B_SM + ((size_t)2 << 20);

// ---- float offsets within SM region (zeroed part first) ----
constexpr size_t KLSUMR = 0;
constexpr size_t KLSUMP = 256;
constexpr size_t OCCDENP= 2304;
constexpr size_t W50P   = 2816;
constexpr size_t EDENP  = 3328;
constexpr size_t H2TP   = 3336;
constexpr size_t H2DENP = 5384;
constexpr size_t OCCRAW = 5392;
constexpr size_t ZEND   = 18192;
constexpr size_t QC     = ZEND;
constexpr size_t KC     = QC + 12800;
constexpr size_t VC     = KC + 12800;
constexpr size_t VCA    = VC + 12800;
constexpr size_t VCB    = VCA + 12800;
constexpr size_t WFA    = VCB + 12800;
constexpr size_t WFB    = WFA + 65536;
constexpr size_t BFA    = WFB + 65536;
constexpr size_t BFB    = BFA + 256;
constexpr size_t OSCB   = BFB + 256;
constexpr size_t OCCB   = OSCB + 12800;
constexpr size_t ASC    = OCCB + 12800;
constexpr size_t ACC50  = ASC + 64;
constexpr size_t SMEND  = ACC50 + 64;

// ---- short offsets within X region (all fragment-major) ----
constexpr size_t XT_WQKV = 0;          // 48t x 8k0 x 64 x 8 = 196608
constexpr size_t XT_WFAT = 196608;     // 16 x 8 x 64 x 8 = 65536
constexpr size_t XT_WFBT = 262144;
constexpr size_t XT_KVT  = 327680;     // 16 x 8 x 64 x 8
constexpr size_t XT_QCH  = 393216;     // 4 x 8 x 64 x 8 = 16384
constexpr size_t XT_KCH  = 409600;
constexpr size_t XT_VCAT = 425984;     // 16 x 2 x 64 x 8 = 16384
constexpr size_t XT_VCBT = 442368;
constexpr size_t XT_END  = 458752;
constexpr size_t WS_NEEDED = B_X + XT_END * 2;

typedef short bf16x8 __attribute__((ext_vector_type(8)));
typedef float f32x4 __attribute__((ext_vector_type(4)));

__device__ __forceinline__ float rcpf_(float x){ return __builtin_amdgcn_rcpf(x); }
__device__ __forceinline__ float fsig_(float x){ return rcpf_(1.0f + __expf(-x)); }
__device__ __forceinline__ float ftanh_(float x){ return 1.0f - 2.0f * rcpf_(__expf(2.0f * x) + 1.0f); }

__device__ __forceinline__ float bf2f(unsigned short u){
  return __uint_as_float(((unsigned int)u) << 16);
}
__device__ __forceinline__ unsigned short f2bf(float f){
  union { __hip_bfloat16 h; unsigned short u; } c;
  c.h = __float2bfloat16(f);
  return c.u;
}
__device__ __forceinline__ f32x4 mfma16(bf16x8 a, bf16x8 b, f32x4 c){
  return __builtin_amdgcn_mfma_f32_16x16x32_bf16(a, b, c, 0, 0, 0);
}

__device__ __forceinline__ float waveAllSum(float v){
  #pragma unroll
  for (int m = 1; m < 64; m <<= 1) v += __shfl_xor(v, m, 64);
  return v;
}

// fragment-major index helper
__device__ __forceinline__ size_t fragIdx(int n, int k, int K8){
  const int tile = n >> 4, cn = n & 15;
  const int k0 = k >> 5, kqi = (k >> 3) & 3, e = k & 7;
  return (((size_t)tile * K8 + k0) * 64 + (kqi * 16 + cn)) * 8 + e;
}

// ---------- prep0: fragment-major Wqkv^T (blocks 0..47) + qc/kc/vc (48..97) ----------
__global__ void __launch_bounds__(256) k_prep0(const float* __restrict__ x, const float* __restrict__ Wqkv,
                                               float* qc, float* kc, float* vc,
                                               unsigned short* qch, unsigned short* kch,
                                               unsigned short* __restrict__ WT){
  const int b = blockIdx.x, t = threadIdx.x;
  if (b < 48) {
    __shared__ unsigned short Tt[64][72];
    const int bn = b % 12, bk = b / 12;
    const int n0 = bn * 64, k0g = bk * 64;
    #pragma unroll
    for (int i = 0; i < 16; i++) {
      const int k_l = (t >> 6) + i * 4;
      const int n_l = t & 63;
      Tt[n_l][k_l] = f2bf(Wqkv[(size_t)(k0g + k_l) * 768 + n0 + n_l]);
    }
    __syncthreads();
    #pragma unroll
    for (int i = 0; i < 2; i++) {
      const int fr = t * 2 + i;
      const int t_l = fr >> 7;
      const int k0_l = (fr >> 6) & 1;
      const int lane_f = fr & 63;
      const int n_l = t_l * 16 + (lane_f & 15);
      const int k_l = k0_l * 32 + (lane_f >> 4) * 8;
      const int tg = (n0 >> 4) + t_l;
      const int k0gl = (k0g >> 5) + k0_l;
      bf16x8 v = *(const bf16x8*)&Tt[n_l][k_l];
      *(bf16x8*)&WT[(((size_t)tg * 8 + k0gl) * 64 + lane_f) * 8] = v;
    }
    return;
  }
  __shared__ float xs[256];
  const int r = b - 48, j = t;
  xs[j] = x[r * DD + j];
  __syncthreads();
  float aq = 0.f, ak = 0.f, av = 0.f;
  for (int k = 0; k < DD; k++) {
    float xv = xs[k];
    aq += xv * Wqkv[k * 768 + j];
    ak += xv * Wqkv[k * 768 + 256 + j];
    av += xv * Wqkv[k * 768 + 512 + j];
  }
  qc[r * DD + j] = aq; kc[r * DD + j] = ak; vc[r * DD + j] = av;
  qch[fragIdx(r, j, 8)] = f2bf(aq);
  kch[fragIdx(r, j, 8)] = f2bf(ak);
  if (r == 0) {
    for (int c = 50; c < 64; c++) {
      qch[fragIdx(c, j, 8)] = 0;
      kch[fragIdx(c, j, 8)] = 0;
    }
  }
}

// ---------- prep1: Vca/Vcb (0..49) + Wfa/Wfb/bfa/bfb (50..563), fragment-major bf16 ----------
__global__ void __launch_bounds__(256) k_prep1(const float* vc, const float* Wa, const float* Wb,
                                               const float* ba, const float* bb,
                                               const float* Wf, const float* bf,
                                               float* Vca, float* Vcb,
                                               unsigned short* VcaTh, unsigned short* VcbTh,
                                               float* Wfa, float* Wfb, float* bfa, float* bfb,
                                               unsigned short* WfaTh, unsigned short* WfbTh){
  __shared__ float rs[256];
  const int b = blockIdx.x, j = threadIdx.x;
  if (b < 50) {
    const int r = b;
    rs[j] = vc[r * DD + j];
    __syncthreads();
    float a = 0.f, bv = 0.f;
    for (int k = 0; k < DD; k++) { float v = rs[k]; a += v * Wa[k * DD + j]; bv += v * Wb[k * DD + j]; }
    Vca[r * DD + j] = a; Vcb[r * DD + j] = bv;
    VcaTh[fragIdx(j, r, 2)] = f2bf(a);
    VcbTh[fragIdx(j, r, 2)] = f2bf(bv);
    if (r == 0) {
      for (int c = 50; c < 64; c++) {
        VcaTh[fragIdx(j, c, 2)] = 0;
        VcbTh[fragIdx(j, c, 2)] = 0;
      }
    }
    return;
  }
  const int bb2 = b - 50;
  const float* src; const float* Wm;
  if (bb2 < 256)      { src = Wf + bb2 * DD;         Wm = Wa; }
  else if (bb2 < 512) { src = Wf + (bb2 - 256) * DD; Wm = Wb; }
  else if (bb2 == 512){ src = bf;                    Wm = Wa; }
  else                { src = bf;                    Wm = Wb; }
  rs[j] = src[j];
  __syncthreads();
  float a = 0.f;
  for (int k = 0; k < DD; k++) a += rs[k] * Wm[k * DD + j];
  if (bb2 < 256)      { Wfa[bb2 * DD + j] = a; WfaTh[fragIdx(j, bb2, 8)] = f2bf(a); }
  else if (bb2 < 512) { Wfb[(bb2 - 256) * DD + j] = a; WfbTh[fragIdx(j, bb2 - 256, 8)] = f2bf(a); }
  else if (bb2 == 512) bfa[j] = a + ba[j];
  else bfb[j] = a + bb[j];
}

// ---------- fused: osc row + gated(osc row) -> A_sc ----------
__global__ void __launch_bounds__(256) k_oscg(const float* __restrict__ qc, const float* __restrict__ kc,
                                              const float* __restrict__ vc,
                                              const float* __restrict__ Wa, const float* __restrict__ Wb,
                                              const float* __restrict__ ba, const float* __restrict__ bb,
                                              const float* __restrict__ Wc, const float* __restrict__ bc,
                                              float* __restrict__ osc, float* __restrict__ A){
  const int i = blockIdx.x, t = threadIdx.x;
  __shared__ float qs[256];
  __shared__ float P[64];
  __shared__ float red[4];
  qs[t] = qc[i * DD + t];
  __syncthreads();
  if (t < 64) {
    float s = -1e30f;
    if (t < 50) {
      float acc = 0.f;
      const float4* kr = (const float4*)&kc[t * DD];
      #pragma unroll 8
      for (int k = 0; k < 64; k++) {
        float4 kv = kr[k];
        float4 qv = *(const float4*)&qs[k * 4];
        acc += qv.x * kv.x + qv.y * kv.y + qv.z * kv.z + qv.w * kv.w;
      }
      s = acc * SCL;
    }
    float mx = s;
    #pragma unroll
    for (int m = 1; m < 64; m <<= 1) mx = fmaxf(mx, __shfl_xor(mx, m, 64));
    float e = (t < 50) ? __expf(s - mx) : 0.f;
    float den = waveAllSum(e);
    P[t] = e * rcpf_(den);
  }
  __syncthreads();
  float a = 0.f;
  for (int jj = 0; jj < 50; jj++) a += P[jj] * vc[jj * DD + t];
  osc[i * DD + t] = a;
  __syncthreads();
  qs[t] = a;
  __syncthreads();
  float u = 0.f, v = 0.f;
  for (int k = 0; k < DD; k++) { float tv = qs[k]; u += tv * Wa[k * DD + t]; v += tv * Wb[k * DD + t]; }
  float g = ftanh_(u + ba[t]) * fsig_(v + bb[t]) * Wc[t];
  g = waveAllSum(g);
  const int lane = t & 63, wv = t >> 6;
  if (lane == 0) red[wv] = g;
  __syncthreads();
  if (t == 0) A[i] = red[0] + red[1] + red[2] + red[3] + bc[0];
}

// ---------- gated() on 50 rows ----------
__global__ void __launch_bounds__(256) k_gated(const float* __restrict__ tin,
                                               const float* __restrict__ Wa, const float* __restrict__ Wb,
                                               const float* __restrict__ ba, const float* __restrict__ bb,
                                               const float* __restrict__ Wc, const float* __restrict__ bc,
                                               float* __restrict__ A){
  int r = blockIdx.x, j = threadIdx.x;
  __shared__ float ts[256];
  __shared__ float red[4];
  ts[j] = tin[r * DD + j];
  __syncthreads();
  float u = 0.f, v = 0.f;
  for (int k = 0; k < DD; k++) { float tv = ts[k]; u += tv * Wa[k * DD + j]; v += tv * Wb[k * DD + j]; }
  float g = ftanh_(u + ba[j]) * fsig_(v + bb[j]) * Wc[j];
  g = waveAllSum(g);
  int lane = j & 63, wv = j >> 6;
  if (lane == 0) red[wv] = g;
  __syncthreads();
  if (j == 0) A[r] = red[0] + red[1] + red[2] + red[3] + bc[0];
}

// ---------- fused path kernel: 32 rows/block, 38912 B arena (4 blocks/CU) ----------
// Arena: Psh ushort[32][72] @0 (4608; exp(g) floats in cols 64-65)
//        denp float[32][4]  @4608 (512)
//        qpsb ushort[32][264] @5120  (staging ground for x, then q outputs)
//        kpsb ushort[32][264] @22016
__global__ void __launch_bounds__(256) k_path1(
    const float* __restrict__ x, const unsigned short* __restrict__ WTf,
    const float* __restrict__ sln,
    const unsigned short* __restrict__ kchf, const unsigned short* __restrict__ qchf,
    const unsigned short* __restrict__ VcaTf, const unsigned short* __restrict__ VcbTf,
    const float* __restrict__ ba, const float* __restrict__ bb,
    const float* __restrict__ Wc, const float* __restrict__ bc,
    unsigned short* __restrict__ vph, unsigned short* __restrict__ qlh, unsigned short* __restrict__ klh,
    float* __restrict__ E, float* __restrict__ w50p, float* __restrict__ edenp, float* __restrict__ occdenp){
  __shared__ __align__(16) char arena[38912];
  unsigned short (*Psh)[72]   = (unsigned short (*)[72])arena;
  float (*denp)[4]            = (float (*)[4])(arena + 4608);
  unsigned short (*qpsb)[264] = (unsigned short (*)[264])(arena + 5120);
  unsigned short (*kpsb)[264] = (unsigned short (*)[264])(arena + 22016);

  const int tid = threadIdx.x;
  const int i0 = blockIdx.x * 32;
  const int part = blockIdx.x & 7;
  const int lane = tid & 63;
  const int wvv = tid >> 6;
  const int cn = lane & 15;
  const int m0 = (lane >> 4) * 4;
  const int kq = (lane >> 4) * 8;

  // stage x (bf16) into qpsb (acts as xsh; overwritten by GEMM after B2)
  for (int l = tid; l < 2048; l += 256) {
    const int r = l >> 6, c4 = (l & 63) * 4;
    const float4 xv = *(const float4*)&x[(size_t)(MM + i0 + r) * DD + c4];
    ushort4 o; o.x = f2bf(xv.x); o.y = f2bf(xv.y); o.z = f2bf(xv.z); o.w = f2bf(xv.w);
    *(ushort4*)&qpsb[r][c4] = o;
  }
  __syncthreads();

  // A fragments into registers; then free qpsb for GEMM output
  bf16x8 af0[8], af1[8];
  #pragma unroll
  for (int k0 = 0; k0 < 8; k0++) {
    af0[k0] = *(const bf16x8*)&qpsb[cn][k0 * 32 + kq];
    af1[k0] = *(const bf16x8*)&qpsb[16 + cn][k0 * 32 + kq];
  }
  __syncthreads();

  // ---- GEMM: [32 x 256] @ [256 x 768]; each B fragment feeds 2 MFMAs ----
  bf16x8 b0[8], b1[8];
  {
    const unsigned short* Bt = WTf + ((size_t)wvv * 8 * 64 + lane) * 8;
    #pragma unroll
    for (int k0 = 0; k0 < 8; k0++) b0[k0] = *(const bf16x8*)&Bt[(size_t)k0 * 512];
  }
  #pragma unroll 1
  for (int tt = 0; tt < 12; tt++) {
    const int t = wvv + 4 * tt;
    if (tt + 1 < 12) {
      const unsigned short* Bt = WTf + (((size_t)(t + 4) * 8) * 64 + lane) * 8;
      #pragma unroll
      for (int k0 = 0; k0 < 8; k0++) b1[k0] = *(const bf16x8*)&Bt[(size_t)k0 * 512];
    }
    f32x4 acc0 = {0.f, 0.f, 0.f, 0.f};
    f32x4 acc1 = {0.f, 0.f, 0.f, 0.f};
    #pragma unroll
    for (int k0 = 0; k0 < 8; k0++) {
      acc0 = mfma16(af0[k0], b0[k0], acc0);
      acc1 = mfma16(af1[k0], b0[k0], acc1);
    }
    if (t < 16) {
      int c = t * 16 + cn;
      #pragma unroll
      for (int i = 0; i < 4; i++) {
        qpsb[m0 + i][c] = f2bf(acc0[i]);
        qpsb[16 + m0 + i][c] = f2bf(acc1[i]);
      }
    } else if (t < 32) {
      int c = (t - 16) * 16 + cn;
      #pragma unroll
      for (int i = 0; i < 4; i++) {
        kpsb[m0 + i][c] = f2bf(acc0[i]);
        kpsb[16 + m0 + i][c] = f2bf(acc1[i]);
      }
    } else {
      int c = (t - 32) * 16 + cn;
      #pragma unroll
      for (int i = 0; i < 4; i++) {
        vph[(size_t)(i0 + m0 + i) * DD + c] = f2bf(acc0[i]);
        vph[(size_t)(i0 + 16 + m0 + i) * DD + c] = f2bf(acc1[i]);
      }
    }
    #pragma unroll
    for (int k0 = 0; k0 < 8; k0++) b0[k0] = b1[k0];
  }
  __syncthreads();

  // ---- scores via MFMA; exp kept in regs; den partials via 16-lane reduce ----
  float ep0[4], ep1[4];
  {
    f32x4 accp0 = {0.f,0.f,0.f,0.f}, accp1 = {0.f,0.f,0.f,0.f};
    f32x4 accc0 = {0.f,0.f,0.f,0.f}, accc1 = {0.f,0.f,0.f,0.f};
    const unsigned short* Bk = kchf + ((size_t)wvv * 8 * 64 + lane) * 8;
    const unsigned short* Bq = qchf + ((size_t)wvv * 8 * 64 + lane) * 8;
    #pragma unroll
    for (int k0 = 0; k0 < 8; k0++) {
      bf16x8 aq0 = *(const bf16x8*)&qpsb[cn][k0 * 32 + kq];
      bf16x8 aq1 = *(const bf16x8*)&qpsb[16 + cn][k0 * 32 + kq];
      bf16x8 ak0 = *(const bf16x8*)&kpsb[cn][k0 * 32 + kq];
      bf16x8 ak1 = *(const bf16x8*)&kpsb[16 + cn][k0 * 32 + kq];
      bf16x8 bk = *(const bf16x8*)&Bk[(size_t)k0 * 512];
      bf16x8 bq = *(const bf16x8*)&Bq[(size_t)k0 * 512];
      accp0 = mfma16(aq0, bk, accp0);
      accp1 = mfma16(aq1, bk, accp1);
      accc0 = mfma16(ak0, bq, accc0);
      accc1 = mfma16(ak1, bq, accc1);
    }
    const int col = wvv * 16 + cn;
    const bool ok = (col < 50);
    #pragma unroll
    for (int i = 0; i < 4; i++) {
      ep0[i] = ok ? __expf(accp0[i] * SCL) : 0.f;
      ep1[i] = ok ? __expf(accp1[i] * SCL) : 0.f;
    }
    float osum = 0.f;
    #pragma unroll
    for (int i = 0; i < 4; i++) {
      float ec0 = __expf(accc0[i] * SCL);
      float ec1 = __expf(accc1[i] * SCL);
      E[(size_t)(i0 + m0 + i) * 64 + col] = ok ? ec0 : 0.f;
      E[(size_t)(i0 + 16 + m0 + i) * 64 + col] = ok ? ec1 : 0.f;
      if (ok) osum += ec0 + ec1;
    }
    osum += __shfl_xor(osum, 16, 64);
    osum += __shfl_xor(osum, 32, 64);
    if (lane < 16 && ok) atomicAdd(&occdenp[part * 64 + col], osum);
    // den partials: sum ep over the 16 cn lanes (low 4 bits of lane)
    float d0[4], d1[4];
    #pragma unroll
    for (int i = 0; i < 4; i++) { d0[i] = ep0[i]; d1[i] = ep1[i]; }
    #pragma unroll
    for (int m = 1; m < 16; m <<= 1) {
      #pragma unroll
      for (int i = 0; i < 4; i++) {
        d0[i] += __shfl_xor(d0[i], m, 64);
        d1[i] += __shfl_xor(d1[i], m, 64);
      }
    }
    if (cn == 0) {
      #pragma unroll
      for (int i = 0; i < 4; i++) {
        denp[m0 + i][wvv] = d0[i];
        denp[16 + m0 + i][wvv] = d1[i];
      }
    }
  }
  __syncthreads();

  // ---- normalize P from regs -> Psh (fragment-ready layout) ----
  {
    const int col = wvv * 16 + cn;
    #pragma unroll
    for (int i = 0; i < 4; i++) {
      float4 dp = *(const float4*)&denp[m0 + i][0];
      Psh[m0 + i][col] = f2bf(ep0[i] * rcpf_(dp.x + dp.y + dp.z + dp.w));
      float4 dq = *(const float4*)&denp[16 + m0 + i][0];
      Psh[16 + m0 + i][col] = f2bf(ep1[i] * rcpf_(dq.x + dq.y + dq.z + dq.w));
    }
  }

  // ---- phase B: transforms (8 rows per wave) ----
  float4 sl4 = ((const float4*)sln)[lane];
  float4 rsp;
  rsp.x = rcpf_(log1pf(expf(sl4.x))); rsp.y = rcpf_(log1pf(expf(sl4.y)));
  rsp.z = rcpf_(log1pf(expf(sl4.z))); rsp.w = rcpf_(log1pf(expf(sl4.w)));
  float4 ba4 = ((const float4*)ba)[lane];
  float4 bb4 = ((const float4*)bb)[lane];
  float4 wc4 = ((const float4*)Wc)[lane];
  float bcv = bc[0];
  for (int rr = 0; rr < 8; rr++) {
    const int r = wvv * 8 + rr;
    const int row = i0 + r;
    ushort4 qu = *(const ushort4*)&qpsb[r][lane * 4];
    ushort4 ku = *(const ushort4*)&kpsb[r][lane * 4];
    float4 q4 = {bf2f(qu.x), bf2f(qu.y), bf2f(qu.z), bf2f(qu.w)};
    float4 k4 = {bf2f(ku.x), bf2f(ku.y), bf2f(ku.z), bf2f(ku.w)};
    float4 lq, lk;
    lq.x = (fmaxf(q4.x, 0.f) + 1e-6f) * rsp.x; lq.y = (fmaxf(q4.y, 0.f) + 1e-6f) * rsp.y;
    lq.z = (fmaxf(q4.z, 0.f) + 1e-6f) * rsp.z; lq.w = (fmaxf(q4.w, 0.f) + 1e-6f) * rsp.w;
    lk.x = (fmaxf(k4.x, 0.f) + 1e-6f) * rsp.x; lk.y = (fmaxf(k4.y, 0.f) + 1e-6f) * rsp.y;
    lk.z = (fmaxf(k4.z, 0.f) + 1e-6f) * rsp.z; lk.w = (fmaxf(k4.w, 0.f) + 1e-6f) * rsp.w;
    float4 q3, k3;
    q3.x = lq.x*lq.x*lq.x; q3.y = lq.y*lq.y*lq.y; q3.z = lq.z*lq.z*lq.z; q3.w = lq.w*lq.w*lq.w;
    k3.x = lk.x*lk.x*lk.x; k3.y = lk.y*lk.y*lk.y; k3.z = lk.z*lk.z*lk.z; k3.w = lk.w*lk.w*lk.w;
    float n1q = lq.x*lq.x + lq.y*lq.y + lq.z*lq.z + lq.w*lq.w;
    float n3q = q3.x*q3.x + q3.y*q3.y + q3.z*q3.z + q3.w*q3.w;
    float n1k = lk.x*lk.x + lk.y*lk.y + lk.z*lk.z + lk.w*lk.w;
    float n3k = k3.x*k3.x + k3.y*k3.y + k3.z*k3.z + k3.w*k3.w;
    n1q = waveAllSum(n1q); n3q = waveAllSum(n3q);
    n1k = waveAllSum(n1k); n3k = waveAllSum(n3k);
    float fq = sqrtf(n1q * rcpf_(n3q));
    float fk = sqrtf(n1k * rcpf_(n3k));
    ushort4 qo, ko;
    qo.x = f2bf(q3.x * fq); qo.y = f2bf(q3.y * fq); qo.z = f2bf(q3.z * fq); qo.w = f2bf(q3.w * fq);
    ko.x = f2bf(k3.x * fk); ko.y = f2bf(k3.y * fk); ko.z = f2bf(k3.z * fk); ko.w = f2bf(k3.w * fk);
    *(ushort4*)&qlh[(size_t)row * DD + lane * 4] = qo;
    *(ushort4*)&klh[(size_t)row * DD + lane * 4] = ko;
  }
  __syncthreads();

  // ---- gate via MFMA: u = P@Vca, v = P@Vcb (fragment-major B, K8=2) ----
  {
    bf16x8 ap0[2], ap1[2];
    #pragma unroll
    for (int k0 = 0; k0 < 2; k0++) {
      ap0[k0] = *(const bf16x8*)&Psh[cn][k0 * 32 + kq];
      ap1[k0] = *(const bf16x8*)&Psh[16 + cn][k0 * 32 + kq];
    }
    #pragma unroll 1
    for (int tt = 0; tt < 4; tt++) {
      const int nt = wvv * 4 + tt;
      const unsigned short* Bu = VcaTf + (((size_t)nt * 2) * 64 + lane) * 8;
      const unsigned short* Bv = VcbTf + (((size_t)nt * 2) * 64 + lane) * 8;
      f32x4 au0 = {0.f,0.f,0.f,0.f}, au1 = {0.f,0.f,0.f,0.f};
      f32x4 av0 = {0.f,0.f,0.f,0.f}, av1 = {0.f,0.f,0.f,0.f};
      #pragma unroll
      for (int k0 = 0; k0 < 2; k0++) {
        bf16x8 bu = *(const bf16x8*)&Bu[(size_t)k0 * 512];
        bf16x8 bv = *(const bf16x8*)&Bv[(size_t)k0 * 512];
        au0 = mfma16(ap0[k0], bu, au0);
        au1 = mfma16(ap1[k0], bu, au1);
        av0 = mfma16(ap0[k0], bv, av0);
        av1 = mfma16(ap1[k0], bv, av1);
      }
      #pragma unroll
      for (int i = 0; i < 4; i++) {
        qpsb[m0 + i][nt * 16 + cn] = f2bf(au0[i]);
        qpsb[16 + m0 + i][nt * 16 + cn] = f2bf(au1[i]);
        kpsb[m0 + i][nt * 16 + cn] = f2bf(av0[i]);
        kpsb[16 + m0 + i][nt * 16 + cn] = f2bf(av1[i]);
      }
    }
  }
  __syncthreads();

  // ---- gate eval; exp(g) stored in Psh row padding ----
  {
    float4 ba4b = ba4, bb4b = bb4, wc4b = wc4;
    #pragma unroll
    for (int rr = 0; rr < 8; rr++) {
      const int r = wvv * 8 + rr;
      ushort4 uu = *(const ushort4*)&qpsb[r][lane * 4];
      ushort4 vv = *(const ushort4*)&kpsb[r][lane * 4];
      float g = ftanh_(bf2f(uu.x) + ba4b.x) * fsig_(bf2f(vv.x) + bb4b.x) * wc4b.x
              + ftanh_(bf2f(uu.y) + ba4b.y) * fsig_(bf2f(vv.y) + bb4b.y) * wc4b.y
              + ftanh_(bf2f(uu.z) + ba4b.z) * fsig_(bf2f(vv.z) + bb4b.z) * wc4b.z
              + ftanh_(bf2f(uu.w) + ba4b.w) * fsig_(bf2f(vv.w) + bb4b.w) * wc4b.w;
      g = waveAllSum(g);
      if (lane == 0) *(float*)&Psh[r][64] = __expf(g + bcv);
    }
  }
  __syncthreads();
  if (tid < 64) {
    float s = 0.f;
    #pragma unroll
    for (int r = 0; r < 32; r++) s += *(const float*)&Psh[r][64] * bf2f(Psh[r][tid]);
    atomicAdd(&w50p[part * 64 + tid], s);
  }
  if (tid == 0) {
    float es = 0.f;
    #pragma unroll
    for (int r = 0; r < 32; r++) es += *(const float*)&Psh[r][64];
    atomicAdd(&edenp[part], es);
  }
}

// ---------- occ numerator: 512 threads, two j-halves per block ----------
__global__ void __launch_bounds__(512) k_occnum(const float* __restrict__ E, const unsigned short* __restrict__ vph,
                                                float* __restrict__ occraw){
  const int d = threadIdx.x & 255;
  const int half = threadIdx.x >> 8;
  const int j0 = blockIdx.x * 256;
  __shared__ float Es[2][32][64];
  float acc[52];
  #pragma unroll
  for (int i = 0; i < 52; i++) acc[i] = 0.f;
  for (int s = 0; s < 4; s++) {
    const int sj = j0 + (half * 4 + s) * 32;
    for (int l = d; l < 512; l += 256) {
      int jj = l >> 4, cq = l & 15;
      *(float4*)&Es[half][jj][cq * 4] = ((const float4*)(E + (size_t)(sj + jj) * 64))[cq];
    }
    __syncthreads();
    for (int jj = 0; jj < 32; jj++) {
      float vv = bf2f(vph[(size_t)(sj + jj) * DD + d]);
      #pragma unroll
      for (int q = 0; q < 13; q++) {
        float4 e4 = *(const float4*)&Es[half][jj][q * 4];
        acc[q * 4 + 0] += e4.x * vv; acc[q * 4 + 1] += e4.y * vv;
        acc[q * 4 + 2] += e4.z * vv; acc[q * 4 + 3] += e4.w * vv;
      }
    }
    __syncthreads();
  }
  for (int i = 0; i < 50; i++) atomicAdd(&occraw[i * DD + d], acc[i]);
}

// ---------- kv = kl^T @ vp: LDS-staged MFMA, 4 c-bands x 128 z-chunks ----------
__global__ void __launch_bounds__(256) k_kv(const unsigned short* __restrict__ klh,
                                            const unsigned short* __restrict__ vph,
                                            unsigned short* __restrict__ PP,
                                            float* __restrict__ klsump){
  __shared__ unsigned short Akl[32][72];
  __shared__ unsigned short Bvp[32][264];
  const int tid = threadIdx.x;
  const int lane = tid & 63;
  const int wvv = tid >> 6;
  const int cn = lane & 15;
  const int m0 = (lane >> 4) * 4;
  const int kq = (lane >> 4) * 8;
  const int cb = blockIdx.x;
  const int z  = blockIdx.y;
  const int jj = tid >> 3;
  const int c8 = (tid & 7) * 8;

  f32x4 acc[4][4];
  f32x4 acc1[4];
  #pragma unroll
  for (int mt = 0; mt < 4; mt++) {
    acc1[mt] = (f32x4){0.f,0.f,0.f,0.f};
    #pragma unroll
    for (int tl = 0; tl < 4; tl++) acc[mt][tl] = (f32x4){0.f,0.f,0.f,0.f};
  }
  bf16x8 ones;
  #pragma unroll
  for (int i = 0; i < 8; i++) ones[i] = (short)0x3F80;

  const int jbase = z * 512;
  #pragma unroll 1
  for (int step = 0; step < 16; step++) {
    const int j0 = jbase + step * 32;
    {
      bf16x8 av = *(const bf16x8*)&klh[(size_t)(j0 + jj) * 256 + cb * 64 + c8];
      *(bf16x8*)&Akl[jj][c8] = av;
      #pragma unroll
      for (int rep = 0; rep < 4; rep++) {
        bf16x8 bv = *(const bf16x8*)&vph[(size_t)(j0 + jj) * 256 + rep * 64 + c8];
        *(bf16x8*)&Bvp[jj][rep * 64 + c8] = bv;
      }
    }
    __syncthreads();
    bf16x8 afr[4], bfr[4];
    #pragma unroll
    for (int mt = 0; mt < 4; mt++) {
      #pragma unroll
      for (int e = 0; e < 8; e++) afr[mt][e] = (short)Akl[kq + e][cn + mt * 16];
    }
    #pragma unroll
    for (int tl = 0; tl < 4; tl++) {
      #pragma unroll
      for (int e = 0; e < 8; e++) bfr[tl][e] = (short)Bvp[kq + e][wvv * 64 + tl * 16 + cn];
    }
    #pragma unroll
    for (int mt = 0; mt < 4; mt++) {
      acc1[mt] = mfma16(afr[mt], ones, acc1[mt]);
      #pragma unroll
      for (int tl = 0; tl < 4; tl++) acc[mt][tl] = mfma16(afr[mt], bfr[tl], acc[mt][tl]);
    }
    __syncthreads();
  }
  unsigned short* P = PP + ((size_t)(cb * 128 + z)) * 16384;
  #pragma unroll
  for (int mt = 0; mt < 4; mt++)
    #pragma unroll
    for (int tl = 0; tl < 4; tl++) {
      const int n = (wvv * 4 + tl) * 16 + cn;
      #pragma unroll
      for (int i = 0; i < 4; i++)
        P[(size_t)(mt * 16 + m0 + i) * 256 + n] = f2bf(acc[mt][tl][i]);
    }
  if (wvv == 0 && cn == 0) {
    #pragma unroll
    for (int mt = 0; mt < 4; mt++)
      #pragma unroll
      for (int i = 0; i < 4; i++)
        atomicAdd(&klsump[(z & 7) * 256 + cb * 64 + mt * 16 + m0 + i], acc1[mt][i]);
  }
}

// ---------- merged: kvred (0..255) + occfin (256..305) + klsum reduce (306) ----------
__global__ void __launch_bounds__(256) k_fin2(const unsigned short* __restrict__ PP,
                                              unsigned short* __restrict__ kvTf,
                                              const float* __restrict__ occraw,
                                              const float* __restrict__ occdenp,
                                              float* __restrict__ occ,
                                              const float* __restrict__ klsump,
                                              float* __restrict__ klsum){
  const int b = blockIdx.x, d = threadIdx.x;
  if (b < 256) {
    const int cb = b >> 6, m = b & 63;
    float s = 0.f;
    for (int z = 0; z < 128; z++)
      s += bf2f(PP[((size_t)(cb * 128 + z)) * 16384 + (size_t)m * 256 + d]);
    kvTf[fragIdx(d, b, 8)] = f2bf(s);
  } else if (b < 306) {
    const int i = b - 256;
    float den = 0.f;
    #pragma unroll
    for (int p = 0; p < 8; p++) den += occdenp[p * 64 + i];
    occ[i * DD + d] = occraw[i * DD + d] / den;
  } else {
    float s = 0.f;
    #pragma unroll
    for (int p = 0; p < 8; p++) s += klsump[p * 256 + d];
    klsum[d] = s;
  }
}

// ---------- fused tail: 32 rows/block, aVb aliases Tsh (34048 B) ----------
__global__ void __launch_bounds__(256) k_tail(const unsigned short* __restrict__ qlh,
                                              const unsigned short* __restrict__ kvTf,
                                              const float* __restrict__ klsum,
                                              const unsigned short* __restrict__ vph,
                                              const float* __restrict__ dwcw, const float* __restrict__ dwcb,
                                              const unsigned short* __restrict__ WfaTf,
                                              const unsigned short* __restrict__ WfbTf,
                                              const float* __restrict__ bfa, const float* __restrict__ bfb,
                                              const float* __restrict__ Wc, const float* __restrict__ bc,
                                              float* __restrict__ h2tp, float* __restrict__ h2denp){
  __shared__ __align__(16) char tarena[34048];
  unsigned short (*Tsh)[264] = (unsigned short (*)[264])tarena;
  unsigned short (*OSb)[264] = (unsigned short (*)[264])(tarena + 16896);
  unsigned short (*aVb)[264] = Tsh;   // alias: Tsh dead once aft regs loaded
  float* zf = (float*)(tarena + 33792);
  float* ev = (float*)(tarena + 33920);
  const int tid = threadIdx.x;
  const int i0 = blockIdx.x * 32;
  const int part = blockIdx.x & 7;
  const int lane = tid & 63;
  const int wvv = tid >> 6;
  const int cn = lane & 15;
  const int m0 = (lane >> 4) * 4;
  const int kq = (lane >> 4) * 8;
  for (int l = tid; l < 2048; l += 256) {
    int r = l >> 6, c4 = (l & 63) * 4;
    *(ushort4*)&Tsh[r][c4] = *(const ushort4*)&qlh[(size_t)(i0 + r) * DD + c4];
  }
  __syncthreads();
  // ---- OS = ql @ kv (each B fragment feeds 2 MFMAs) ----
  {
    bf16x8 afq0[8], afq1[8];
    #pragma unroll
    for (int k0 = 0; k0 < 8; k0++) {
      afq0[k0] = *(const bf16x8*)&Tsh[cn][k0 * 32 + kq];
      afq1[k0] = *(const bf16x8*)&Tsh[16 + cn][k0 * 32 + kq];
    }
    #pragma unroll 1
    for (int tt = 0; tt < 4; tt++) {
      const int nt = wvv * 4 + tt;
      const unsigned short* Bt = kvTf + (((size_t)nt * 8) * 64 + lane) * 8;
      f32x4 acc0 = {0.f,0.f,0.f,0.f};
      f32x4 acc1 = {0.f,0.f,0.f,0.f};
      #pragma unroll
      for (int k0 = 0; k0 < 8; k0++) {
        bf16x8 b = *(const bf16x8*)&Bt[(size_t)k0 * 512];
        acc0 = mfma16(afq0[k0], b, acc0);
        acc1 = mfma16(afq1[k0], b, acc1);
      }
      #pragma unroll
      for (int i = 0; i < 4; i++) {
        OSb[m0 + i][nt * 16 + cn] = f2bf(acc0[i]);
        OSb[16 + m0 + i][nt * 16 + cn] = f2bf(acc1[i]);
      }
    }
  }
  // ---- zf (8 rows per wave) ----
  {
    float4 ks4 = ((const float4*)klsum)[lane];
    #pragma unroll
    for (int rr = 0; rr < 8; rr++) {
      const int r = wvv * 8 + rr;
      ushort4 q4 = *(const ushort4*)&Tsh[r][lane * 4];
      float s = bf2f(q4.x)*ks4.x + bf2f(q4.y)*ks4.y + bf2f(q4.z)*ks4.z + bf2f(q4.w)*ks4.w;
      s = waveAllSum(s);
      if (lane == 0) zf[r] = rcpf_(s + 1e-6f);
    }
  }
  __syncthreads();
  // ---- depthwise conv, 32 rows; Tf stored in-place into fm[] ----
  const int j = tid;
  float w[25];
  #pragma unroll
  for (int t = 0; t < 25; t++) w[t] = dwcw[j * 25 + t];
  const float bias = dwcb[j];
  const int y = i0 >> 8, x0 = i0 & 255;
  float fm[32];
  #pragma unroll
  for (int r = 0; r < 32; r++) fm[r] = bias;
  #pragma unroll
  for (int dy = -2; dy <= 2; dy++) {
    const int yy = y + dy;
    if ((unsigned)yy > 255u) continue;
    float buf[36];
    #pragma unroll
    for (int i = 0; i < 36; i++) {
      const int xx = x0 - 2 + i;
      buf[i] = ((unsigned)xx <= 255u) ? bf2f(vph[(size_t)((yy << 8) + xx) * DD + j]) : 0.f;
    }
    const float* wr = &w[(dy + 2) * 5];
    #pragma unroll
    for (int r = 0; r < 32; r++)
      fm[r] += buf[r] * wr[0] + buf[r+1] * wr[1] + buf[r+2] * wr[2]
             + buf[r+3] * wr[3] + buf[r+4] * wr[4];
  }
  #pragma unroll
  for (int r = 0; r < 32; r++) {
    fm[r] = bf2f(OSb[r][j]) * zf[r] + fm[r];   // Tf in place
    Tsh[r][j] = f2bf(fm[r]);
  }
  __syncthreads();
  // ---- u = T@Wfa, v = T@Wfb; aft loaded, then Tsh freed for aVb ----
  {
    bf16x8 aft0[8], aft1[8];
    #pragma unroll
    for (int k0 = 0; k0 < 8; k0++) {
      aft0[k0] = *(const bf16x8*)&Tsh[cn][k0 * 32 + kq];
      aft1[k0] = *(const bf16x8*)&Tsh[16 + cn][k0 * 32 + kq];
    }
    __syncthreads();   // all waves hold T in regs before aVb(=Tsh) overwrite
    #pragma unroll 1
    for (int jb = 0; jb < 8; jb++) {
      const int nt = wvv * 4 + (jb & 3);
      const unsigned short* Bt = ((jb < 4) ? WfaTf : WfbTf) + (((size_t)nt * 8) * 64 + lane) * 8;
      f32x4 acc0 = {0.f,0.f,0.f,0.f};
      f32x4 acc1 = {0.f,0.f,0.f,0.f};
      #pragma unroll
      for (int k0 = 0; k0 < 8; k0++) {
        bf16x8 b = *(const bf16x8*)&Bt[(size_t)k0 * 512];
        acc0 = mfma16(aft0[k0], b, acc0);
        acc1 = mfma16(aft1[k0], b, acc1);
      }
      unsigned short (*dst)[264] = (jb < 4) ? OSb : aVb;
      #pragma unroll
      for (int i = 0; i < 4; i++) {
        dst[m0 + i][nt * 16 + cn] = f2bf(acc0[i]);
        dst[16 + m0 + i][nt * 16 + cn] = f2bf(acc1[i]);
      }
    }
  }
  __syncthreads();
  // ---- gate eval (8 rows per wave) ----
  {
    float4 bfa4 = ((const float4*)bfa)[lane];
    float4 bfb4 = ((const float4*)bfb)[lane];
    float4 wc4 = ((const float4*)Wc)[lane];
    const float bcv = bc[0];
    #pragma unroll
    for (int rr = 0; rr < 8; rr++) {
      const int r = wvv * 8 + rr;
      ushort4 uu = *(const ushort4*)&OSb[r][lane * 4];
      ushort4 vv = *(const ushort4*)&aVb[r][lane * 4];
      float g = ftanh_(bf2f(uu.x) + bfa4.x) * fsig_(bf2f(vv.x) + bfb4.x) * wc4.x
              + ftanh_(bf2f(uu.y) + bfa4.y) * fsig_(bf2f(vv.y) + bfb4.y) * wc4.y
              + ftanh_(bf2f(uu.z) + bfa4.z) * fsig_(bf2f(vv.z) + bfb4.z) * wc4.z
              + ftanh_(bf2f(uu.w) + bfa4.w) * fsig_(bf2f(vv.w) + bfb4.w) * wc4.w;
      g = waveAllSum(g);
      if (lane == 0) ev[r] = __expf(g + bcv);
    }
  }
  __syncthreads();
  float hp = 0.f;
  #pragma unroll
  for (int r = 0; r < 32; r++) hp += ev[r] * fm[r];
  atomicAdd(&h2tp[part * 256 + j], hp);
  if (tid == 0) {
    float es = 0.f;
    #pragma unroll
    for (int r = 0; r < 32; r++) es += ev[r];
    atomicAdd(&h2denp[part], es);
  }
}

// ---------- final tiny MLPs ----------
__global__ void __launch_bounds__(256) k_final(
    const float* __restrict__ A_cc, const float* __restrict__ occ,
    const float* __restrict__ A_sc, const float* __restrict__ osc,
    const float* __restrict__ w50p, const float* __restrict__ edenp,
    const float* __restrict__ h2tp, const float* __restrict__ h2denp,
    const float* __restrict__ vc, const float* __restrict__ Wf, const float* __restrict__ bf,
    const float* __restrict__ W1, const float* __restrict__ b1,
    const float* __restrict__ W2, const float* __restrict__ b2,
    const float* __restrict__ W3a, const float* __restrict__ b3a,
    const float* __restrict__ W3b, const float* __restrict__ b3b,
    float* __restrict__ out){
  int j = threadIdx.x;
  __shared__ float pw[64];
  __shared__ float w50t[64];
  __shared__ float t1[256], t2[256], h1[256], h2[256], fz[512], z1[256];
  if (j < 64) {
    float s = 0.f;
    #pragma unroll
    for (int p = 0; p < 8; p++) s += w50p[p * 64 + j];
    w50t[j] = s;
  }
  float edentot = 0.f, h2dentot = 0.f;
  #pragma unroll
  for (int p = 0; p < 8; p++) { edentot += edenp[p]; h2dentot += h2denp[p]; }
  // ===== CROSS =====
  if (j < 64) pw[j] = (j < 50) ? expf(A_cc[j]) : 0.f;
  __syncthreads();
  float den = 0.f;
  for (int i = 0; i < 50; i++) den += pw[i];
  float raw = 0.f;
  for (int i = 0; i < 50; i++) raw += pw[i] * occ[i * DD + j];
  t1[j] = raw / den;
  float r2 = 0.f;
  for (int i = 0; i < 50; i++) r2 += w50t[i] * vc[i * DD + j];
  t2[j] = r2 / edentot;
  __syncthreads();
  float a1 = 0.f, a2 = 0.f;
  for (int k = 0; k < DD; k++) { a1 += t1[k] * W1[k * DD + j]; a2 += t2[k] * W2[k * DD + j]; }
  h1[j] = fmaxf(a1 + b1[j], 0.f);
  h2[j] = fmaxf(a2 + b2[j], 0.f);
  __syncthreads();
  fz[j] = h1[j]; fz[256 + j] = h2[j];
  __syncthreads();
  float z = 0.f;
  for (int k = 0; k < 512; k++) z += fz[k] * W3a[k * DD + j];
  z1[j] = fmaxf(z + b3a[j], 0.f);
  __syncthreads();
  float o = 0.f;
  for (int k = 0; k < DD; k++) o += z1[k] * W3b[k * DD + j];
  out[j] = fmaxf(o + b3b[j], 0.f);
  __syncthreads();
  // ===== SELF =====
  if (j < 64) pw[j] = (j < 50) ? expf(A_sc[j]) : 0.f;
  __syncthreads();
  den = 0.f;
  for (int i = 0; i < 50; i++) den += pw[i];
  raw = 0.f;
  for (int i = 0; i < 50; i++) raw += pw[i] * osc[i * DD + j];
  t1[j] = raw / den;
  {
    float s = 0.f;
    #pragma unroll
    for (int p = 0; p < 8; p++) s += h2tp[p * 256 + j];
    t2[j] = s / h2dentot;
  }
  __syncthreads();
  float hs = 0.f;
  for (int k = 0; k < DD; k++) hs += t2[k] * Wf[k * DD + j];
  __syncthreads();
  t2[j] = hs + bf[j];
  __syncthreads();
  a1 = 0.f; a2 = 0.f;
  for (int k = 0; k < DD; k++) { a1 += t1[k] * W1[k * DD + j]; a2 += t2[k] * W2[k * DD + j]; }
  h1[j] = fmaxf(a1 + b1[j], 0.f);
  h2[j] = fmaxf(a2 + b2[j], 0.f);
  __syncthreads();
  fz[j] = h1[j]; fz[256 + j] = h2[j];
  __syncthreads();
  z = 0.f;
  for (int k = 0; k < 512; k++) z += fz[k] * W3a[k * DD + j];
  z1[j] = fmaxf(z + b3a[j], 0.f);
  __syncthreads();
  o = 0.f;
  for (int k = 0; k < DD; k++) o += z1[k] * W3b[k * DD + j];
  out[256 + j] = fmaxf(o + b3b[j], 0.f);
}

extern "C" void kernel_launch(void* const* d_in, const int* in_sizes, int n_in,
                              void* d_out, int out_size, void* d_ws, size_t ws_size,
                              hipStream_t stream) {
  if (ws_size < WS_NEEDED) return;
  const float* x   = (const float*)d_in[0];
  const float* Wqkv= (const float*)d_in[1];
  const float* sln = (const float*)d_in[2];
  const float* dwcw= (const float*)d_in[3];
  const float* dwcb= (const float*)d_in[4];
  const float* Wa  = (const float*)d_in[5];
  const float* ba  = (const float*)d_in[6];
  const float* Wb  = (const float*)d_in[7];
  const float* bb  = (const float*)d_in[8];
  const float* Wc  = (const float*)d_in[9];
  const float* bc  = (const float*)d_in[10];
  const float* W1  = (const float*)d_in[11];
  const float* b1  = (const float*)d_in[12];
  const float* W2  = (const float*)d_in[13];
  const float* b2  = (const float*)d_in[14];
  const float* W3a = (const float*)d_in[15];
  const float* b3a = (const float*)d_in[16];
  const float* W3b = (const float*)d_in[17];
  const float* b3b = (const float*)d_in[18];
  const float* Wf  = (const float*)d_in[19];
  const float* bf  = (const float*)d_in[20];

  char* wsb = (char*)d_ws;
  unsigned short* VPH = (unsigned short*)(wsb + B_VPH);
  unsigned short* QLH = (unsigned short*)(wsb + B_QLH);
  unsigned short* KLH = (unsigned short*)(wsb + B_KLH);
  float* EB = (float*)(wsb + B_E);
  float* SM = (float*)(wsb + B_SM);
  unsigned short* XT = (unsigned short*)(wsb + B_X);
  float* outp = (float*)d_out;

  hipMemsetAsync((void*)SM, 0, ZEND * sizeof(float), stream);

  k_prep0<<<98, 256, 0, stream>>>(x, Wqkv, SM + QC, SM + KC, SM + VC,
                                  XT + XT_QCH, XT + XT_KCH, XT + XT_WQKV);
  k_prep1<<<564, 256, 0, stream>>>(SM + VC, Wa, Wb, ba, bb, Wf, bf,
                                   SM + VCA, SM + VCB, XT + XT_VCAT, XT + XT_VCBT,
                                   SM + WFA, SM + WFB, SM + BFA, SM + BFB,
                                   XT + XT_WFAT, XT + XT_WFBT);
  k_oscg<<<50, 256, 0, stream>>>(SM + QC, SM + KC, SM + VC, Wa, Wb, ba, bb, Wc, bc,
                                 SM + OSCB, SM + ASC);

  k_path1<<<2048, 256, 0, stream>>>(x, XT + XT_WQKV, sln, XT + XT_KCH, XT + XT_QCH,
                                    XT + XT_VCAT, XT + XT_VCBT, ba, bb, Wc, bc,
                                    VPH, QLH, KLH, EB, SM + W50P, SM + EDENP, SM + OCCDENP);
  k_occnum<<<256, 512, 0, stream>>>(EB, VPH, SM + OCCRAW);
  k_kv<<<dim3(4, 128), 256, 0, stream>>>(KLH, VPH, (unsigned short*)EB, SM + KLSUMP);
  k_fin2<<<307, 256, 0, stream>>>((const unsigned short*)EB, XT + XT_KVT,
                                  SM + OCCRAW, SM + OCCDENP, SM + OCCB,
                                  SM + KLSUMP, SM + KLSUMR);
  k_gated<<<50, 256, 0, stream>>>(SM + OCCB, Wa, Wb, ba, bb, Wc, bc, SM + ACC50);

  k_tail<<<2048, 256, 0, stream>>>(QLH, XT + XT_KVT, SM + KLSUMR, VPH, dwcw, dwcb,
                                   XT + XT_WFAT, XT + XT_WFBT, SM + BFA, SM + BFB,
                                   Wc, bc, SM + H2TP, SM + H2DENP);

  k_final<<<1, 256, 0, stream>>>(SM + ACC50, SM + OCCB, SM + ASC, SM + OSCB,
                                 SM + W50P, SM + EDENP, SM + H2TP, SM + H2DENP,
                                 SM + VC, Wf, bf, W1, b1, W2, b2, W3a, b3a, W3b, b3b, outp);
}

// Round 7
// 574.744 us; speedup vs baseline: 1.0180x; 1.0180x over previous
//
#include <hip/hip_runtime.h>
#include <hip/hip_bf16.h>
#include <math.h>

// MixedAttentionLayer — R15:
//  - k_tail reverted to R12 form (R14's Tsh/aVb alias + extra barrier caused
//    the 578->585 regression; k_path1 was measured unchanged).
//  - k_kv: LDS staging now TRANSPOSED at write (k-major, stride-swizzled
//    off(c,k)=c*40+(c>>3)*8+k). Fragment reads become 8x ds_read_b128
//    instead of 64 scalar ds_read_u16 per thread per step (m33->m92 lesson).
//  - k_path1 kept at R14 form (stable 143-147us across 3 rounds of changes).

constexpr int DD = 256;
constexpr int MM = 50;
constexpr float SCL = 0.0625f; // 256^-0.5

// ---- byte offsets in d_ws ----
constexpr size_t B_VPH = 0;
constexpr size_t B_QLH = (size_t)32 << 20;
constexpr size_t B_KLH = (size_t)64 << 20;
constexpr size_t B_E   = (size_t)96 << 20;
constexpr size_t B_SM  = (size_t)112 << 20;
constexpr size_t B_X   = B_SM + ((size_t)2 << 20);

// ---- float offsets within SM region (zeroed part first) ----
constexpr size_t KLSUMR = 0;
constexpr size_t KLSUMP = 256;
constexpr size_t OCCDENP= 2304;
constexpr size_t W50P   = 2816;
constexpr size_t EDENP  = 3328;
constexpr size_t H2TP   = 3336;
constexpr size_t H2DENP = 5384;
constexpr size_t OCCRAW = 5392;
constexpr size_t ZEND   = 18192;
constexpr size_t QC     = ZEND;
constexpr size_t KC     = QC + 12800;
constexpr size_t VC     = KC + 12800;
constexpr size_t VCA    = VC + 12800;
constexpr size_t VCB    = VCA + 12800;
constexpr size_t WFA    = VCB + 12800;
constexpr size_t WFB    = WFA + 65536;
constexpr size_t BFA    = WFB + 65536;
constexpr size_t BFB    = BFA + 256;
constexpr size_t OSCB   = BFB + 256;
constexpr size_t OCCB   = OSCB + 12800;
constexpr size_t ASC    = OCCB + 12800;
constexpr size_t ACC50  = ASC + 64;
constexpr size_t SMEND  = ACC50 + 64;

// ---- short offsets within X region (all fragment-major) ----
constexpr size_t XT_WQKV = 0;          // 48t x 8k0 x 64 x 8 = 196608
constexpr size_t XT_WFAT = 196608;     // 16 x 8 x 64 x 8 = 65536
constexpr size_t XT_WFBT = 262144;
constexpr size_t XT_KVT  = 327680;     // 16 x 8 x 64 x 8
constexpr size_t XT_QCH  = 393216;     // 4 x 8 x 64 x 8 = 16384
constexpr size_t XT_KCH  = 409600;
constexpr size_t XT_VCAT = 425984;     // 16 x 2 x 64 x 8 = 16384
constexpr size_t XT_VCBT = 442368;
constexpr size_t XT_END  = 458752;
constexpr size_t WS_NEEDED = B_X + XT_END * 2;

typedef short bf16x8 __attribute__((ext_vector_type(8)));
typedef float f32x4 __attribute__((ext_vector_type(4)));

__device__ __forceinline__ float rcpf_(float x){ return __builtin_amdgcn_rcpf(x); }
__device__ __forceinline__ float fsig_(float x){ return rcpf_(1.0f + __expf(-x)); }
__device__ __forceinline__ float ftanh_(float x){ return 1.0f - 2.0f * rcpf_(__expf(2.0f * x) + 1.0f); }

__device__ __forceinline__ float bf2f(unsigned short u){
  return __uint_as_float(((unsigned int)u) << 16);
}
__device__ __forceinline__ unsigned short f2bf(float f){
  union { __hip_bfloat16 h; unsigned short u; } c;
  c.h = __float2bfloat16(f);
  return c.u;
}
__device__ __forceinline__ f32x4 mfma16(bf16x8 a, bf16x8 b, f32x4 c){
  return __builtin_amdgcn_mfma_f32_16x16x32_bf16(a, b, c, 0, 0, 0);
}

__device__ __forceinline__ float waveAllSum(float v){
  #pragma unroll
  for (int m = 1; m < 64; m <<= 1) v += __shfl_xor(v, m, 64);
  return v;
}

// fragment-major index helper
__device__ __forceinline__ size_t fragIdx(int n, int k, int K8){
  const int tile = n >> 4, cn = n & 15;
  const int k0 = k >> 5, kqi = (k >> 3) & 3, e = k & 7;
  return (((size_t)tile * K8 + k0) * 64 + (kqi * 16 + cn)) * 8 + e;
}

// k-major swizzled LDS offset for k_kv staging (shorts). Stride 40 shorts
// (80B, 16B-aligned reads) + 8-short bump every 8 cols so writers that are
// 8 columns apart land 4 banks apart (not all on bank 0).
__device__ __forceinline__ int kvOff(int c, int k){
  return c * 40 + (c >> 3) * 8 + k;
}

// ---------- prep0: fragment-major Wqkv^T (blocks 0..47) + qc/kc/vc (48..97) ----------
__global__ void __launch_bounds__(256) k_prep0(const float* __restrict__ x, const float* __restrict__ Wqkv,
                                               float* qc, float* kc, float* vc,
                                               unsigned short* qch, unsigned short* kch,
                                               unsigned short* __restrict__ WT){
  const int b = blockIdx.x, t = threadIdx.x;
  if (b < 48) {
    __shared__ unsigned short Tt[64][72];
    const int bn = b % 12, bk = b / 12;
    const int n0 = bn * 64, k0g = bk * 64;
    #pragma unroll
    for (int i = 0; i < 16; i++) {
      const int k_l = (t >> 6) + i * 4;
      const int n_l = t & 63;
      Tt[n_l][k_l] = f2bf(Wqkv[(size_t)(k0g + k_l) * 768 + n0 + n_l]);
    }
    __syncthreads();
    #pragma unroll
    for (int i = 0; i < 2; i++) {
      const int fr = t * 2 + i;
      const int t_l = fr >> 7;
      const int k0_l = (fr >> 6) & 1;
      const int lane_f = fr & 63;
      const int n_l = t_l * 16 + (lane_f & 15);
      const int k_l = k0_l * 32 + (lane_f >> 4) * 8;
      const int tg = (n0 >> 4) + t_l;
      const int k0gl = (k0g >> 5) + k0_l;
      bf16x8 v = *(const bf16x8*)&Tt[n_l][k_l];
      *(bf16x8*)&WT[(((size_t)tg * 8 + k0gl) * 64 + lane_f) * 8] = v;
    }
    return;
  }
  __shared__ float xs[256];
  const int r = b - 48, j = t;
  xs[j] = x[r * DD + j];
  __syncthreads();
  float aq = 0.f, ak = 0.f, av = 0.f;
  for (int k = 0; k < DD; k++) {
    float xv = xs[k];
    aq += xv * Wqkv[k * 768 + j];
    ak += xv * Wqkv[k * 768 + 256 + j];
    av += xv * Wqkv[k * 768 + 512 + j];
  }
  qc[r * DD + j] = aq; kc[r * DD + j] = ak; vc[r * DD + j] = av;
  qch[fragIdx(r, j, 8)] = f2bf(aq);
  kch[fragIdx(r, j, 8)] = f2bf(ak);
  if (r == 0) {
    for (int c = 50; c < 64; c++) {
      qch[fragIdx(c, j, 8)] = 0;
      kch[fragIdx(c, j, 8)] = 0;
    }
  }
}

// ---------- prep1: Vca/Vcb (0..49) + Wfa/Wfb/bfa/bfb (50..563), fragment-major bf16 ----------
__global__ void __launch_bounds__(256) k_prep1(const float* vc, const float* Wa, const float* Wb,
                                               const float* ba, const float* bb,
                                               const float* Wf, const float* bf,
                                               float* Vca, float* Vcb,
                                               unsigned short* VcaTh, unsigned short* VcbTh,
                                               float* Wfa, float* Wfb, float* bfa, float* bfb,
                                               unsigned short* WfaTh, unsigned short* WfbTh){
  __shared__ float rs[256];
  const int b = blockIdx.x, j = threadIdx.x;
  if (b < 50) {
    const int r = b;
    rs[j] = vc[r * DD + j];
    __syncthreads();
    float a = 0.f, bv = 0.f;
    for (int k = 0; k < DD; k++) { float v = rs[k]; a += v * Wa[k * DD + j]; bv += v * Wb[k * DD + j]; }
    Vca[r * DD + j] = a; Vcb[r * DD + j] = bv;
    VcaTh[fragIdx(j, r, 2)] = f2bf(a);
    VcbTh[fragIdx(j, r, 2)] = f2bf(bv);
    if (r == 0) {
      for (int c = 50; c < 64; c++) {
        VcaTh[fragIdx(j, c, 2)] = 0;
        VcbTh[fragIdx(j, c, 2)] = 0;
      }
    }
    return;
  }
  const int bb2 = b - 50;
  const float* src; const float* Wm;
  if (bb2 < 256)      { src = Wf + bb2 * DD;         Wm = Wa; }
  else if (bb2 < 512) { src = Wf + (bb2 - 256) * DD; Wm = Wb; }
  else if (bb2 == 512){ src = bf;                    Wm = Wa; }
  else                { src = bf;                    Wm = Wb; }
  rs[j] = src[j];
  __syncthreads();
  float a = 0.f;
  for (int k = 0; k < DD; k++) a += rs[k] * Wm[k * DD + j];
  if (bb2 < 256)      { Wfa[bb2 * DD + j] = a; WfaTh[fragIdx(j, bb2, 8)] = f2bf(a); }
  else if (bb2 < 512) { Wfb[(bb2 - 256) * DD + j] = a; WfbTh[fragIdx(j, bb2 - 256, 8)] = f2bf(a); }
  else if (bb2 == 512) bfa[j] = a + ba[j];
  else bfb[j] = a + bb[j];
}

// ---------- fused: osc row + gated(osc row) -> A_sc ----------
__global__ void __launch_bounds__(256) k_oscg(const float* __restrict__ qc, const float* __restrict__ kc,
                                              const float* __restrict__ vc,
                                              const float* __restrict__ Wa, const float* __restrict__ Wb,
                                              const float* __restrict__ ba, const float* __restrict__ bb,
                                              const float* __restrict__ Wc, const float* __restrict__ bc,
                                              float* __restrict__ osc, float* __restrict__ A){
  const int i = blockIdx.x, t = threadIdx.x;
  __shared__ float qs[256];
  __shared__ float P[64];
  __shared__ float red[4];
  qs[t] = qc[i * DD + t];
  __syncthreads();
  if (t < 64) {
    float s = -1e30f;
    if (t < 50) {
      float acc = 0.f;
      const float4* kr = (const float4*)&kc[t * DD];
      #pragma unroll 8
      for (int k = 0; k < 64; k++) {
        float4 kv = kr[k];
        float4 qv = *(const float4*)&qs[k * 4];
        acc += qv.x * kv.x + qv.y * kv.y + qv.z * kv.z + qv.w * kv.w;
      }
      s = acc * SCL;
    }
    float mx = s;
    #pragma unroll
    for (int m = 1; m < 64; m <<= 1) mx = fmaxf(mx, __shfl_xor(mx, m, 64));
    float e = (t < 50) ? __expf(s - mx) : 0.f;
    float den = waveAllSum(e);
    P[t] = e * rcpf_(den);
  }
  __syncthreads();
  float a = 0.f;
  for (int jj = 0; jj < 50; jj++) a += P[jj] * vc[jj * DD + t];
  osc[i * DD + t] = a;
  __syncthreads();
  qs[t] = a;
  __syncthreads();
  float u = 0.f, v = 0.f;
  for (int k = 0; k < DD; k++) { float tv = qs[k]; u += tv * Wa[k * DD + t]; v += tv * Wb[k * DD + t]; }
  float g = ftanh_(u + ba[t]) * fsig_(v + bb[t]) * Wc[t];
  g = waveAllSum(g);
  const int lane = t & 63, wv = t >> 6;
  if (lane == 0) red[wv] = g;
  __syncthreads();
  if (t == 0) A[i] = red[0] + red[1] + red[2] + red[3] + bc[0];
}

// ---------- gated() on 50 rows ----------
__global__ void __launch_bounds__(256) k_gated(const float* __restrict__ tin,
                                               const float* __restrict__ Wa, const float* __restrict__ Wb,
                                               const float* __restrict__ ba, const float* __restrict__ bb,
                                               const float* __restrict__ Wc, const float* __restrict__ bc,
                                               float* __restrict__ A){
  int r = blockIdx.x, j = threadIdx.x;
  __shared__ float ts[256];
  __shared__ float red[4];
  ts[j] = tin[r * DD + j];
  __syncthreads();
  float u = 0.f, v = 0.f;
  for (int k = 0; k < DD; k++) { float tv = ts[k]; u += tv * Wa[k * DD + j]; v += tv * Wb[k * DD + j]; }
  float g = ftanh_(u + ba[j]) * fsig_(v + bb[j]) * Wc[j];
  g = waveAllSum(g);
  int lane = j & 63, wv = j >> 6;
  if (lane == 0) red[wv] = g;
  __syncthreads();
  if (j == 0) A[r] = red[0] + red[1] + red[2] + red[3] + bc[0];
}

// ---------- fused path kernel: 32 rows/block, 38912 B arena ----------
__global__ void __launch_bounds__(256) k_path1(
    const float* __restrict__ x, const unsigned short* __restrict__ WTf,
    const float* __restrict__ sln,
    const unsigned short* __restrict__ kchf, const unsigned short* __restrict__ qchf,
    const unsigned short* __restrict__ VcaTf, const unsigned short* __restrict__ VcbTf,
    const float* __restrict__ ba, const float* __restrict__ bb,
    const float* __restrict__ Wc, const float* __restrict__ bc,
    unsigned short* __restrict__ vph, unsigned short* __restrict__ qlh, unsigned short* __restrict__ klh,
    float* __restrict__ E, float* __restrict__ w50p, float* __restrict__ edenp, float* __restrict__ occdenp){
  __shared__ __align__(16) char arena[38912];
  unsigned short (*Psh)[72]   = (unsigned short (*)[72])arena;
  float (*denp)[4]            = (float (*)[4])(arena + 4608);
  unsigned short (*qpsb)[264] = (unsigned short (*)[264])(arena + 5120);
  unsigned short (*kpsb)[264] = (unsigned short (*)[264])(arena + 22016);

  const int tid = threadIdx.x;
  const int i0 = blockIdx.x * 32;
  const int part = blockIdx.x & 7;
  const int lane = tid & 63;
  const int wvv = tid >> 6;
  const int cn = lane & 15;
  const int m0 = (lane >> 4) * 4;
  const int kq = (lane >> 4) * 8;

  for (int l = tid; l < 2048; l += 256) {
    const int r = l >> 6, c4 = (l & 63) * 4;
    const float4 xv = *(const float4*)&x[(size_t)(MM + i0 + r) * DD + c4];
    ushort4 o; o.x = f2bf(xv.x); o.y = f2bf(xv.y); o.z = f2bf(xv.z); o.w = f2bf(xv.w);
    *(ushort4*)&qpsb[r][c4] = o;
  }
  __syncthreads();

  bf16x8 af0[8], af1[8];
  #pragma unroll
  for (int k0 = 0; k0 < 8; k0++) {
    af0[k0] = *(const bf16x8*)&qpsb[cn][k0 * 32 + kq];
    af1[k0] = *(const bf16x8*)&qpsb[16 + cn][k0 * 32 + kq];
  }
  __syncthreads();

  // ---- GEMM: [32 x 256] @ [256 x 768]; each B fragment feeds 2 MFMAs ----
  bf16x8 b0[8], b1[8];
  {
    const unsigned short* Bt = WTf + ((size_t)wvv * 8 * 64 + lane) * 8;
    #pragma unroll
    for (int k0 = 0; k0 < 8; k0++) b0[k0] = *(const bf16x8*)&Bt[(size_t)k0 * 512];
  }
  #pragma unroll 1
  for (int tt = 0; tt < 12; tt++) {
    const int t = wvv + 4 * tt;
    if (tt + 1 < 12) {
      const unsigned short* Bt = WTf + (((size_t)(t + 4) * 8) * 64 + lane) * 8;
      #pragma unroll
      for (int k0 = 0; k0 < 8; k0++) b1[k0] = *(const bf16x8*)&Bt[(size_t)k0 * 512];
    }
    f32x4 acc0 = {0.f, 0.f, 0.f, 0.f};
    f32x4 acc1 = {0.f, 0.f, 0.f, 0.f};
    #pragma unroll
    for (int k0 = 0; k0 < 8; k0++) {
      acc0 = mfma16(af0[k0], b0[k0], acc0);
      acc1 = mfma16(af1[k0], b0[k0], acc1);
    }
    if (t < 16) {
      int c = t * 16 + cn;
      #pragma unroll
      for (int i = 0; i < 4; i++) {
        qpsb[m0 + i][c] = f2bf(acc0[i]);
        qpsb[16 + m0 + i][c] = f2bf(acc1[i]);
      }
    } else if (t < 32) {
      int c = (t - 16) * 16 + cn;
      #pragma unroll
      for (int i = 0; i < 4; i++) {
        kpsb[m0 + i][c] = f2bf(acc0[i]);
        kpsb[16 + m0 + i][c] = f2bf(acc1[i]);
      }
    } else {
      int c = (t - 32) * 16 + cn;
      #pragma unroll
      for (int i = 0; i < 4; i++) {
        vph[(size_t)(i0 + m0 + i) * DD + c] = f2bf(acc0[i]);
        vph[(size_t)(i0 + 16 + m0 + i) * DD + c] = f2bf(acc1[i]);
      }
    }
    #pragma unroll
    for (int k0 = 0; k0 < 8; k0++) b0[k0] = b1[k0];
  }
  __syncthreads();

  // ---- scores via MFMA; exp kept in regs; den partials via 16-lane reduce ----
  float ep0[4], ep1[4];
  {
    f32x4 accp0 = {0.f,0.f,0.f,0.f}, accp1 = {0.f,0.f,0.f,0.f};
    f32x4 accc0 = {0.f,0.f,0.f,0.f}, accc1 = {0.f,0.f,0.f,0.f};
    const unsigned short* Bk = kchf + ((size_t)wvv * 8 * 64 + lane) * 8;
    const unsigned short* Bq = qchf + ((size_t)wvv * 8 * 64 + lane) * 8;
    #pragma unroll
    for (int k0 = 0; k0 < 8; k0++) {
      bf16x8 aq0 = *(const bf16x8*)&qpsb[cn][k0 * 32 + kq];
      bf16x8 aq1 = *(const bf16x8*)&qpsb[16 + cn][k0 * 32 + kq];
      bf16x8 ak0 = *(const bf16x8*)&kpsb[cn][k0 * 32 + kq];
      bf16x8 ak1 = *(const bf16x8*)&kpsb[16 + cn][k0 * 32 + kq];
      bf16x8 bk = *(const bf16x8*)&Bk[(size_t)k0 * 512];
      bf16x8 bq = *(const bf16x8*)&Bq[(size_t)k0 * 512];
      accp0 = mfma16(aq0, bk, accp0);
      accp1 = mfma16(aq1, bk, accp1);
      accc0 = mfma16(ak0, bq, accc0);
      accc1 = mfma16(ak1, bq, accc1);
    }
    const int col = wvv * 16 + cn;
    const bool ok = (col < 50);
    #pragma unroll
    for (int i = 0; i < 4; i++) {
      ep0[i] = ok ? __expf(accp0[i] * SCL) : 0.f;
      ep1[i] = ok ? __expf(accp1[i] * SCL) : 0.f;
    }
    float osum = 0.f;
    #pragma unroll
    for (int i = 0; i < 4; i++) {
      float ec0 = __expf(accc0[i] * SCL);
      float ec1 = __expf(accc1[i] * SCL);
      E[(size_t)(i0 + m0 + i) * 64 + col] = ok ? ec0 : 0.f;
      E[(size_t)(i0 + 16 + m0 + i) * 64 + col] = ok ? ec1 : 0.f;
      if (ok) osum += ec0 + ec1;
    }
    osum += __shfl_xor(osum, 16, 64);
    osum += __shfl_xor(osum, 32, 64);
    if (lane < 16 && ok) atomicAdd(&occdenp[part * 64 + col], osum);
    float d0[4], d1[4];
    #pragma unroll
    for (int i = 0; i < 4; i++) { d0[i] = ep0[i]; d1[i] = ep1[i]; }
    #pragma unroll
    for (int m = 1; m < 16; m <<= 1) {
      #pragma unroll
      for (int i = 0; i < 4; i++) {
        d0[i] += __shfl_xor(d0[i], m, 64);
        d1[i] += __shfl_xor(d1[i], m, 64);
      }
    }
    if (cn == 0) {
      #pragma unroll
      for (int i = 0; i < 4; i++) {
        denp[m0 + i][wvv] = d0[i];
        denp[16 + m0 + i][wvv] = d1[i];
      }
    }
  }
  __syncthreads();

  // ---- normalize P from regs -> Psh (fragment-ready layout) ----
  {
    const int col = wvv * 16 + cn;
    #pragma unroll
    for (int i = 0; i < 4; i++) {
      float4 dp = *(const float4*)&denp[m0 + i][0];
      Psh[m0 + i][col] = f2bf(ep0[i] * rcpf_(dp.x + dp.y + dp.z + dp.w));
      float4 dq = *(const float4*)&denp[16 + m0 + i][0];
      Psh[16 + m0 + i][col] = f2bf(ep1[i] * rcpf_(dq.x + dq.y + dq.z + dq.w));
    }
  }

  // ---- phase B: transforms (8 rows per wave) ----
  float4 sl4 = ((const float4*)sln)[lane];
  float4 rsp;
  rsp.x = rcpf_(log1pf(expf(sl4.x))); rsp.y = rcpf_(log1pf(expf(sl4.y)));
  rsp.z = rcpf_(log1pf(expf(sl4.z))); rsp.w = rcpf_(log1pf(expf(sl4.w)));
  float4 ba4 = ((const float4*)ba)[lane];
  float4 bb4 = ((const float4*)bb)[lane];
  float4 wc4 = ((const float4*)Wc)[lane];
  float bcv = bc[0];
  for (int rr = 0; rr < 8; rr++) {
    const int r = wvv * 8 + rr;
    const int row = i0 + r;
    ushort4 qu = *(const ushort4*)&qpsb[r][lane * 4];
    ushort4 ku = *(const ushort4*)&kpsb[r][lane * 4];
    float4 q4 = {bf2f(qu.x), bf2f(qu.y), bf2f(qu.z), bf2f(qu.w)};
    float4 k4 = {bf2f(ku.x), bf2f(ku.y), bf2f(ku.z), bf2f(ku.w)};
    float4 lq, lk;
    lq.x = (fmaxf(q4.x, 0.f) + 1e-6f) * rsp.x; lq.y = (fmaxf(q4.y, 0.f) + 1e-6f) * rsp.y;
    lq.z = (fmaxf(q4.z, 0.f) + 1e-6f) * rsp.z; lq.w = (fmaxf(q4.w, 0.f) + 1e-6f) * rsp.w;
    lk.x = (fmaxf(k4.x, 0.f) + 1e-6f) * rsp.x; lk.y = (fmaxf(k4.y, 0.f) + 1e-6f) * rsp.y;
    lk.z = (fmaxf(k4.z, 0.f) + 1e-6f) * rsp.z; lk.w = (fmaxf(k4.w, 0.f) + 1e-6f) * rsp.w;
    float4 q3, k3;
    q3.x = lq.x*lq.x*lq.x; q3.y = lq.y*lq.y*lq.y; q3.z = lq.z*lq.z*lq.z; q3.w = lq.w*lq.w*lq.w;
    k3.x = lk.x*lk.x*lk.x; k3.y = lk.y*lk.y*lk.y; k3.z = lk.z*lk.z*lk.z; k3.w = lk.w*lk.w*lk.w;
    float n1q = lq.x*lq.x + lq.y*lq.y + lq.z*lq.z + lq.w*lq.w;
    float n3q = q3.x*q3.x + q3.y*q3.y + q3.z*q3.z + q3.w*q3.w;
    float n1k = lk.x*lk.x + lk.y*lk.y + lk.z*lk.z + lk.w*lk.w;
    float n3k = k3.x*k3.x + k3.y*k3.y + k3.z*k3.z + k3.w*k3.w;
    n1q = waveAllSum(n1q); n3q = waveAllSum(n3q);
    n1k = waveAllSum(n1k); n3k = waveAllSum(n3k);
    float fq = sqrtf(n1q * rcpf_(n3q));
    float fk = sqrtf(n1k * rcpf_(n3k));
    ushort4 qo, ko;
    qo.x = f2bf(q3.x * fq); qo.y = f2bf(q3.y * fq); qo.z = f2bf(q3.z * fq); qo.w = f2bf(q3.w * fq);
    ko.x = f2bf(k3.x * fk); ko.y = f2bf(k3.y * fk); ko.z = f2bf(k3.z * fk); ko.w = f2bf(k3.w * fk);
    *(ushort4*)&qlh[(size_t)row * DD + lane * 4] = qo;
    *(ushort4*)&klh[(size_t)row * DD + lane * 4] = ko;
  }
  __syncthreads();

  // ---- gate via MFMA: u = P@Vca, v = P@Vcb (fragment-major B, K8=2) ----
  {
    bf16x8 ap0[2], ap1[2];
    #pragma unroll
    for (int k0 = 0; k0 < 2; k0++) {
      ap0[k0] = *(const bf16x8*)&Psh[cn][k0 * 32 + kq];
      ap1[k0] = *(const bf16x8*)&Psh[16 + cn][k0 * 32 + kq];
    }
    #pragma unroll 1
    for (int tt = 0; tt < 4; tt++) {
      const int nt = wvv * 4 + tt;
      const unsigned short* Bu = VcaTf + (((size_t)nt * 2) * 64 + lane) * 8;
      const unsigned short* Bv = VcbTf + (((size_t)nt * 2) * 64 + lane) * 8;
      f32x4 au0 = {0.f,0.f,0.f,0.f}, au1 = {0.f,0.f,0.f,0.f};
      f32x4 av0 = {0.f,0.f,0.f,0.f}, av1 = {0.f,0.f,0.f,0.f};
      #pragma unroll
      for (int k0 = 0; k0 < 2; k0++) {
        bf16x8 bu = *(const bf16x8*)&Bu[(size_t)k0 * 512];
        bf16x8 bv = *(const bf16x8*)&Bv[(size_t)k0 * 512];
        au0 = mfma16(ap0[k0], bu, au0);
        au1 = mfma16(ap1[k0], bu, au1);
        av0 = mfma16(ap0[k0], bv, av0);
        av1 = mfma16(ap1[k0], bv, av1);
      }
      #pragma unroll
      for (int i = 0; i < 4; i++) {
        qpsb[m0 + i][nt * 16 + cn] = f2bf(au0[i]);
        qpsb[16 + m0 + i][nt * 16 + cn] = f2bf(au1[i]);
        kpsb[m0 + i][nt * 16 + cn] = f2bf(av0[i]);
        kpsb[16 + m0 + i][nt * 16 + cn] = f2bf(av1[i]);
      }
    }
  }
  __syncthreads();

  // ---- gate eval; exp(g) stored in Psh row padding ----
  #pragma unroll
  for (int rr = 0; rr < 8; rr++) {
    const int r = wvv * 8 + rr;
    ushort4 uu = *(const ushort4*)&qpsb[r][lane * 4];
    ushort4 vv = *(const ushort4*)&kpsb[r][lane * 4];
    float g = ftanh_(bf2f(uu.x) + ba4.x) * fsig_(bf2f(vv.x) + bb4.x) * wc4.x
            + ftanh_(bf2f(uu.y) + ba4.y) * fsig_(bf2f(vv.y) + bb4.y) * wc4.y
            + ftanh_(bf2f(uu.z) + ba4.z) * fsig_(bf2f(vv.z) + bb4.z) * wc4.z
            + ftanh_(bf2f(uu.w) + ba4.w) * fsig_(bf2f(vv.w) + bb4.w) * wc4.w;
    g = waveAllSum(g);
    if (lane == 0) *(float*)&Psh[r][64] = __expf(g + bcv);
  }
  __syncthreads();
  if (tid < 64) {
    float s = 0.f;
    #pragma unroll
    for (int r = 0; r < 32; r++) s += *(const float*)&Psh[r][64] * bf2f(Psh[r][tid]);
    atomicAdd(&w50p[part * 64 + tid], s);
  }
  if (tid == 0) {
    float es = 0.f;
    #pragma unroll
    for (int r = 0; r < 32; r++) es += *(const float*)&Psh[r][64];
    atomicAdd(&edenp[part], es);
  }
}

// ---------- occ numerator: 512 threads, two j-halves per block ----------
__global__ void __launch_bounds__(512) k_occnum(const float* __restrict__ E, const unsigned short* __restrict__ vph,
                                                float* __restrict__ occraw){
  const int d = threadIdx.x & 255;
  const int half = threadIdx.x >> 8;
  const int j0 = blockIdx.x * 256;
  __shared__ float Es[2][32][64];
  float acc[52];
  #pragma unroll
  for (int i = 0; i < 52; i++) acc[i] = 0.f;
  for (int s = 0; s < 4; s++) {
    const int sj = j0 + (half * 4 + s) * 32;
    for (int l = d; l < 512; l += 256) {
      int jj = l >> 4, cq = l & 15;
      *(float4*)&Es[half][jj][cq * 4] = ((const float4*)(E + (size_t)(sj + jj) * 64))[cq];
    }
    __syncthreads();
    for (int jj = 0; jj < 32; jj++) {
      float vv = bf2f(vph[(size_t)(sj + jj) * DD + d]);
      #pragma unroll
      for (int q = 0; q < 13; q++) {
        float4 e4 = *(const float4*)&Es[half][jj][q * 4];
        acc[q * 4 + 0] += e4.x * vv; acc[q * 4 + 1] += e4.y * vv;
        acc[q * 4 + 2] += e4.z * vv; acc[q * 4 + 3] += e4.w * vv;
      }
    }
    __syncthreads();
  }
  for (int i = 0; i < 50; i++) atomicAdd(&occraw[i * DD + d], acc[i]);
}

// ---------- kv = kl^T @ vp: transposed (k-major) LDS staging, b128 reads ----------
__global__ void __launch_bounds__(256) k_kv(const unsigned short* __restrict__ klh,
                                            const unsigned short* __restrict__ vph,
                                            unsigned short* __restrict__ PP,
                                            float* __restrict__ klsump){
  __shared__ __align__(16) unsigned short AklT[2608];    // kvOff(63,31)+1
  __shared__ __align__(16) unsigned short BvpT[10480];   // kvOff(255,31)+1
  const int tid = threadIdx.x;
  const int lane = tid & 63;
  const int wvv = tid >> 6;
  const int cn = lane & 15;
  const int m0 = (lane >> 4) * 4;
  const int kq = (lane >> 4) * 8;
  const int cb = blockIdx.x;
  const int z  = blockIdx.y;
  const int jj = tid >> 3;       // k index within 32-row step
  const int c8 = (tid & 7) * 8;  // col offset

  f32x4 acc[4][4];
  f32x4 acc1[4];
  #pragma unroll
  for (int mt = 0; mt < 4; mt++) {
    acc1[mt] = (f32x4){0.f,0.f,0.f,0.f};
    #pragma unroll
    for (int tl = 0; tl < 4; tl++) acc[mt][tl] = (f32x4){0.f,0.f,0.f,0.f};
  }
  bf16x8 ones;
  #pragma unroll
  for (int i = 0; i < 8; i++) ones[i] = (short)0x3F80;

  const int jbase = z * 512;
  #pragma unroll 1
  for (int step = 0; step < 16; step++) {
    const int j0 = jbase + step * 32;
    {
      bf16x8 av = *(const bf16x8*)&klh[(size_t)(j0 + jj) * 256 + cb * 64 + c8];
      #pragma unroll
      for (int i = 0; i < 8; i++) AklT[kvOff(c8 + i, jj)] = (unsigned short)av[i];
      #pragma unroll
      for (int rep = 0; rep < 4; rep++) {
        bf16x8 bv = *(const bf16x8*)&vph[(size_t)(j0 + jj) * 256 + rep * 64 + c8];
        #pragma unroll
        for (int i = 0; i < 8; i++) BvpT[kvOff(rep * 64 + c8 + i, jj)] = (unsigned short)bv[i];
      }
    }
    __syncthreads();
    bf16x8 afr[4], bfr[4];
    #pragma unroll
    for (int mt = 0; mt < 4; mt++)
      afr[mt] = *(const bf16x8*)&AklT[kvOff(cn + mt * 16, kq)];
    #pragma unroll
    for (int tl = 0; tl < 4; tl++)
      bfr[tl] = *(const bf16x8*)&BvpT[kvOff(wvv * 64 + tl * 16 + cn, kq)];
    #pragma unroll
    for (int mt = 0; mt < 4; mt++) {
      acc1[mt] = mfma16(afr[mt], ones, acc1[mt]);
      #pragma unroll
      for (int tl = 0; tl < 4; tl++) acc[mt][tl] = mfma16(afr[mt], bfr[tl], acc[mt][tl]);
    }
    __syncthreads();
  }
  unsigned short* P = PP + ((size_t)(cb * 128 + z)) * 16384;
  #pragma unroll
  for (int mt = 0; mt < 4; mt++)
    #pragma unroll
    for (int tl = 0; tl < 4; tl++) {
      const int n = (wvv * 4 + tl) * 16 + cn;
      #pragma unroll
      for (int i = 0; i < 4; i++)
        P[(size_t)(mt * 16 + m0 + i) * 256 + n] = f2bf(acc[mt][tl][i]);
    }
  if (wvv == 0 && cn == 0) {
    #pragma unroll
    for (int mt = 0; mt < 4; mt++)
      #pragma unroll
      for (int i = 0; i < 4; i++)
        atomicAdd(&klsump[(z & 7) * 256 + cb * 64 + mt * 16 + m0 + i], acc1[mt][i]);
  }
}

// ---------- merged: kvred (0..255) + occfin (256..305) + klsum reduce (306) ----------
__global__ void __launch_bounds__(256) k_fin2(const unsigned short* __restrict__ PP,
                                              unsigned short* __restrict__ kvTf,
                                              const float* __restrict__ occraw,
                                              const float* __restrict__ occdenp,
                                              float* __restrict__ occ,
                                              const float* __restrict__ klsump,
                                              float* __restrict__ klsum){
  const int b = blockIdx.x, d = threadIdx.x;
  if (b < 256) {
    const int cb = b >> 6, m = b & 63;
    float s = 0.f;
    for (int z = 0; z < 128; z++)
      s += bf2f(PP[((size_t)(cb * 128 + z)) * 16384 + (size_t)m * 256 + d]);
    kvTf[fragIdx(d, b, 8)] = f2bf(s);
  } else if (b < 306) {
    const int i = b - 256;
    float den = 0.f;
    #pragma unroll
    for (int p = 0; p < 8; p++) den += occdenp[p * 64 + i];
    occ[i * DD + d] = occraw[i * DD + d] / den;
  } else {
    float s = 0.f;
    #pragma unroll
    for (int p = 0; p < 8; p++) s += klsump[p * 256 + d];
    klsum[d] = s;
  }
}

// ---------- fused tail: 32 rows/block (R12 form) ----------
__global__ void __launch_bounds__(256) k_tail(const unsigned short* __restrict__ qlh,
                                              const unsigned short* __restrict__ kvTf,
                                              const float* __restrict__ klsum,
                                              const unsigned short* __restrict__ vph,
                                              const float* __restrict__ dwcw, const float* __restrict__ dwcb,
                                              const unsigned short* __restrict__ WfaTf,
                                              const unsigned short* __restrict__ WfbTf,
                                              const float* __restrict__ bfa, const float* __restrict__ bfb,
                                              const float* __restrict__ Wc, const float* __restrict__ bc,
                                              float* __restrict__ h2tp, float* __restrict__ h2denp){
  __shared__ unsigned short Tsh[32][264];
  __shared__ unsigned short OSb[32][264];
  __shared__ unsigned short aVb[32][264];
  __shared__ float zf[32];
  __shared__ float ev[32];
  const int tid = threadIdx.x;
  const int i0 = blockIdx.x * 32;
  const int part = blockIdx.x & 7;
  const int lane = tid & 63;
  const int wvv = tid >> 6;
  const int cn = lane & 15;
  const int m0 = (lane >> 4) * 4;
  const int kq = (lane >> 4) * 8;
  for (int l = tid; l < 2048; l += 256) {
    int r = l >> 6, c4 = (l & 63) * 4;
    *(ushort4*)&Tsh[r][c4] = *(const ushort4*)&qlh[(size_t)(i0 + r) * DD + c4];
  }
  __syncthreads();
  // ---- OS = ql @ kv (each B fragment feeds 2 MFMAs) ----
  {
    bf16x8 afq0[8], afq1[8];
    #pragma unroll
    for (int k0 = 0; k0 < 8; k0++) {
      afq0[k0] = *(const bf16x8*)&Tsh[cn][k0 * 32 + kq];
      afq1[k0] = *(const bf16x8*)&Tsh[16 + cn][k0 * 32 + kq];
    }
    #pragma unroll 1
    for (int tt = 0; tt < 4; tt++) {
      const int nt = wvv * 4 + tt;
      const unsigned short* Bt = kvTf + (((size_t)nt * 8) * 64 + lane) * 8;
      f32x4 acc0 = {0.f,0.f,0.f,0.f};
      f32x4 acc1 = {0.f,0.f,0.f,0.f};
      #pragma unroll
      for (int k0 = 0; k0 < 8; k0++) {
        bf16x8 b = *(const bf16x8*)&Bt[(size_t)k0 * 512];
        acc0 = mfma16(afq0[k0], b, acc0);
        acc1 = mfma16(afq1[k0], b, acc1);
      }
      #pragma unroll
      for (int i = 0; i < 4; i++) {
        OSb[m0 + i][nt * 16 + cn] = f2bf(acc0[i]);
        OSb[16 + m0 + i][nt * 16 + cn] = f2bf(acc1[i]);
      }
    }
  }
  // ---- zf (8 rows per wave) ----
  {
    float4 ks4 = ((const float4*)klsum)[lane];
    #pragma unroll
    for (int rr = 0; rr < 8; rr++) {
      const int r = wvv * 8 + rr;
      ushort4 q4 = *(const ushort4*)&Tsh[r][lane * 4];
      float s = bf2f(q4.x)*ks4.x + bf2f(q4.y)*ks4.y + bf2f(q4.z)*ks4.z + bf2f(q4.w)*ks4.w;
      s = waveAllSum(s);
      if (lane == 0) zf[r] = rcpf_(s + 1e-6f);
    }
  }
  __syncthreads();
  // ---- depthwise conv, 32 rows; Tf stored in-place into fm[] ----
  const int j = tid;
  float w[25];
  #pragma unroll
  for (int t = 0; t < 25; t++) w[t] = dwcw[j * 25 + t];
  const float bias = dwcb[j];
  const int y = i0 >> 8, x0 = i0 & 255;
  float fm[32];
  #pragma unroll
  for (int r = 0; r < 32; r++) fm[r] = bias;
  #pragma unroll
  for (int dy = -2; dy <= 2; dy++) {
    const int yy = y + dy;
    if ((unsigned)yy > 255u) continue;
    float buf[36];
    #pragma unroll
    for (int i = 0; i < 36; i++) {
      const int xx = x0 - 2 + i;
      buf[i] = ((unsigned)xx <= 255u) ? bf2f(vph[(size_t)((yy << 8) + xx) * DD + j]) : 0.f;
    }
    const float* wr = &w[(dy + 2) * 5];
    #pragma unroll
    for (int r = 0; r < 32; r++)
      fm[r] += buf[r] * wr[0] + buf[r+1] * wr[1] + buf[r+2] * wr[2]
             + buf[r+3] * wr[3] + buf[r+4] * wr[4];
  }
  #pragma unroll
  for (int r = 0; r < 32; r++) {
    fm[r] = bf2f(OSb[r][j]) * zf[r] + fm[r];   // Tf in place
    Tsh[r][j] = f2bf(fm[r]);
  }
  __syncthreads();
  // ---- u = T@Wfa, v = T@Wfb (each B fragment feeds 2 MFMAs) ----
  {
    bf16x8 aft0[8], aft1[8];
    #pragma unroll
    for (int k0 = 0; k0 < 8; k0++) {
      aft0[k0] = *(const bf16x8*)&Tsh[cn][k0 * 32 + kq];
      aft1[k0] = *(const bf16x8*)&Tsh[16 + cn][k0 * 32 + kq];
    }
    #pragma unroll 1
    for (int jb = 0; jb < 8; jb++) {
      const int nt = wvv * 4 + (jb & 3);
      const unsigned short* Bt = ((jb < 4) ? WfaTf : WfbTf) + (((size_t)nt * 8) * 64 + lane) * 8;
      f32x4 acc0 = {0.f,0.f,0.f,0.f};
      f32x4 acc1 = {0.f,0.f,0.f,0.f};
      #pragma unroll
      for (int k0 = 0; k0 < 8; k0++) {
        bf16x8 b = *(const bf16x8*)&Bt[(size_t)k0 * 512];
        acc0 = mfma16(aft0[k0], b, acc0);
        acc1 = mfma16(aft1[k0], b, acc1);
      }
      unsigned short (*dst)[264] = (jb < 4) ? OSb : aVb;
      #pragma unroll
      for (int i = 0; i < 4; i++) {
        dst[m0 + i][nt * 16 + cn] = f2bf(acc0[i]);
        dst[16 + m0 + i][nt * 16 + cn] = f2bf(acc1[i]);
      }
    }
  }
  __syncthreads();
  // ---- gate eval (8 rows per wave) ----
  {
    float4 bfa4 = ((const float4*)bfa)[lane];
    float4 bfb4 = ((const float4*)bfb)[lane];
    float4 wc4 = ((const float4*)Wc)[lane];
    const float bcv = bc[0];
    #pragma unroll
    for (int rr = 0; rr < 8; rr++) {
      const int r = wvv * 8 + rr;
      ushort4 uu = *(const ushort4*)&OSb[r][lane * 4];
      ushort4 vv = *(const ushort4*)&aVb[r][lane * 4];
      float g = ftanh_(bf2f(uu.x) + bfa4.x) * fsig_(bf2f(vv.x) + bfb4.x) * wc4.x
              + ftanh_(bf2f(uu.y) + bfa4.y) * fsig_(bf2f(vv.y) + bfb4.y) * wc4.y
              + ftanh_(bf2f(uu.z) + bfa4.z) * fsig_(bf2f(vv.z) + bfb4.z) * wc4.z
              + ftanh_(bf2f(uu.w) + bfa4.w) * fsig_(bf2f(vv.w) + bfb4.w) * wc4.w;
      g = waveAllSum(g);
      if (lane == 0) ev[r] = __expf(g + bcv);
    }
  }
  __syncthreads();
  float hp = 0.f;
  #pragma unroll
  for (int r = 0; r < 32; r++) hp += ev[r] * fm[r];
  atomicAdd(&h2tp[part * 256 + j], hp);
  if (tid == 0) {
    float es = 0.f;
    #pragma unroll
    for (int r = 0; r < 32; r++) es += ev[r];
    atomicAdd(&h2denp[part], es);
  }
}

// ---------- final tiny MLPs ----------
__global__ void __launch_bounds__(256) k_final(
    const float* __restrict__ A_cc, const float* __restrict__ occ,
    const float* __restrict__ A_sc, const float* __restrict__ osc,
    const float* __restrict__ w50p, const float* __restrict__ edenp,
    const float* __restrict__ h2tp, const float* __restrict__ h2denp,
    const float* __restrict__ vc, const float* __restrict__ Wf, const float* __restrict__ bf,
    const float* __restrict__ W1, const float* __restrict__ b1,
    const float* __restrict__ W2, const float* __restrict__ b2,
    const float* __restrict__ W3a, const float* __restrict__ b3a,
    const float* __restrict__ W3b, const float* __restrict__ b3b,
    float* __restrict__ out){
  int j = threadIdx.x;
  __shared__ float pw[64];
  __shared__ float w50t[64];
  __shared__ float t1[256], t2[256], h1[256], h2[256], fz[512], z1[256];
  if (j < 64) {
    float s = 0.f;
    #pragma unroll
    for (int p = 0; p < 8; p++) s += w50p[p * 64 + j];
    w50t[j] = s;
  }
  float edentot = 0.f, h2dentot = 0.f;
  #pragma unroll
  for (int p = 0; p < 8; p++) { edentot += edenp[p]; h2dentot += h2denp[p]; }
  // ===== CROSS =====
  if (j < 64) pw[j] = (j < 50) ? expf(A_cc[j]) : 0.f;
  __syncthreads();
  float den = 0.f;
  for (int i = 0; i < 50; i++) den += pw[i];
  float raw = 0.f;
  for (int i = 0; i < 50; i++) raw += pw[i] * occ[i * DD + j];
  t1[j] = raw / den;
  float r2 = 0.f;
  for (int i = 0; i < 50; i++) r2 += w50t[i] * vc[i * DD + j];
  t2[j] = r2 / edentot;
  __syncthreads();
  float a1 = 0.f, a2 = 0.f;
  for (int k = 0; k < DD; k++) { a1 += t1[k] * W1[k * DD + j]; a2 += t2[k] * W2[k * DD + j]; }
  h1[j] = fmaxf(a1 + b1[j], 0.f);
  h2[j] = fmaxf(a2 + b2[j], 0.f);
  __syncthreads();
  fz[j] = h1[j]; fz[256 + j] = h2[j];
  __syncthreads();
  float z = 0.f;
  for (int k = 0; k < 512; k++) z += fz[k] * W3a[k * DD + j];
  z1[j] = fmaxf(z + b3a[j], 0.f);
  __syncthreads();
  float o = 0.f;
  for (int k = 0; k < DD; k++) o += z1[k] * W3b[k * DD + j];
  out[j] = fmaxf(o + b3b[j], 0.f);
  __syncthreads();
  // ===== SELF =====
  if (j < 64) pw[j] = (j < 50) ? expf(A_sc[j]) : 0.f;
  __syncthreads();
  den = 0.f;
  for (int i = 0; i < 50; i++) den += pw[i];
  raw = 0.f;
  for (int i = 0; i < 50; i++) raw += pw[i] * osc[i * DD + j];
  t1[j] = raw / den;
  {
    float s = 0.f;
    #pragma unroll
    for (int p = 0; p < 8; p++) s += h2tp[p * 256 + j];
    t2[j] = s / h2dentot;
  }
  __syncthreads();
  float hs = 0.f;
  for (int k = 0; k < DD; k++) hs += t2[k] * Wf[k * DD + j];
  __syncthreads();
  t2[j] = hs + bf[j];
  __syncthreads();
  a1 = 0.f; a2 = 0.f;
  for (int k = 0; k < DD; k++) { a1 += t1[k] * W1[k * DD + j]; a2 += t2[k] * W2[k * DD + j]; }
  h1[j] = fmaxf(a1 + b1[j], 0.f);
  h2[j] = fmaxf(a2 + b2[j], 0.f);
  __syncthreads();
  fz[j] = h1[j]; fz[256 + j] = h2[j];
  __syncthreads();
  z = 0.f;
  for (int k = 0; k < 512; k++) z += fz[k] * W3a[k * DD + j];
  z1[j] = fmaxf(z + b3a[j], 0.f);
  __syncthreads();
  o = 0.f;
  for (int k = 0; k < DD; k++) o += z1[k] * W3b[k * DD + j];
  out[256 + j] = fmaxf(o + b3b[j], 0.f);
}

extern "C" void kernel_launch(void* const* d_in, const int* in_sizes, int n_in,
                              void* d_out, int out_size, void* d_ws, size_t ws_size,
                              hipStream_t stream) {
  if (ws_size < WS_NEEDED) return;
  const float* x   = (const float*)d_in[0];
  const float* Wqkv= (const float*)d_in[1];
  const float* sln = (const float*)d_in[2];
  const float* dwcw= (const float*)d_in[3];
  const float* dwcb= (const float*)d_in[4];
  const float* Wa  = (const float*)d_in[5];
  const float* ba  = (const float*)d_in[6];
  const float* Wb  = (const float*)d_in[7];
  const float* bb  = (const float*)d_in[8];
  const float* Wc  = (const float*)d_in[9];
  const float* bc  = (const float*)d_in[10];
  const float* W1  = (const float*)d_in[11];
  const float* b1  = (const float*)d_in[12];
  const float* W2  = (const float*)d_in[13];
  const float* b2  = (const float*)d_in[14];
  const float* W3a = (const float*)d_in[15];
  const float* b3a = (const float*)d_in[16];
  const float* W3b = (const float*)d_in[17];
  const float* b3b = (const float*)d_in[18];
  const float* Wf  = (const float*)d_in[19];
  const float* bf  = (const float*)d_in[20];

  char* wsb = (char*)d_ws;
  unsigned short* VPH = (unsigned short*)(wsb + B_VPH);
  unsigned short* QLH = (unsigned short*)(wsb + B_QLH);
  unsigned short* KLH = (unsigned short*)(wsb + B_KLH);
  float* EB = (float*)(wsb + B_E);
  float* SM = (float*)(wsb + B_SM);
  unsigned short* XT = (unsigned short*)(wsb + B_X);
  float* outp = (float*)d_out;

  hipMemsetAsync((void*)SM, 0, ZEND * sizeof(float), stream);

  k_prep0<<<98, 256, 0, stream>>>(x, Wqkv, SM + QC, SM + KC, SM + VC,
                                  XT + XT_QCH, XT + XT_KCH, XT + XT_WQKV);
  k_prep1<<<564, 256, 0, stream>>>(SM + VC, Wa, Wb, ba, bb, Wf, bf,
                                   SM + VCA, SM + VCB, XT + XT_VCAT, XT + XT_VCBT,
                                   SM + WFA, SM + WFB, SM + BFA, SM + BFB,
                                   XT + XT_WFAT, XT + XT_WFBT);
  k_oscg<<<50, 256, 0, stream>>>(SM + QC, SM + KC, SM + VC, Wa, Wb, ba, bb, Wc, bc,
                                 SM + OSCB, SM + ASC);

  k_path1<<<2048, 256, 0, stream>>>(x, XT + XT_WQKV, sln, XT + XT_KCH, XT + XT_QCH,
                                    XT + XT_VCAT, XT + XT_VCBT, ba, bb, Wc, bc,
                                    VPH, QLH, KLH, EB, SM + W50P, SM + EDENP, SM + OCCDENP);
  k_occnum<<<256, 512, 0, stream>>>(EB, VPH, SM + OCCRAW);
  k_kv<<<dim3(4, 128), 256, 0, stream>>>(KLH, VPH, (unsigned short*)EB, SM + KLSUMP);
  k_fin2<<<307, 256, 0, stream>>>((const unsigned short*)EB, XT + XT_KVT,
                                  SM + OCCRAW, SM + OCCDENP, SM + OCCB,
                                  SM + KLSUMP, SM + KLSUMR);
  k_gated<<<50, 256, 0, stream>>>(SM + OCCB, Wa, Wb, ba, bb, Wc, bc, SM + ACC50);

  k_tail<<<2048, 256, 0, stream>>>(QLH, XT + XT_KVT, SM + KLSUMR, VPH, dwcw, dwcb,
                                   XT + XT_WFAT, XT + XT_WFBT, SM + BFA, SM + BFB,
                                   Wc, bc, SM + H2TP, SM + H2DENP);

  k_final<<<1, 256, 0, stream>>>(SM + ACC50, SM + OCCB, SM + ASC, SM + OSCB,
                                 SM + W50P, SM + EDENP, SM + H2TP, SM + H2DENP,
                                 SM + VC, Wf, bf, W1, b1, W2, b2, W3a, b3a, W3b, b3b, outp);
}

// Round 8
// 528.364 us; speedup vs baseline: 1.1074x; 1.0878x over previous
//
#include <hip/hip_runtime.h>
#include <hip/hip_bf16.h>
#include <math.h>

// MixedAttentionLayer — R16:
//  - k_occnum MFMA-ized: occraw = E^T @ vph (M=64,N=256,K=65536) using the
//    k_kv staging pattern. path1 now writes E as bf16 (Eh, half traffic);
//    denominator accumulated from the rounded value for num/den consistency.
//    128 z-blocks, 16 MFMA/step, f32 atomics into occraw.
//  - prep1's weight part (514 input-only blocks) merged into prep0 launch;
//    prep1 shrinks to the 50 vc-dependent blocks.
//  - k_path1 (143-144us plateau, 4 attempts) / k_kv / k_tail unchanged.

constexpr int DD = 256;
constexpr int MM = 50;
constexpr float SCL = 0.0625f; // 256^-0.5

// ---- byte offsets in d_ws ----
constexpr size_t B_VPH = 0;
constexpr size_t B_QLH = (size_t)32 << 20;
constexpr size_t B_KLH = (size_t)64 << 20;
constexpr size_t B_E   = (size_t)96 << 20;
constexpr size_t B_SM  = (size_t)112 << 20;
constexpr size_t B_X   = B_SM + ((size_t)2 << 20);

// ---- float offsets within SM region (zeroed part first) ----
constexpr size_t KLSUMR = 0;
constexpr size_t KLSUMP = 256;
constexpr size_t OCCDENP= 2304;
constexpr size_t W50P   = 2816;
constexpr size_t EDENP  = 3328;
constexpr size_t H2TP   = 3336;
constexpr size_t H2DENP = 5384;
constexpr size_t OCCRAW = 5392;
constexpr size_t ZEND   = 18192;
constexpr size_t QC     = ZEND;
constexpr size_t KC     = QC + 12800;
constexpr size_t VC     = KC + 12800;
constexpr size_t VCA    = VC + 12800;
constexpr size_t VCB    = VCA + 12800;
constexpr size_t WFA    = VCB + 12800;
constexpr size_t WFB    = WFA + 65536;
constexpr size_t BFA    = WFB + 65536;
constexpr size_t BFB    = BFA + 256;
constexpr size_t OSCB   = BFB + 256;
constexpr size_t OCCB   = OSCB + 12800;
constexpr size_t ASC    = OCCB + 12800;
constexpr size_t ACC50  = ASC + 64;
constexpr size_t SMEND  = ACC50 + 64;

// ---- short offsets within X region (all fragment-major) ----
constexpr size_t XT_WQKV = 0;          // 48t x 8k0 x 64 x 8 = 196608
constexpr size_t XT_WFAT = 196608;     // 16 x 8 x 64 x 8 = 65536
constexpr size_t XT_WFBT = 262144;
constexpr size_t XT_KVT  = 327680;     // 16 x 8 x 64 x 8
constexpr size_t XT_QCH  = 393216;     // 4 x 8 x 64 x 8 = 16384
constexpr size_t XT_KCH  = 409600;
constexpr size_t XT_VCAT = 425984;     // 16 x 2 x 64 x 8 = 16384
constexpr size_t XT_VCBT = 442368;
constexpr size_t XT_END  = 458752;
constexpr size_t WS_NEEDED = B_X + XT_END * 2;

typedef short bf16x8 __attribute__((ext_vector_type(8)));
typedef float f32x4 __attribute__((ext_vector_type(4)));

__device__ __forceinline__ float rcpf_(float x){ return __builtin_amdgcn_rcpf(x); }
__device__ __forceinline__ float fsig_(float x){ return rcpf_(1.0f + __expf(-x)); }
__device__ __forceinline__ float ftanh_(float x){ return 1.0f - 2.0f * rcpf_(__expf(2.0f * x) + 1.0f); }

__device__ __forceinline__ float bf2f(unsigned short u){
  return __uint_as_float(((unsigned int)u) << 16);
}
__device__ __forceinline__ unsigned short f2bf(float f){
  union { __hip_bfloat16 h; unsigned short u; } c;
  c.h = __float2bfloat16(f);
  return c.u;
}
__device__ __forceinline__ f32x4 mfma16(bf16x8 a, bf16x8 b, f32x4 c){
  return __builtin_amdgcn_mfma_f32_16x16x32_bf16(a, b, c, 0, 0, 0);
}

__device__ __forceinline__ float waveAllSum(float v){
  #pragma unroll
  for (int m = 1; m < 64; m <<= 1) v += __shfl_xor(v, m, 64);
  return v;
}

// fragment-major index helper
__device__ __forceinline__ size_t fragIdx(int n, int k, int K8){
  const int tile = n >> 4, cn = n & 15;
  const int k0 = k >> 5, kqi = (k >> 3) & 3, e = k & 7;
  return (((size_t)tile * K8 + k0) * 64 + (kqi * 16 + cn)) * 8 + e;
}

// k-major swizzled LDS offset for k_kv/k_occnum staging (shorts).
__device__ __forceinline__ int kvOff(int c, int k){
  return c * 40 + (c >> 3) * 8 + k;
}

// ---------- prep0: Wqkv^T frags (0..47) + qc/kc/vc (48..97) + Wf-weight part (98..611) ----------
__global__ void __launch_bounds__(256) k_prep0(const float* __restrict__ x, const float* __restrict__ Wqkv,
                                               float* qc, float* kc, float* vc,
                                               unsigned short* qch, unsigned short* kch,
                                               unsigned short* __restrict__ WT,
                                               const float* __restrict__ Wa, const float* __restrict__ Wb,
                                               const float* __restrict__ ba, const float* __restrict__ bb,
                                               const float* __restrict__ Wf, const float* __restrict__ bf,
                                               float* Wfa, float* Wfb, float* bfa, float* bfb,
                                               unsigned short* WfaTh, unsigned short* WfbTh){
  const int b = blockIdx.x, t = threadIdx.x;
  if (b < 48) {
    __shared__ unsigned short Tt[64][72];
    const int bn = b % 12, bk = b / 12;
    const int n0 = bn * 64, k0g = bk * 64;
    #pragma unroll
    for (int i = 0; i < 16; i++) {
      const int k_l = (t >> 6) + i * 4;
      const int n_l = t & 63;
      Tt[n_l][k_l] = f2bf(Wqkv[(size_t)(k0g + k_l) * 768 + n0 + n_l]);
    }
    __syncthreads();
    #pragma unroll
    for (int i = 0; i < 2; i++) {
      const int fr = t * 2 + i;
      const int t_l = fr >> 7;
      const int k0_l = (fr >> 6) & 1;
      const int lane_f = fr & 63;
      const int n_l = t_l * 16 + (lane_f & 15);
      const int k_l = k0_l * 32 + (lane_f >> 4) * 8;
      const int tg = (n0 >> 4) + t_l;
      const int k0gl = (k0g >> 5) + k0_l;
      bf16x8 v = *(const bf16x8*)&Tt[n_l][k_l];
      *(bf16x8*)&WT[(((size_t)tg * 8 + k0gl) * 64 + lane_f) * 8] = v;
    }
    return;
  }
  __shared__ float xs[256];
  const int j = t;
  if (b < 98) {
    const int r = b - 48;
    xs[j] = x[r * DD + j];
    __syncthreads();
    float aq = 0.f, ak = 0.f, av = 0.f;
    for (int k = 0; k < DD; k++) {
      float xv = xs[k];
      aq += xv * Wqkv[k * 768 + j];
      ak += xv * Wqkv[k * 768 + 256 + j];
      av += xv * Wqkv[k * 768 + 512 + j];
    }
    qc[r * DD + j] = aq; kc[r * DD + j] = ak; vc[r * DD + j] = av;
    qch[fragIdx(r, j, 8)] = f2bf(aq);
    kch[fragIdx(r, j, 8)] = f2bf(ak);
    if (r == 0) {
      for (int c = 50; c < 64; c++) {
        qch[fragIdx(c, j, 8)] = 0;
        kch[fragIdx(c, j, 8)] = 0;
      }
    }
    return;
  }
  // weight part (input-only): bb2 in [0, 514)
  const int bb2 = b - 98;
  const float* src; const float* Wm;
  if (bb2 < 256)      { src = Wf + bb2 * DD;         Wm = Wa; }
  else if (bb2 < 512) { src = Wf + (bb2 - 256) * DD; Wm = Wb; }
  else if (bb2 == 512){ src = bf;                    Wm = Wa; }
  else                { src = bf;                    Wm = Wb; }
  xs[j] = src[j];
  __syncthreads();
  float a = 0.f;
  for (int k = 0; k < DD; k++) a += xs[k] * Wm[k * DD + j];
  if (bb2 < 256)      { Wfa[bb2 * DD + j] = a; WfaTh[fragIdx(j, bb2, 8)] = f2bf(a); }
  else if (bb2 < 512) { Wfb[(bb2 - 256) * DD + j] = a; WfbTh[fragIdx(j, bb2 - 256, 8)] = f2bf(a); }
  else if (bb2 == 512) bfa[j] = a + ba[j];
  else bfb[j] = a + bb[j];
}

// ---------- prep1: Vca/Vcb (50 blocks, needs vc) ----------
__global__ void __launch_bounds__(256) k_prep1(const float* vc, const float* Wa, const float* Wb,
                                               float* Vca, float* Vcb,
                                               unsigned short* VcaTh, unsigned short* VcbTh){
  __shared__ float rs[256];
  const int b = blockIdx.x, j = threadIdx.x;
  const int r = b;
  rs[j] = vc[r * DD + j];
  __syncthreads();
  float a = 0.f, bv = 0.f;
  for (int k = 0; k < DD; k++) { float v = rs[k]; a += v * Wa[k * DD + j]; bv += v * Wb[k * DD + j]; }
  Vca[r * DD + j] = a; Vcb[r * DD + j] = bv;
  VcaTh[fragIdx(j, r, 2)] = f2bf(a);
  VcbTh[fragIdx(j, r, 2)] = f2bf(bv);
  if (r == 0) {
    for (int c = 50; c < 64; c++) {
      VcaTh[fragIdx(j, c, 2)] = 0;
      VcbTh[fragIdx(j, c, 2)] = 0;
    }
  }
}

// ---------- fused: osc row + gated(osc row) -> A_sc ----------
__global__ void __launch_bounds__(256) k_oscg(const float* __restrict__ qc, const float* __restrict__ kc,
                                              const float* __restrict__ vc,
                                              const float* __restrict__ Wa, const float* __restrict__ Wb,
                                              const float* __restrict__ ba, const float* __restrict__ bb,
                                              const float* __restrict__ Wc, const float* __restrict__ bc,
                                              float* __restrict__ osc, float* __restrict__ A){
  const int i = blockIdx.x, t = threadIdx.x;
  __shared__ float qs[256];
  __shared__ float P[64];
  __shared__ float red[4];
  qs[t] = qc[i * DD + t];
  __syncthreads();
  if (t < 64) {
    float s = -1e30f;
    if (t < 50) {
      float acc = 0.f;
      const float4* kr = (const float4*)&kc[t * DD];
      #pragma unroll 8
      for (int k = 0; k < 64; k++) {
        float4 kv = kr[k];
        float4 qv = *(const float4*)&qs[k * 4];
        acc += qv.x * kv.x + qv.y * kv.y + qv.z * kv.z + qv.w * kv.w;
      }
      s = acc * SCL;
    }
    float mx = s;
    #pragma unroll
    for (int m = 1; m < 64; m <<= 1) mx = fmaxf(mx, __shfl_xor(mx, m, 64));
    float e = (t < 50) ? __expf(s - mx) : 0.f;
    float den = waveAllSum(e);
    P[t] = e * rcpf_(den);
  }
  __syncthreads();
  float a = 0.f;
  for (int jj = 0; jj < 50; jj++) a += P[jj] * vc[jj * DD + t];
  osc[i * DD + t] = a;
  __syncthreads();
  qs[t] = a;
  __syncthreads();
  float u = 0.f, v = 0.f;
  for (int k = 0; k < DD; k++) { float tv = qs[k]; u += tv * Wa[k * DD + t]; v += tv * Wb[k * DD + t]; }
  float g = ftanh_(u + ba[t]) * fsig_(v + bb[t]) * Wc[t];
  g = waveAllSum(g);
  const int lane = t & 63, wv = t >> 6;
  if (lane == 0) red[wv] = g;
  __syncthreads();
  if (t == 0) A[i] = red[0] + red[1] + red[2] + red[3] + bc[0];
}

// ---------- gated() on 50 rows ----------
__global__ void __launch_bounds__(256) k_gated(const float* __restrict__ tin,
                                               const float* __restrict__ Wa, const float* __restrict__ Wb,
                                               const float* __restrict__ ba, const float* __restrict__ bb,
                                               const float* __restrict__ Wc, const float* __restrict__ bc,
                                               float* __restrict__ A){
  int r = blockIdx.x, j = threadIdx.x;
  __shared__ float ts[256];
  __shared__ float red[4];
  ts[j] = tin[r * DD + j];
  __syncthreads();
  float u = 0.f, v = 0.f;
  for (int k = 0; k < DD; k++) { float tv = ts[k]; u += tv * Wa[k * DD + j]; v += tv * Wb[k * DD + j]; }
  float g = ftanh_(u + ba[j]) * fsig_(v + bb[j]) * Wc[j];
  g = waveAllSum(g);
  int lane = j & 63, wv = j >> 6;
  if (lane == 0) red[wv] = g;
  __syncthreads();
  if (j == 0) A[r] = red[0] + red[1] + red[2] + red[3] + bc[0];
}

// ---------- fused path kernel: 32 rows/block, 38912 B arena ----------
__global__ void __launch_bounds__(256) k_path1(
    const float* __restrict__ x, const unsigned short* __restrict__ WTf,
    const float* __restrict__ sln,
    const unsigned short* __restrict__ kchf, const unsigned short* __restrict__ qchf,
    const unsigned short* __restrict__ VcaTf, const unsigned short* __restrict__ VcbTf,
    const float* __restrict__ ba, const float* __restrict__ bb,
    const float* __restrict__ Wc, const float* __restrict__ bc,
    unsigned short* __restrict__ vph, unsigned short* __restrict__ qlh, unsigned short* __restrict__ klh,
    unsigned short* __restrict__ Eh, float* __restrict__ w50p, float* __restrict__ edenp, float* __restrict__ occdenp){
  __shared__ __align__(16) char arena[38912];
  unsigned short (*Psh)[72]   = (unsigned short (*)[72])arena;
  float (*denp)[4]            = (float (*)[4])(arena + 4608);
  unsigned short (*qpsb)[264] = (unsigned short (*)[264])(arena + 5120);
  unsigned short (*kpsb)[264] = (unsigned short (*)[264])(arena + 22016);

  const int tid = threadIdx.x;
  const int i0 = blockIdx.x * 32;
  const int part = blockIdx.x & 7;
  const int lane = tid & 63;
  const int wvv = tid >> 6;
  const int cn = lane & 15;
  const int m0 = (lane >> 4) * 4;
  const int kq = (lane >> 4) * 8;

  for (int l = tid; l < 2048; l += 256) {
    const int r = l >> 6, c4 = (l & 63) * 4;
    const float4 xv = *(const float4*)&x[(size_t)(MM + i0 + r) * DD + c4];
    ushort4 o; o.x = f2bf(xv.x); o.y = f2bf(xv.y); o.z = f2bf(xv.z); o.w = f2bf(xv.w);
    *(ushort4*)&qpsb[r][c4] = o;
  }
  __syncthreads();

  bf16x8 af0[8], af1[8];
  #pragma unroll
  for (int k0 = 0; k0 < 8; k0++) {
    af0[k0] = *(const bf16x8*)&qpsb[cn][k0 * 32 + kq];
    af1[k0] = *(const bf16x8*)&qpsb[16 + cn][k0 * 32 + kq];
  }
  __syncthreads();

  // ---- GEMM: [32 x 256] @ [256 x 768]; each B fragment feeds 2 MFMAs ----
  bf16x8 b0[8], b1[8];
  {
    const unsigned short* Bt = WTf + ((size_t)wvv * 8 * 64 + lane) * 8;
    #pragma unroll
    for (int k0 = 0; k0 < 8; k0++) b0[k0] = *(const bf16x8*)&Bt[(size_t)k0 * 512];
  }
  #pragma unroll 1
  for (int tt = 0; tt < 12; tt++) {
    const int t = wvv + 4 * tt;
    if (tt + 1 < 12) {
      const unsigned short* Bt = WTf + (((size_t)(t + 4) * 8) * 64 + lane) * 8;
      #pragma unroll
      for (int k0 = 0; k0 < 8; k0++) b1[k0] = *(const bf16x8*)&Bt[(size_t)k0 * 512];
    }
    f32x4 acc0 = {0.f, 0.f, 0.f, 0.f};
    f32x4 acc1 = {0.f, 0.f, 0.f, 0.f};
    #pragma unroll
    for (int k0 = 0; k0 < 8; k0++) {
      acc0 = mfma16(af0[k0], b0[k0], acc0);
      acc1 = mfma16(af1[k0], b0[k0], acc1);
    }
    if (t < 16) {
      int c = t * 16 + cn;
      #pragma unroll
      for (int i = 0; i < 4; i++) {
        qpsb[m0 + i][c] = f2bf(acc0[i]);
        qpsb[16 + m0 + i][c] = f2bf(acc1[i]);
      }
    } else if (t < 32) {
      int c = (t - 16) * 16 + cn;
      #pragma unroll
      for (int i = 0; i < 4; i++) {
        kpsb[m0 + i][c] = f2bf(acc0[i]);
        kpsb[16 + m0 + i][c] = f2bf(acc1[i]);
      }
    } else {
      int c = (t - 32) * 16 + cn;
      #pragma unroll
      for (int i = 0; i < 4; i++) {
        vph[(size_t)(i0 + m0 + i) * DD + c] = f2bf(acc0[i]);
        vph[(size_t)(i0 + 16 + m0 + i) * DD + c] = f2bf(acc1[i]);
      }
    }
    #pragma unroll
    for (int k0 = 0; k0 < 8; k0++) b0[k0] = b1[k0];
  }
  __syncthreads();

  // ---- scores via MFMA; exp kept in regs; den partials via 16-lane reduce ----
  float ep0[4], ep1[4];
  {
    f32x4 accp0 = {0.f,0.f,0.f,0.f}, accp1 = {0.f,0.f,0.f,0.f};
    f32x4 accc0 = {0.f,0.f,0.f,0.f}, accc1 = {0.f,0.f,0.f,0.f};
    const unsigned short* Bk = kchf + ((size_t)wvv * 8 * 64 + lane) * 8;
    const unsigned short* Bq = qchf + ((size_t)wvv * 8 * 64 + lane) * 8;
    #pragma unroll
    for (int k0 = 0; k0 < 8; k0++) {
      bf16x8 aq0 = *(const bf16x8*)&qpsb[cn][k0 * 32 + kq];
      bf16x8 aq1 = *(const bf16x8*)&qpsb[16 + cn][k0 * 32 + kq];
      bf16x8 ak0 = *(const bf16x8*)&kpsb[cn][k0 * 32 + kq];
      bf16x8 ak1 = *(const bf16x8*)&kpsb[16 + cn][k0 * 32 + kq];
      bf16x8 bk = *(const bf16x8*)&Bk[(size_t)k0 * 512];
      bf16x8 bq = *(const bf16x8*)&Bq[(size_t)k0 * 512];
      accp0 = mfma16(aq0, bk, accp0);
      accp1 = mfma16(aq1, bk, accp1);
      accc0 = mfma16(ak0, bq, accc0);
      accc1 = mfma16(ak1, bq, accc1);
    }
    const int col = wvv * 16 + cn;
    const bool ok = (col < 50);
    #pragma unroll
    for (int i = 0; i < 4; i++) {
      ep0[i] = ok ? __expf(accp0[i] * SCL) : 0.f;
      ep1[i] = ok ? __expf(accp1[i] * SCL) : 0.f;
    }
    float osum = 0.f;
    #pragma unroll
    for (int i = 0; i < 4; i++) {
      unsigned short h0 = ok ? f2bf(__expf(accc0[i] * SCL)) : (unsigned short)0;
      unsigned short h1 = ok ? f2bf(__expf(accc1[i] * SCL)) : (unsigned short)0;
      Eh[(size_t)(i0 + m0 + i) * 64 + col] = h0;
      Eh[(size_t)(i0 + 16 + m0 + i) * 64 + col] = h1;
      if (ok) osum += bf2f(h0) + bf2f(h1);   // rounded value: num/den consistent
    }
    osum += __shfl_xor(osum, 16, 64);
    osum += __shfl_xor(osum, 32, 64);
    if (lane < 16 && ok) atomicAdd(&occdenp[part * 64 + col], osum);
    float d0[4], d1[4];
    #pragma unroll
    for (int i = 0; i < 4; i++) { d0[i] = ep0[i]; d1[i] = ep1[i]; }
    #pragma unroll
    for (int m = 1; m < 16; m <<= 1) {
      #pragma unroll
      for (int i = 0; i < 4; i++) {
        d0[i] += __shfl_xor(d0[i], m, 64);
        d1[i] += __shfl_xor(d1[i], m, 64);
      }
    }
    if (cn == 0) {
      #pragma unroll
      for (int i = 0; i < 4; i++) {
        denp[m0 + i][wvv] = d0[i];
        denp[16 + m0 + i][wvv] = d1[i];
      }
    }
  }
  __syncthreads();

  // ---- normalize P from regs -> Psh (fragment-ready layout) ----
  {
    const int col = wvv * 16 + cn;
    #pragma unroll
    for (int i = 0; i < 4; i++) {
      float4 dp = *(const float4*)&denp[m0 + i][0];
      Psh[m0 + i][col] = f2bf(ep0[i] * rcpf_(dp.x + dp.y + dp.z + dp.w));
      float4 dq = *(const float4*)&denp[16 + m0 + i][0];
      Psh[16 + m0 + i][col] = f2bf(ep1[i] * rcpf_(dq.x + dq.y + dq.z + dq.w));
    }
  }

  // ---- phase B: transforms (8 rows per wave) ----
  float4 sl4 = ((const float4*)sln)[lane];
  float4 rsp;
  rsp.x = rcpf_(log1pf(expf(sl4.x))); rsp.y = rcpf_(log1pf(expf(sl4.y)));
  rsp.z = rcpf_(log1pf(expf(sl4.z))); rsp.w = rcpf_(log1pf(expf(sl4.w)));
  float4 ba4 = ((const float4*)ba)[lane];
  float4 bb4 = ((const float4*)bb)[lane];
  float4 wc4 = ((const float4*)Wc)[lane];
  float bcv = bc[0];
  for (int rr = 0; rr < 8; rr++) {
    const int r = wvv * 8 + rr;
    const int row = i0 + r;
    ushort4 qu = *(const ushort4*)&qpsb[r][lane * 4];
    ushort4 ku = *(const ushort4*)&kpsb[r][lane * 4];
    float4 q4 = {bf2f(qu.x), bf2f(qu.y), bf2f(qu.z), bf2f(qu.w)};
    float4 k4 = {bf2f(ku.x), bf2f(ku.y), bf2f(ku.z), bf2f(ku.w)};
    float4 lq, lk;
    lq.x = (fmaxf(q4.x, 0.f) + 1e-6f) * rsp.x; lq.y = (fmaxf(q4.y, 0.f) + 1e-6f) * rsp.y;
    lq.z = (fmaxf(q4.z, 0.f) + 1e-6f) * rsp.z; lq.w = (fmaxf(q4.w, 0.f) + 1e-6f) * rsp.w;
    lk.x = (fmaxf(k4.x, 0.f) + 1e-6f) * rsp.x; lk.y = (fmaxf(k4.y, 0.f) + 1e-6f) * rsp.y;
    lk.z = (fmaxf(k4.z, 0.f) + 1e-6f) * rsp.z; lk.w = (fmaxf(k4.w, 0.f) + 1e-6f) * rsp.w;
    float4 q3, k3;
    q3.x = lq.x*lq.x*lq.x; q3.y = lq.y*lq.y*lq.y; q3.z = lq.z*lq.z*lq.z; q3.w = lq.w*lq.w*lq.w;
    k3.x = lk.x*lk.x*lk.x; k3.y = lk.y*lk.y*lk.y; k3.z = lk.z*lk.z*lk.z; k3.w = lk.w*lk.w*lk.w;
    float n1q = lq.x*lq.x + lq.y*lq.y + lq.z*lq.z + lq.w*lq.w;
    float n3q = q3.x*q3.x + q3.y*q3.y + q3.z*q3.z + q3.w*q3.w;
    float n1k = lk.x*lk.x + lk.y*lk.y + lk.z*lk.z + lk.w*lk.w;
    float n3k = k3.x*k3.x + k3.y*k3.y + k3.z*k3.z + k3.w*k3.w;
    n1q = waveAllSum(n1q); n3q = waveAllSum(n3q);
    n1k = waveAllSum(n1k); n3k = waveAllSum(n3k);
    float fq = sqrtf(n1q * rcpf_(n3q));
    float fk = sqrtf(n1k * rcpf_(n3k));
    ushort4 qo, ko;
    qo.x = f2bf(q3.x * fq); qo.y = f2bf(q3.y * fq); qo.z = f2bf(q3.z * fq); qo.w = f2bf(q3.w * fq);
    ko.x = f2bf(k3.x * fk); ko.y = f2bf(k3.y * fk); ko.z = f2bf(k3.z * fk); ko.w = f2bf(k3.w * fk);
    *(ushort4*)&qlh[(size_t)row * DD + lane * 4] = qo;
    *(ushort4*)&klh[(size_t)row * DD + lane * 4] = ko;
  }
  __syncthreads();

  // ---- gate via MFMA: u = P@Vca, v = P@Vcb (fragment-major B, K8=2) ----
  {
    bf16x8 ap0[2], ap1[2];
    #pragma unroll
    for (int k0 = 0; k0 < 2; k0++) {
      ap0[k0] = *(const bf16x8*)&Psh[cn][k0 * 32 + kq];
      ap1[k0] = *(const bf16x8*)&Psh[16 + cn][k0 * 32 + kq];
    }
    #pragma unroll 1
    for (int tt = 0; tt < 4; tt++) {
      const int nt = wvv * 4 + tt;
      const unsigned short* Bu = VcaTf + (((size_t)nt * 2) * 64 + lane) * 8;
      const unsigned short* Bv = VcbTf + (((size_t)nt * 2) * 64 + lane) * 8;
      f32x4 au0 = {0.f,0.f,0.f,0.f}, au1 = {0.f,0.f,0.f,0.f};
      f32x4 av0 = {0.f,0.f,0.f,0.f}, av1 = {0.f,0.f,0.f,0.f};
      #pragma unroll
      for (int k0 = 0; k0 < 2; k0++) {
        bf16x8 bu = *(const bf16x8*)&Bu[(size_t)k0 * 512];
        bf16x8 bv = *(const bf16x8*)&Bv[(size_t)k0 * 512];
        au0 = mfma16(ap0[k0], bu, au0);
        au1 = mfma16(ap1[k0], bu, au1);
        av0 = mfma16(ap0[k0], bv, av0);
        av1 = mfma16(ap1[k0], bv, av1);
      }
      #pragma unroll
      for (int i = 0; i < 4; i++) {
        qpsb[m0 + i][nt * 16 + cn] = f2bf(au0[i]);
        qpsb[16 + m0 + i][nt * 16 + cn] = f2bf(au1[i]);
        kpsb[m0 + i][nt * 16 + cn] = f2bf(av0[i]);
        kpsb[16 + m0 + i][nt * 16 + cn] = f2bf(av1[i]);
      }
    }
  }
  __syncthreads();

  // ---- gate eval; exp(g) stored in Psh row padding ----
  #pragma unroll
  for (int rr = 0; rr < 8; rr++) {
    const int r = wvv * 8 + rr;
    ushort4 uu = *(const ushort4*)&qpsb[r][lane * 4];
    ushort4 vv = *(const ushort4*)&kpsb[r][lane * 4];
    float g = ftanh_(bf2f(uu.x) + ba4.x) * fsig_(bf2f(vv.x) + bb4.x) * wc4.x
            + ftanh_(bf2f(uu.y) + ba4.y) * fsig_(bf2f(vv.y) + bb4.y) * wc4.y
            + ftanh_(bf2f(uu.z) + ba4.z) * fsig_(bf2f(vv.z) + bb4.z) * wc4.z
            + ftanh_(bf2f(uu.w) + ba4.w) * fsig_(bf2f(vv.w) + bb4.w) * wc4.w;
    g = waveAllSum(g);
    if (lane == 0) *(float*)&Psh[r][64] = __expf(g + bcv);
  }
  __syncthreads();
  if (tid < 64) {
    float s = 0.f;
    #pragma unroll
    for (int r = 0; r < 32; r++) s += *(const float*)&Psh[r][64] * bf2f(Psh[r][tid]);
    atomicAdd(&w50p[part * 64 + tid], s);
  }
  if (tid == 0) {
    float es = 0.f;
    #pragma unroll
    for (int r = 0; r < 32; r++) es += *(const float*)&Psh[r][64];
    atomicAdd(&edenp[part], es);
  }
}

// ---------- occ numerator as MFMA: occraw += E^T @ vph (per 512-row z-block) ----------
__global__ void __launch_bounds__(256) k_occnum(const unsigned short* __restrict__ Eh,
                                                const unsigned short* __restrict__ vph,
                                                float* __restrict__ occraw){
  __shared__ __align__(16) unsigned short EhT[2608];
  __shared__ __align__(16) unsigned short BvpT[10480];
  const int tid = threadIdx.x;
  const int lane = tid & 63;
  const int wvv = tid >> 6;
  const int cn = lane & 15;
  const int m0 = (lane >> 4) * 4;
  const int kq = (lane >> 4) * 8;
  const int z  = blockIdx.x;
  const int jj = tid >> 3;
  const int c8 = (tid & 7) * 8;

  f32x4 acc[4][4];
  #pragma unroll
  for (int mt = 0; mt < 4; mt++)
    #pragma unroll
    for (int tl = 0; tl < 4; tl++) acc[mt][tl] = (f32x4){0.f,0.f,0.f,0.f};

  const int jbase = z * 512;
  #pragma unroll 1
  for (int step = 0; step < 16; step++) {
    const int j0 = jbase + step * 32;
    {
      bf16x8 av = *(const bf16x8*)&Eh[(size_t)(j0 + jj) * 64 + c8];
      #pragma unroll
      for (int i = 0; i < 8; i++) EhT[kvOff(c8 + i, jj)] = (unsigned short)av[i];
      #pragma unroll
      for (int rep = 0; rep < 4; rep++) {
        bf16x8 bv = *(const bf16x8*)&vph[(size_t)(j0 + jj) * 256 + rep * 64 + c8];
        #pragma unroll
        for (int i = 0; i < 8; i++) BvpT[kvOff(rep * 64 + c8 + i, jj)] = (unsigned short)bv[i];
      }
    }
    __syncthreads();
    bf16x8 afr[4], bfr[4];
    #pragma unroll
    for (int mt = 0; mt < 4; mt++)
      afr[mt] = *(const bf16x8*)&EhT[kvOff(cn + mt * 16, kq)];
    #pragma unroll
    for (int tl = 0; tl < 4; tl++)
      bfr[tl] = *(const bf16x8*)&BvpT[kvOff(wvv * 64 + tl * 16 + cn, kq)];
    #pragma unroll
    for (int mt = 0; mt < 4; mt++)
      #pragma unroll
      for (int tl = 0; tl < 4; tl++) acc[mt][tl] = mfma16(afr[mt], bfr[tl], acc[mt][tl]);
    __syncthreads();
  }
  #pragma unroll
  for (int mt = 0; mt < 4; mt++)
    #pragma unroll
    for (int i = 0; i < 4; i++) {
      const int ri = mt * 16 + m0 + i;
      if (ri < 50) {
        #pragma unroll
        for (int tl = 0; tl < 4; tl++) {
          const int d = wvv * 64 + tl * 16 + cn;
          atomicAdd(&occraw[ri * DD + d], acc[mt][tl][i]);
        }
      }
    }
}

// ---------- kv = kl^T @ vp: transposed (k-major) LDS staging, b128 reads ----------
__global__ void __launch_bounds__(256) k_kv(const unsigned short* __restrict__ klh,
                                            const unsigned short* __restrict__ vph,
                                            unsigned short* __restrict__ PP,
                                            float* __restrict__ klsump){
  __shared__ __align__(16) unsigned short AklT[2608];
  __shared__ __align__(16) unsigned short BvpT[10480];
  const int tid = threadIdx.x;
  const int lane = tid & 63;
  const int wvv = tid >> 6;
  const int cn = lane & 15;
  const int m0 = (lane >> 4) * 4;
  const int kq = (lane >> 4) * 8;
  const int cb = blockIdx.x;
  const int z  = blockIdx.y;
  const int jj = tid >> 3;
  const int c8 = (tid & 7) * 8;

  f32x4 acc[4][4];
  f32x4 acc1[4];
  #pragma unroll
  for (int mt = 0; mt < 4; mt++) {
    acc1[mt] = (f32x4){0.f,0.f,0.f,0.f};
    #pragma unroll
    for (int tl = 0; tl < 4; tl++) acc[mt][tl] = (f32x4){0.f,0.f,0.f,0.f};
  }
  bf16x8 ones;
  #pragma unroll
  for (int i = 0; i < 8; i++) ones[i] = (short)0x3F80;

  const int jbase = z * 512;
  #pragma unroll 1
  for (int step = 0; step < 16; step++) {
    const int j0 = jbase + step * 32;
    {
      bf16x8 av = *(const bf16x8*)&klh[(size_t)(j0 + jj) * 256 + cb * 64 + c8];
      #pragma unroll
      for (int i = 0; i < 8; i++) AklT[kvOff(c8 + i, jj)] = (unsigned short)av[i];
      #pragma unroll
      for (int rep = 0; rep < 4; rep++) {
        bf16x8 bv = *(const bf16x8*)&vph[(size_t)(j0 + jj) * 256 + rep * 64 + c8];
        #pragma unroll
        for (int i = 0; i < 8; i++) BvpT[kvOff(rep * 64 + c8 + i, jj)] = (unsigned short)bv[i];
      }
    }
    __syncthreads();
    bf16x8 afr[4], bfr[4];
    #pragma unroll
    for (int mt = 0; mt < 4; mt++)
      afr[mt] = *(const bf16x8*)&AklT[kvOff(cn + mt * 16, kq)];
    #pragma unroll
    for (int tl = 0; tl < 4; tl++)
      bfr[tl] = *(const bf16x8*)&BvpT[kvOff(wvv * 64 + tl * 16 + cn, kq)];
    #pragma unroll
    for (int mt = 0; mt < 4; mt++) {
      acc1[mt] = mfma16(afr[mt], ones, acc1[mt]);
      #pragma unroll
      for (int tl = 0; tl < 4; tl++) acc[mt][tl] = mfma16(afr[mt], bfr[tl], acc[mt][tl]);
    }
    __syncthreads();
  }
  unsigned short* P = PP + ((size_t)(cb * 128 + z)) * 16384;
  #pragma unroll
  for (int mt = 0; mt < 4; mt++)
    #pragma unroll
    for (int tl = 0; tl < 4; tl++) {
      const int n = (wvv * 4 + tl) * 16 + cn;
      #pragma unroll
      for (int i = 0; i < 4; i++)
        P[(size_t)(mt * 16 + m0 + i) * 256 + n] = f2bf(acc[mt][tl][i]);
    }
  if (wvv == 0 && cn == 0) {
    #pragma unroll
    for (int mt = 0; mt < 4; mt++)
      #pragma unroll
      for (int i = 0; i < 4; i++)
        atomicAdd(&klsump[(z & 7) * 256 + cb * 64 + mt * 16 + m0 + i], acc1[mt][i]);
  }
}

// ---------- merged: kvred (0..255) + occfin (256..305) + klsum reduce (306) ----------
__global__ void __launch_bounds__(256) k_fin2(const unsigned short* __restrict__ PP,
                                              unsigned short* __restrict__ kvTf,
                                              const float* __restrict__ occraw,
                                              const float* __restrict__ occdenp,
                                              float* __restrict__ occ,
                                              const float* __restrict__ klsump,
                                              float* __restrict__ klsum){
  const int b = blockIdx.x, d = threadIdx.x;
  if (b < 256) {
    const int cb = b >> 6, m = b & 63;
    float s = 0.f;
    for (int z = 0; z < 128; z++)
      s += bf2f(PP[((size_t)(cb * 128 + z)) * 16384 + (size_t)m * 256 + d]);
    kvTf[fragIdx(d, b, 8)] = f2bf(s);
  } else if (b < 306) {
    const int i = b - 256;
    float den = 0.f;
    #pragma unroll
    for (int p = 0; p < 8; p++) den += occdenp[p * 64 + i];
    occ[i * DD + d] = occraw[i * DD + d] / den;
  } else {
    float s = 0.f;
    #pragma unroll
    for (int p = 0; p < 8; p++) s += klsump[p * 256 + d];
    klsum[d] = s;
  }
}

// ---------- fused tail: 32 rows/block (R12 form) ----------
__global__ void __launch_bounds__(256) k_tail(const unsigned short* __restrict__ qlh,
                                              const unsigned short* __restrict__ kvTf,
                                              const float* __restrict__ klsum,
                                              const unsigned short* __restrict__ vph,
                                              const float* __restrict__ dwcw, const float* __restrict__ dwcb,
                                              const unsigned short* __restrict__ WfaTf,
                                              const unsigned short* __restrict__ WfbTf,
                                              const float* __restrict__ bfa, const float* __restrict__ bfb,
                                              const float* __restrict__ Wc, const float* __restrict__ bc,
                                              float* __restrict__ h2tp, float* __restrict__ h2denp){
  __shared__ unsigned short Tsh[32][264];
  __shared__ unsigned short OSb[32][264];
  __shared__ unsigned short aVb[32][264];
  __shared__ float zf[32];
  __shared__ float ev[32];
  const int tid = threadIdx.x;
  const int i0 = blockIdx.x * 32;
  const int part = blockIdx.x & 7;
  const int lane = tid & 63;
  const int wvv = tid >> 6;
  const int cn = lane & 15;
  const int m0 = (lane >> 4) * 4;
  const int kq = (lane >> 4) * 8;
  for (int l = tid; l < 2048; l += 256) {
    int r = l >> 6, c4 = (l & 63) * 4;
    *(ushort4*)&Tsh[r][c4] = *(const ushort4*)&qlh[(size_t)(i0 + r) * DD + c4];
  }
  __syncthreads();
  // ---- OS = ql @ kv (each B fragment feeds 2 MFMAs) ----
  {
    bf16x8 afq0[8], afq1[8];
    #pragma unroll
    for (int k0 = 0; k0 < 8; k0++) {
      afq0[k0] = *(const bf16x8*)&Tsh[cn][k0 * 32 + kq];
      afq1[k0] = *(const bf16x8*)&Tsh[16 + cn][k0 * 32 + kq];
    }
    #pragma unroll 1
    for (int tt = 0; tt < 4; tt++) {
      const int nt = wvv * 4 + tt;
      const unsigned short* Bt = kvTf + (((size_t)nt * 8) * 64 + lane) * 8;
      f32x4 acc0 = {0.f,0.f,0.f,0.f};
      f32x4 acc1 = {0.f,0.f,0.f,0.f};
      #pragma unroll
      for (int k0 = 0; k0 < 8; k0++) {
        bf16x8 b = *(const bf16x8*)&Bt[(size_t)k0 * 512];
        acc0 = mfma16(afq0[k0], b, acc0);
        acc1 = mfma16(afq1[k0], b, acc1);
      }
      #pragma unroll
      for (int i = 0; i < 4; i++) {
        OSb[m0 + i][nt * 16 + cn] = f2bf(acc0[i]);
        OSb[16 + m0 + i][nt * 16 + cn] = f2bf(acc1[i]);
      }
    }
  }
  // ---- zf (8 rows per wave) ----
  {
    float4 ks4 = ((const float4*)klsum)[lane];
    #pragma unroll
    for (int rr = 0; rr < 8; rr++) {
      const int r = wvv * 8 + rr;
      ushort4 q4 = *(const ushort4*)&Tsh[r][lane * 4];
      float s = bf2f(q4.x)*ks4.x + bf2f(q4.y)*ks4.y + bf2f(q4.z)*ks4.z + bf2f(q4.w)*ks4.w;
      s = waveAllSum(s);
      if (lane == 0) zf[r] = rcpf_(s + 1e-6f);
    }
  }
  __syncthreads();
  // ---- depthwise conv, 32 rows; Tf stored in-place into fm[] ----
  const int j = tid;
  float w[25];
  #pragma unroll
  for (int t = 0; t < 25; t++) w[t] = dwcw[j * 25 + t];
  const float bias = dwcb[j];
  const int y = i0 >> 8, x0 = i0 & 255;
  float fm[32];
  #pragma unroll
  for (int r = 0; r < 32; r++) fm[r] = bias;
  #pragma unroll
  for (int dy = -2; dy <= 2; dy++) {
    const int yy = y + dy;
    if ((unsigned)yy > 255u) continue;
    float buf[36];
    #pragma unroll
    for (int i = 0; i < 36; i++) {
      const int xx = x0 - 2 + i;
      buf[i] = ((unsigned)xx <= 255u) ? bf2f(vph[(size_t)((yy << 8) + xx) * DD + j]) : 0.f;
    }
    const float* wr = &w[(dy + 2) * 5];
    #pragma unroll
    for (int r = 0; r < 32; r++)
      fm[r] += buf[r] * wr[0] + buf[r+1] * wr[1] + buf[r+2] * wr[2]
             + buf[r+3] * wr[3] + buf[r+4] * wr[4];
  }
  #pragma unroll
  for (int r = 0; r < 32; r++) {
    fm[r] = bf2f(OSb[r][j]) * zf[r] + fm[r];   // Tf in place
    Tsh[r][j] = f2bf(fm[r]);
  }
  __syncthreads();
  // ---- u = T@Wfa, v = T@Wfb (each B fragment feeds 2 MFMAs) ----
  {
    bf16x8 aft0[8], aft1[8];
    #pragma unroll
    for (int k0 = 0; k0 < 8; k0++) {
      aft0[k0] = *(const bf16x8*)&Tsh[cn][k0 * 32 + kq];
      aft1[k0] = *(const bf16x8*)&Tsh[16 + cn][k0 * 32 + kq];
    }
    #pragma unroll 1
    for (int jb = 0; jb < 8; jb++) {
      const int nt = wvv * 4 + (jb & 3);
      const unsigned short* Bt = ((jb < 4) ? WfaTf : WfbTf) + (((size_t)nt * 8) * 64 + lane) * 8;
      f32x4 acc0 = {0.f,0.f,0.f,0.f};
      f32x4 acc1 = {0.f,0.f,0.f,0.f};
      #pragma unroll
      for (int k0 = 0; k0 < 8; k0++) {
        bf16x8 b = *(const bf16x8*)&Bt[(size_t)k0 * 512];
        acc0 = mfma16(aft0[k0], b, acc0);
        acc1 = mfma16(aft1[k0], b, acc1);
      }
      unsigned short (*dst)[264] = (jb < 4) ? OSb : aVb;
      #pragma unroll
      for (int i = 0; i < 4; i++) {
        dst[m0 + i][nt * 16 + cn] = f2bf(acc0[i]);
        dst[16 + m0 + i][nt * 16 + cn] = f2bf(acc1[i]);
      }
    }
  }
  __syncthreads();
  // ---- gate eval (8 rows per wave) ----
  {
    float4 bfa4 = ((const float4*)bfa)[lane];
    float4 bfb4 = ((const float4*)bfb)[lane];
    float4 wc4 = ((const float4*)Wc)[lane];
    const float bcv = bc[0];
    #pragma unroll
    for (int rr = 0; rr < 8; rr++) {
      const int r = wvv * 8 + rr;
      ushort4 uu = *(const ushort4*)&OSb[r][lane * 4];
      ushort4 vv = *(const ushort4*)&aVb[r][lane * 4];
      float g = ftanh_(bf2f(uu.x) + bfa4.x) * fsig_(bf2f(vv.x) + bfb4.x) * wc4.x
              + ftanh_(bf2f(uu.y) + bfa4.y) * fsig_(bf2f(vv.y) + bfb4.y) * wc4.y
              + ftanh_(bf2f(uu.z) + bfa4.z) * fsig_(bf2f(vv.z) + bfb4.z) * wc4.z
              + ftanh_(bf2f(uu.w) + bfa4.w) * fsig_(bf2f(vv.w) + bfb4.w) * wc4.w;
      g = waveAllSum(g);
      if (lane == 0) ev[r] = __expf(g + bcv);
    }
  }
  __syncthreads();
  float hp = 0.f;
  #pragma unroll
  for (int r = 0; r < 32; r++) hp += ev[r] * fm[r];
  atomicAdd(&h2tp[part * 256 + j], hp);
  if (tid == 0) {
    float es = 0.f;
    #pragma unroll
    for (int r = 0; r < 32; r++) es += ev[r];
    atomicAdd(&h2denp[part], es);
  }
}

// ---------- final tiny MLPs ----------
__global__ void __launch_bounds__(256) k_final(
    const float* __restrict__ A_cc, const float* __restrict__ occ,
    const float* __restrict__ A_sc, const float* __restrict__ osc,
    const float* __restrict__ w50p, const float* __restrict__ edenp,
    const float* __restrict__ h2tp, const float* __restrict__ h2denp,
    const float* __restrict__ vc, const float* __restrict__ Wf, const float* __restrict__ bf,
    const float* __restrict__ W1, const float* __restrict__ b1,
    const float* __restrict__ W2, const float* __restrict__ b2,
    const float* __restrict__ W3a, const float* __restrict__ b3a,
    const float* __restrict__ W3b, const float* __restrict__ b3b,
    float* __restrict__ out){
  int j = threadIdx.x;
  __shared__ float pw[64];
  __shared__ float w50t[64];
  __shared__ float t1[256], t2[256], h1[256], h2[256], fz[512], z1[256];
  if (j < 64) {
    float s = 0.f;
    #pragma unroll
    for (int p = 0; p < 8; p++) s += w50p[p * 64 + j];
    w50t[j] = s;
  }
  float edentot = 0.f, h2dentot = 0.f;
  #pragma unroll
  for (int p = 0; p < 8; p++) { edentot += edenp[p]; h2dentot += h2denp[p]; }
  // ===== CROSS =====
  if (j < 64) pw[j] = (j < 50) ? expf(A_cc[j]) : 0.f;
  __syncthreads();
  float den = 0.f;
  for (int i = 0; i < 50; i++) den += pw[i];
  float raw = 0.f;
  for (int i = 0; i < 50; i++) raw += pw[i] * occ[i * DD + j];
  t1[j] = raw / den;
  float r2 = 0.f;
  for (int i = 0; i < 50; i++) r2 += w50t[i] * vc[i * DD + j];
  t2[j] = r2 / edentot;
  __syncthreads();
  float a1 = 0.f, a2 = 0.f;
  for (int k = 0; k < DD; k++) { a1 += t1[k] * W1[k * DD + j]; a2 += t2[k] * W2[k * DD + j]; }
  h1[j] = fmaxf(a1 + b1[j], 0.f);
  h2[j] = fmaxf(a2 + b2[j], 0.f);
  __syncthreads();
  fz[j] = h1[j]; fz[256 + j] = h2[j];
  __syncthreads();
  float z = 0.f;
  for (int k = 0; k < 512; k++) z += fz[k] * W3a[k * DD + j];
  z1[j] = fmaxf(z + b3a[j], 0.f);
  __syncthreads();
  float o = 0.f;
  for (int k = 0; k < DD; k++) o += z1[k] * W3b[k * DD + j];
  out[j] = fmaxf(o + b3b[j], 0.f);
  __syncthreads();
  // ===== SELF =====
  if (j < 64) pw[j] = (j < 50) ? expf(A_sc[j]) : 0.f;
  __syncthreads();
  den = 0.f;
  for (int i = 0; i < 50; i++) den += pw[i];
  raw = 0.f;
  for (int i = 0; i < 50; i++) raw += pw[i] * osc[i * DD + j];
  t1[j] = raw / den;
  {
    float s = 0.f;
    #pragma unroll
    for (int p = 0; p < 8; p++) s += h2tp[p * 256 + j];
    t2[j] = s / h2dentot;
  }
  __syncthreads();
  float hs = 0.f;
  for (int k = 0; k < DD; k++) hs += t2[k] * Wf[k * DD + j];
  __syncthreads();
  t2[j] = hs + bf[j];
  __syncthreads();
  a1 = 0.f; a2 = 0.f;
  for (int k = 0; k < DD; k++) { a1 += t1[k] * W1[k * DD + j]; a2 += t2[k] * W2[k * DD + j]; }
  h1[j] = fmaxf(a1 + b1[j], 0.f);
  h2[j] = fmaxf(a2 + b2[j], 0.f);
  __syncthreads();
  fz[j] = h1[j]; fz[256 + j] = h2[j];
  __syncthreads();
  z = 0.f;
  for (int k = 0; k < 512; k++) z += fz[k] * W3a[k * DD + j];
  z1[j] = fmaxf(z + b3a[j], 0.f);
  __syncthreads();
  o = 0.f;
  for (int k = 0; k < DD; k++) o += z1[k] * W3b[k * DD + j];
  out[256 + j] = fmaxf(o + b3b[j], 0.f);
}

extern "C" void kernel_launch(void* const* d_in, const int* in_sizes, int n_in,
                              void* d_out, int out_size, void* d_ws, size_t ws_size,
                              hipStream_t stream) {
  if (ws_size < WS_NEEDED) return;
  const float* x   = (const float*)d_in[0];
  const float* Wqkv= (const float*)d_in[1];
  const float* sln = (const float*)d_in[2];
  const float* dwcw= (const float*)d_in[3];
  const float* dwcb= (const float*)d_in[4];
  const float* Wa  = (const float*)d_in[5];
  const float* ba  = (const float*)d_in[6];
  const float* Wb  = (const float*)d_in[7];
  const float* bb  = (const float*)d_in[8];
  const float* Wc  = (const float*)d_in[9];
  const float* bc  = (const float*)d_in[10];
  const float* W1  = (const float*)d_in[11];
  const float* b1  = (const float*)d_in[12];
  const float* W2  = (const float*)d_in[13];
  const float* b2  = (const float*)d_in[14];
  const float* W3a = (const float*)d_in[15];
  const float* b3a = (const float*)d_in[16];
  const float* W3b = (const float*)d_in[17];
  const float* b3b = (const float*)d_in[18];
  const float* Wf  = (const float*)d_in[19];
  const float* bf  = (const float*)d_in[20];

  char* wsb = (char*)d_ws;
  unsigned short* VPH = (unsigned short*)(wsb + B_VPH);
  unsigned short* QLH = (unsigned short*)(wsb + B_QLH);
  unsigned short* KLH = (unsigned short*)(wsb + B_KLH);
  unsigned short* EHB = (unsigned short*)(wsb + B_E);
  float* SM = (float*)(wsb + B_SM);
  unsigned short* XT = (unsigned short*)(wsb + B_X);
  float* outp = (float*)d_out;

  hipMemsetAsync((void*)SM, 0, ZEND * sizeof(float), stream);

  k_prep0<<<612, 256, 0, stream>>>(x, Wqkv, SM + QC, SM + KC, SM + VC,
                                   XT + XT_QCH, XT + XT_KCH, XT + XT_WQKV,
                                   Wa, Wb, ba, bb, Wf, bf,
                                   SM + WFA, SM + WFB, SM + BFA, SM + BFB,
                                   XT + XT_WFAT, XT + XT_WFBT);
  k_prep1<<<50, 256, 0, stream>>>(SM + VC, Wa, Wb,
                                  SM + VCA, SM + VCB, XT + XT_VCAT, XT + XT_VCBT);
  k_oscg<<<50, 256, 0, stream>>>(SM + QC, SM + KC, SM + VC, Wa, Wb, ba, bb, Wc, bc,
                                 SM + OSCB, SM + ASC);

  k_path1<<<2048, 256, 0, stream>>>(x, XT + XT_WQKV, sln, XT + XT_KCH, XT + XT_QCH,
                                    XT + XT_VCAT, XT + XT_VCBT, ba, bb, Wc, bc,
                                    VPH, QLH, KLH, EHB, SM + W50P, SM + EDENP, SM + OCCDENP);
  k_occnum<<<128, 256, 0, stream>>>(EHB, VPH, SM + OCCRAW);
  k_kv<<<dim3(4, 128), 256, 0, stream>>>(KLH, VPH, EHB, SM + KLSUMP);
  k_fin2<<<307, 256, 0, stream>>>(EHB, XT + XT_KVT,
                                  SM + OCCRAW, SM + OCCDENP, SM + OCCB,
                                  SM + KLSUMP, SM + KLSUMR);
  k_gated<<<50, 256, 0, stream>>>(SM + OCCB, Wa, Wb, ba, bb, Wc, bc, SM + ACC50);

  k_tail<<<2048, 256, 0, stream>>>(QLH, XT + XT_KVT, SM + KLSUMR, VPH, dwcw, dwcb,
                                   XT + XT_WFAT, XT + XT_WFBT, SM + BFA, SM + BFB,
                                   Wc, bc, SM + H2TP, SM + H2DENP);

  k_final<<<1, 256, 0, stream>>>(SM + ACC50, SM + OCCB, SM + ASC, SM + OSCB,
                                 SM + W50P, SM + EDENP, SM + H2TP, SM + H2DENP,
                                 SM + VC, Wf, bf, W1, b1, W2, b2, W3a, b3a, W3b, b3b, outp);
}

// Round 9
// 512.774 us; speedup vs baseline: 1.1411x; 1.0304x over previous
//
#include <hip/hip_runtime.h>
#include <hip/hip_bf16.h>
#include <math.h>

// MixedAttentionLayer — R17:
//  - k_occnum merged into k_kv as cb==4 (A = Eh, epilogue = occraw atomics).
//    Race-safety: z-grid halved to 64 (1024 rows/block) so PP partials (8MB)
//    live in the upper half of B_E, disjoint from Eh (lower 8MB).
//  - k_fin2: kvred vectorized (ushort8, 32 blocks x 8 m-rows); occ gated()
//    fused into the occfin branch (k_gated launch deleted).
//  - Launch count 10 -> 8. k_path1/k_tail unchanged.

constexpr int DD = 256;
constexpr int MM = 50;
constexpr float SCL = 0.0625f; // 256^-0.5

// ---- byte offsets in d_ws ----
constexpr size_t B_VPH = 0;
constexpr size_t B_QLH = (size_t)32 << 20;
constexpr size_t B_KLH = (size_t)64 << 20;
constexpr size_t B_E   = (size_t)96 << 20;
constexpr size_t B_SM  = (size_t)112 << 20;
constexpr size_t B_X   = B_SM + ((size_t)2 << 20);

// shorts offset of PP partials within B_E region (upper 8MB, after Eh's 8MB)
constexpr size_t PP_OFF = (size_t)4 << 20;   // 4M shorts = 8MB

// ---- float offsets within SM region (zeroed part first) ----
constexpr size_t KLSUMR = 0;
constexpr size_t KLSUMP = 256;
constexpr size_t OCCDENP= 2304;
constexpr size_t W50P   = 2816;
constexpr size_t EDENP  = 3328;
constexpr size_t H2TP   = 3336;
constexpr size_t H2DENP = 5384;
constexpr size_t OCCRAW = 5392;
constexpr size_t ZEND   = 18192;
constexpr size_t QC     = ZEND;
constexpr size_t KC     = QC + 12800;
constexpr size_t VC     = KC + 12800;
constexpr size_t VCA    = VC + 12800;
constexpr size_t VCB    = VCA + 12800;
constexpr size_t WFA    = VCB + 12800;
constexpr size_t WFB    = WFA + 65536;
constexpr size_t BFA    = WFB + 65536;
constexpr size_t BFB    = BFA + 256;
constexpr size_t OSCB   = BFB + 256;
constexpr size_t OCCB   = OSCB + 12800;
constexpr size_t ASC    = OCCB + 12800;
constexpr size_t ACC50  = ASC + 64;
constexpr size_t SMEND  = ACC50 + 64;

// ---- short offsets within X region (all fragment-major) ----
constexpr size_t XT_WQKV = 0;          // 48t x 8k0 x 64 x 8 = 196608
constexpr size_t XT_WFAT = 196608;     // 16 x 8 x 64 x 8 = 65536
constexpr size_t XT_WFBT = 262144;
constexpr size_t XT_KVT  = 327680;     // 16 x 8 x 64 x 8
constexpr size_t XT_QCH  = 393216;     // 4 x 8 x 64 x 8 = 16384
constexpr size_t XT_KCH  = 409600;
constexpr size_t XT_VCAT = 425984;     // 16 x 2 x 64 x 8 = 16384
constexpr size_t XT_VCBT = 442368;
constexpr size_t XT_END  = 458752;
constexpr size_t WS_NEEDED = B_X + XT_END * 2;

typedef short bf16x8 __attribute__((ext_vector_type(8)));
typedef float f32x4 __attribute__((ext_vector_type(4)));

__device__ __forceinline__ float rcpf_(float x){ return __builtin_amdgcn_rcpf(x); }
__device__ __forceinline__ float fsig_(float x){ return rcpf_(1.0f + __expf(-x)); }
__device__ __forceinline__ float ftanh_(float x){ return 1.0f - 2.0f * rcpf_(__expf(2.0f * x) + 1.0f); }

__device__ __forceinline__ float bf2f(unsigned short u){
  return __uint_as_float(((unsigned int)u) << 16);
}
__device__ __forceinline__ unsigned short f2bf(float f){
  union { __hip_bfloat16 h; unsigned short u; } c;
  c.h = __float2bfloat16(f);
  return c.u;
}
__device__ __forceinline__ f32x4 mfma16(bf16x8 a, bf16x8 b, f32x4 c){
  return __builtin_amdgcn_mfma_f32_16x16x32_bf16(a, b, c, 0, 0, 0);
}

__device__ __forceinline__ float waveAllSum(float v){
  #pragma unroll
  for (int m = 1; m < 64; m <<= 1) v += __shfl_xor(v, m, 64);
  return v;
}

// fragment-major index helper
__device__ __forceinline__ size_t fragIdx(int n, int k, int K8){
  const int tile = n >> 4, cn = n & 15;
  const int k0 = k >> 5, kqi = (k >> 3) & 3, e = k & 7;
  return (((size_t)tile * K8 + k0) * 64 + (kqi * 16 + cn)) * 8 + e;
}

// k-major swizzled LDS offset for k_kv staging (shorts).
__device__ __forceinline__ int kvOff(int c, int k){
  return c * 40 + (c >> 3) * 8 + k;
}

// ---------- prep0: Wqkv^T frags (0..47) + qc/kc/vc (48..97) + Wf-weight part (98..611) ----------
__global__ void __launch_bounds__(256) k_prep0(const float* __restrict__ x, const float* __restrict__ Wqkv,
                                               float* qc, float* kc, float* vc,
                                               unsigned short* qch, unsigned short* kch,
                                               unsigned short* __restrict__ WT,
                                               const float* __restrict__ Wa, const float* __restrict__ Wb,
                                               const float* __restrict__ ba, const float* __restrict__ bb,
                                               const float* __restrict__ Wf, const float* __restrict__ bf,
                                               float* Wfa, float* Wfb, float* bfa, float* bfb,
                                               unsigned short* WfaTh, unsigned short* WfbTh){
  const int b = blockIdx.x, t = threadIdx.x;
  if (b < 48) {
    __shared__ unsigned short Tt[64][72];
    const int bn = b % 12, bk = b / 12;
    const int n0 = bn * 64, k0g = bk * 64;
    #pragma unroll
    for (int i = 0; i < 16; i++) {
      const int k_l = (t >> 6) + i * 4;
      const int n_l = t & 63;
      Tt[n_l][k_l] = f2bf(Wqkv[(size_t)(k0g + k_l) * 768 + n0 + n_l]);
    }
    __syncthreads();
    #pragma unroll
    for (int i = 0; i < 2; i++) {
      const int fr = t * 2 + i;
      const int t_l = fr >> 7;
      const int k0_l = (fr >> 6) & 1;
      const int lane_f = fr & 63;
      const int n_l = t_l * 16 + (lane_f & 15);
      const int k_l = k0_l * 32 + (lane_f >> 4) * 8;
      const int tg = (n0 >> 4) + t_l;
      const int k0gl = (k0g >> 5) + k0_l;
      bf16x8 v = *(const bf16x8*)&Tt[n_l][k_l];
      *(bf16x8*)&WT[(((size_t)tg * 8 + k0gl) * 64 + lane_f) * 8] = v;
    }
    return;
  }
  __shared__ float xs[256];
  const int j = t;
  if (b < 98) {
    const int r = b - 48;
    xs[j] = x[r * DD + j];
    __syncthreads();
    float aq = 0.f, ak = 0.f, av = 0.f;
    for (int k = 0; k < DD; k++) {
      float xv = xs[k];
      aq += xv * Wqkv[k * 768 + j];
      ak += xv * Wqkv[k * 768 + 256 + j];
      av += xv * Wqkv[k * 768 + 512 + j];
    }
    qc[r * DD + j] = aq; kc[r * DD + j] = ak; vc[r * DD + j] = av;
    qch[fragIdx(r, j, 8)] = f2bf(aq);
    kch[fragIdx(r, j, 8)] = f2bf(ak);
    if (r == 0) {
      for (int c = 50; c < 64; c++) {
        qch[fragIdx(c, j, 8)] = 0;
        kch[fragIdx(c, j, 8)] = 0;
      }
    }
    return;
  }
  const int bb2 = b - 98;
  const float* src; const float* Wm;
  if (bb2 < 256)      { src = Wf + bb2 * DD;         Wm = Wa; }
  else if (bb2 < 512) { src = Wf + (bb2 - 256) * DD; Wm = Wb; }
  else if (bb2 == 512){ src = bf;                    Wm = Wa; }
  else                { src = bf;                    Wm = Wb; }
  xs[j] = src[j];
  __syncthreads();
  float a = 0.f;
  for (int k = 0; k < DD; k++) a += xs[k] * Wm[k * DD + j];
  if (bb2 < 256)      { Wfa[bb2 * DD + j] = a; WfaTh[fragIdx(j, bb2, 8)] = f2bf(a); }
  else if (bb2 < 512) { Wfb[(bb2 - 256) * DD + j] = a; WfbTh[fragIdx(j, bb2 - 256, 8)] = f2bf(a); }
  else if (bb2 == 512) bfa[j] = a + ba[j];
  else bfb[j] = a + bb[j];
}

// ---------- prep1: Vca/Vcb (50 blocks, needs vc) ----------
__global__ void __launch_bounds__(256) k_prep1(const float* vc, const float* Wa, const float* Wb,
                                               float* Vca, float* Vcb,
                                               unsigned short* VcaTh, unsigned short* VcbTh){
  __shared__ float rs[256];
  const int b = blockIdx.x, j = threadIdx.x;
  const int r = b;
  rs[j] = vc[r * DD + j];
  __syncthreads();
  float a = 0.f, bv = 0.f;
  for (int k = 0; k < DD; k++) { float v = rs[k]; a += v * Wa[k * DD + j]; bv += v * Wb[k * DD + j]; }
  Vca[r * DD + j] = a; Vcb[r * DD + j] = bv;
  VcaTh[fragIdx(j, r, 2)] = f2bf(a);
  VcbTh[fragIdx(j, r, 2)] = f2bf(bv);
  if (r == 0) {
    for (int c = 50; c < 64; c++) {
      VcaTh[fragIdx(j, c, 2)] = 0;
      VcbTh[fragIdx(j, c, 2)] = 0;
    }
  }
}

// ---------- fused: osc row + gated(osc row) -> A_sc ----------
__global__ void __launch_bounds__(256) k_oscg(const float* __restrict__ qc, const float* __restrict__ kc,
                                              const float* __restrict__ vc,
                                              const float* __restrict__ Wa, const float* __restrict__ Wb,
                                              const float* __restrict__ ba, const float* __restrict__ bb,
                                              const float* __restrict__ Wc, const float* __restrict__ bc,
                                              float* __restrict__ osc, float* __restrict__ A){
  const int i = blockIdx.x, t = threadIdx.x;
  __shared__ float qs[256];
  __shared__ float P[64];
  __shared__ float red[4];
  qs[t] = qc[i * DD + t];
  __syncthreads();
  if (t < 64) {
    float s = -1e30f;
    if (t < 50) {
      float acc = 0.f;
      const float4* kr = (const float4*)&kc[t * DD];
      #pragma unroll 8
      for (int k = 0; k < 64; k++) {
        float4 kv = kr[k];
        float4 qv = *(const float4*)&qs[k * 4];
        acc += qv.x * kv.x + qv.y * kv.y + qv.z * kv.z + qv.w * kv.w;
      }
      s = acc * SCL;
    }
    float mx = s;
    #pragma unroll
    for (int m = 1; m < 64; m <<= 1) mx = fmaxf(mx, __shfl_xor(mx, m, 64));
    float e = (t < 50) ? __expf(s - mx) : 0.f;
    float den = waveAllSum(e);
    P[t] = e * rcpf_(den);
  }
  __syncthreads();
  float a = 0.f;
  for (int jj = 0; jj < 50; jj++) a += P[jj] * vc[jj * DD + t];
  osc[i * DD + t] = a;
  __syncthreads();
  qs[t] = a;
  __syncthreads();
  float u = 0.f, v = 0.f;
  for (int k = 0; k < DD; k++) { float tv = qs[k]; u += tv * Wa[k * DD + t]; v += tv * Wb[k * DD + t]; }
  float g = ftanh_(u + ba[t]) * fsig_(v + bb[t]) * Wc[t];
  g = waveAllSum(g);
  const int lane = t & 63, wv = t >> 6;
  if (lane == 0) red[wv] = g;
  __syncthreads();
  if (t == 0) A[i] = red[0] + red[1] + red[2] + red[3] + bc[0];
}

// ---------- fused path kernel: 32 rows/block, 38912 B arena ----------
__global__ void __launch_bounds__(256) k_path1(
    const float* __restrict__ x, const unsigned short* __restrict__ WTf,
    const float* __restrict__ sln,
    const unsigned short* __restrict__ kchf, const unsigned short* __restrict__ qchf,
    const unsigned short* __restrict__ VcaTf, const unsigned short* __restrict__ VcbTf,
    const float* __restrict__ ba, const float* __restrict__ bb,
    const float* __restrict__ Wc, const float* __restrict__ bc,
    unsigned short* __restrict__ vph, unsigned short* __restrict__ qlh, unsigned short* __restrict__ klh,
    unsigned short* __restrict__ Eh, float* __restrict__ w50p, float* __restrict__ edenp, float* __restrict__ occdenp){
  __shared__ __align__(16) char arena[38912];
  unsigned short (*Psh)[72]   = (unsigned short (*)[72])arena;
  float (*denp)[4]            = (float (*)[4])(arena + 4608);
  unsigned short (*qpsb)[264] = (unsigned short (*)[264])(arena + 5120);
  unsigned short (*kpsb)[264] = (unsigned short (*)[264])(arena + 22016);

  const int tid = threadIdx.x;
  const int i0 = blockIdx.x * 32;
  const int part = blockIdx.x & 7;
  const int lane = tid & 63;
  const int wvv = tid >> 6;
  const int cn = lane & 15;
  const int m0 = (lane >> 4) * 4;
  const int kq = (lane >> 4) * 8;

  for (int l = tid; l < 2048; l += 256) {
    const int r = l >> 6, c4 = (l & 63) * 4;
    const float4 xv = *(const float4*)&x[(size_t)(MM + i0 + r) * DD + c4];
    ushort4 o; o.x = f2bf(xv.x); o.y = f2bf(xv.y); o.z = f2bf(xv.z); o.w = f2bf(xv.w);
    *(ushort4*)&qpsb[r][c4] = o;
  }
  __syncthreads();

  bf16x8 af0[8], af1[8];
  #pragma unroll
  for (int k0 = 0; k0 < 8; k0++) {
    af0[k0] = *(const bf16x8*)&qpsb[cn][k0 * 32 + kq];
    af1[k0] = *(const bf16x8*)&qpsb[16 + cn][k0 * 32 + kq];
  }
  __syncthreads();

  // ---- GEMM: [32 x 256] @ [256 x 768]; each B fragment feeds 2 MFMAs ----
  bf16x8 b0[8], b1[8];
  {
    const unsigned short* Bt = WTf + ((size_t)wvv * 8 * 64 + lane) * 8;
    #pragma unroll
    for (int k0 = 0; k0 < 8; k0++) b0[k0] = *(const bf16x8*)&Bt[(size_t)k0 * 512];
  }
  #pragma unroll 1
  for (int tt = 0; tt < 12; tt++) {
    const int t = wvv + 4 * tt;
    if (tt + 1 < 12) {
      const unsigned short* Bt = WTf + (((size_t)(t + 4) * 8) * 64 + lane) * 8;
      #pragma unroll
      for (int k0 = 0; k0 < 8; k0++) b1[k0] = *(const bf16x8*)&Bt[(size_t)k0 * 512];
    }
    f32x4 acc0 = {0.f, 0.f, 0.f, 0.f};
    f32x4 acc1 = {0.f, 0.f, 0.f, 0.f};
    #pragma unroll
    for (int k0 = 0; k0 < 8; k0++) {
      acc0 = mfma16(af0[k0], b0[k0], acc0);
      acc1 = mfma16(af1[k0], b0[k0], acc1);
    }
    if (t < 16) {
      int c = t * 16 + cn;
      #pragma unroll
      for (int i = 0; i < 4; i++) {
        qpsb[m0 + i][c] = f2bf(acc0[i]);
        qpsb[16 + m0 + i][c] = f2bf(acc1[i]);
      }
    } else if (t < 32) {
      int c = (t - 16) * 16 + cn;
      #pragma unroll
      for (int i = 0; i < 4; i++) {
        kpsb[m0 + i][c] = f2bf(acc0[i]);
        kpsb[16 + m0 + i][c] = f2bf(acc1[i]);
      }
    } else {
      int c = (t - 32) * 16 + cn;
      #pragma unroll
      for (int i = 0; i < 4; i++) {
        vph[(size_t)(i0 + m0 + i) * DD + c] = f2bf(acc0[i]);
        vph[(size_t)(i0 + 16 + m0 + i) * DD + c] = f2bf(acc1[i]);
      }
    }
    #pragma unroll
    for (int k0 = 0; k0 < 8; k0++) b0[k0] = b1[k0];
  }
  __syncthreads();

  // ---- scores via MFMA; exp kept in regs; den partials via 16-lane reduce ----
  float ep0[4], ep1[4];
  {
    f32x4 accp0 = {0.f,0.f,0.f,0.f}, accp1 = {0.f,0.f,0.f,0.f};
    f32x4 accc0 = {0.f,0.f,0.f,0.f}, accc1 = {0.f,0.f,0.f,0.f};
    const unsigned short* Bk = kchf + ((size_t)wvv * 8 * 64 + lane) * 8;
    const unsigned short* Bq = qchf + ((size_t)wvv * 8 * 64 + lane) * 8;
    #pragma unroll
    for (int k0 = 0; k0 < 8; k0++) {
      bf16x8 aq0 = *(const bf16x8*)&qpsb[cn][k0 * 32 + kq];
      bf16x8 aq1 = *(const bf16x8*)&qpsb[16 + cn][k0 * 32 + kq];
      bf16x8 ak0 = *(const bf16x8*)&kpsb[cn][k0 * 32 + kq];
      bf16x8 ak1 = *(const bf16x8*)&kpsb[16 + cn][k0 * 32 + kq];
      bf16x8 bk = *(const bf16x8*)&Bk[(size_t)k0 * 512];
      bf16x8 bq = *(const bf16x8*)&Bq[(size_t)k0 * 512];
      accp0 = mfma16(aq0, bk, accp0);
      accp1 = mfma16(aq1, bk, accp1);
      accc0 = mfma16(ak0, bq, accc0);
      accc1 = mfma16(ak1, bq, accc1);
    }
    const int col = wvv * 16 + cn;
    const bool ok = (col < 50);
    #pragma unroll
    for (int i = 0; i < 4; i++) {
      ep0[i] = ok ? __expf(accp0[i] * SCL) : 0.f;
      ep1[i] = ok ? __expf(accp1[i] * SCL) : 0.f;
    }
    float osum = 0.f;
    #pragma unroll
    for (int i = 0; i < 4; i++) {
      unsigned short h0 = ok ? f2bf(__expf(accc0[i] * SCL)) : (unsigned short)0;
      unsigned short h1 = ok ? f2bf(__expf(accc1[i] * SCL)) : (unsigned short)0;
      Eh[(size_t)(i0 + m0 + i) * 64 + col] = h0;
      Eh[(size_t)(i0 + 16 + m0 + i) * 64 + col] = h1;
      if (ok) osum += bf2f(h0) + bf2f(h1);
    }
    osum += __shfl_xor(osum, 16, 64);
    osum += __shfl_xor(osum, 32, 64);
    if (lane < 16 && ok) atomicAdd(&occdenp[part * 64 + col], osum);
    float d0[4], d1[4];
    #pragma unroll
    for (int i = 0; i < 4; i++) { d0[i] = ep0[i]; d1[i] = ep1[i]; }
    #pragma unroll
    for (int m = 1; m < 16; m <<= 1) {
      #pragma unroll
      for (int i = 0; i < 4; i++) {
        d0[i] += __shfl_xor(d0[i], m, 64);
        d1[i] += __shfl_xor(d1[i], m, 64);
      }
    }
    if (cn == 0) {
      #pragma unroll
      for (int i = 0; i < 4; i++) {
        denp[m0 + i][wvv] = d0[i];
        denp[16 + m0 + i][wvv] = d1[i];
      }
    }
  }
  __syncthreads();

  // ---- normalize P from regs -> Psh (fragment-ready layout) ----
  {
    const int col = wvv * 16 + cn;
    #pragma unroll
    for (int i = 0; i < 4; i++) {
      float4 dp = *(const float4*)&denp[m0 + i][0];
      Psh[m0 + i][col] = f2bf(ep0[i] * rcpf_(dp.x + dp.y + dp.z + dp.w));
      float4 dq = *(const float4*)&denp[16 + m0 + i][0];
      Psh[16 + m0 + i][col] = f2bf(ep1[i] * rcpf_(dq.x + dq.y + dq.z + dq.w));
    }
  }

  // ---- phase B: transforms (8 rows per wave) ----
  float4 sl4 = ((const float4*)sln)[lane];
  float4 rsp;
  rsp.x = rcpf_(log1pf(expf(sl4.x))); rsp.y = rcpf_(log1pf(expf(sl4.y)));
  rsp.z = rcpf_(log1pf(expf(sl4.z))); rsp.w = rcpf_(log1pf(expf(sl4.w)));
  float4 ba4 = ((const float4*)ba)[lane];
  float4 bb4 = ((const float4*)bb)[lane];
  float4 wc4 = ((const float4*)Wc)[lane];
  float bcv = bc[0];
  for (int rr = 0; rr < 8; rr++) {
    const int r = wvv * 8 + rr;
    const int row = i0 + r;
    ushort4 qu = *(const ushort4*)&qpsb[r][lane * 4];
    ushort4 ku = *(const ushort4*)&kpsb[r][lane * 4];
    float4 q4 = {bf2f(qu.x), bf2f(qu.y), bf2f(qu.z), bf2f(qu.w)};
    float4 k4 = {bf2f(ku.x), bf2f(ku.y), bf2f(ku.z), bf2f(ku.w)};
    float4 lq, lk;
    lq.x = (fmaxf(q4.x, 0.f) + 1e-6f) * rsp.x; lq.y = (fmaxf(q4.y, 0.f) + 1e-6f) * rsp.y;
    lq.z = (fmaxf(q4.z, 0.f) + 1e-6f) * rsp.z; lq.w = (fmaxf(q4.w, 0.f) + 1e-6f) * rsp.w;
    lk.x = (fmaxf(k4.x, 0.f) + 1e-6f) * rsp.x; lk.y = (fmaxf(k4.y, 0.f) + 1e-6f) * rsp.y;
    lk.z = (fmaxf(k4.z, 0.f) + 1e-6f) * rsp.z; lk.w = (fmaxf(k4.w, 0.f) + 1e-6f) * rsp.w;
    float4 q3, k3;
    q3.x = lq.x*lq.x*lq.x; q3.y = lq.y*lq.y*lq.y; q3.z = lq.z*lq.z*lq.z; q3.w = lq.w*lq.w*lq.w;
    k3.x = lk.x*lk.x*lk.x; k3.y = lk.y*lk.y*lk.y; k3.z = lk.z*lk.z*lk.z; k3.w = lk.w*lk.w*lk.w;
    float n1q = lq.x*lq.x + lq.y*lq.y + lq.z*lq.z + lq.w*lq.w;
    float n3q = q3.x*q3.x + q3.y*q3.y + q3.z*q3.z + q3.w*q3.w;
    float n1k = lk.x*lk.x + lk.y*lk.y + lk.z*lk.z + lk.w*lk.w;
    float n3k = k3.x*k3.x + k3.y*k3.y + k3.z*k3.z + k3.w*k3.w;
    n1q = waveAllSum(n1q); n3q = waveAllSum(n3q);
    n1k = waveAllSum(n1k); n3k = waveAllSum(n3k);
    float fq = sqrtf(n1q * rcpf_(n3q));
    float fk = sqrtf(n1k * rcpf_(n3k));
    ushort4 qo, ko;
    qo.x = f2bf(q3.x * fq); qo.y = f2bf(q3.y * fq); qo.z = f2bf(q3.z * fq); qo.w = f2bf(q3.w * fq);
    ko.x = f2bf(k3.x * fk); ko.y = f2bf(k3.y * fk); ko.z = f2bf(k3.z * fk); ko.w = f2bf(k3.w * fk);
    *(ushort4*)&qlh[(size_t)row * DD + lane * 4] = qo;
    *(ushort4*)&klh[(size_t)row * DD + lane * 4] = ko;
  }
  __syncthreads();

  // ---- gate via MFMA: u = P@Vca, v = P@Vcb (fragment-major B, K8=2) ----
  {
    bf16x8 ap0[2], ap1[2];
    #pragma unroll
    for (int k0 = 0; k0 < 2; k0++) {
      ap0[k0] = *(const bf16x8*)&Psh[cn][k0 * 32 + kq];
      ap1[k0] = *(const bf16x8*)&Psh[16 + cn][k0 * 32 + kq];
    }
    #pragma unroll 1
    for (int tt = 0; tt < 4; tt++) {
      const int nt = wvv * 4 + tt;
      const unsigned short* Bu = VcaTf + (((size_t)nt * 2) * 64 + lane) * 8;
      const unsigned short* Bv = VcbTf + (((size_t)nt * 2) * 64 + lane) * 8;
      f32x4 au0 = {0.f,0.f,0.f,0.f}, au1 = {0.f,0.f,0.f,0.f};
      f32x4 av0 = {0.f,0.f,0.f,0.f}, av1 = {0.f,0.f,0.f,0.f};
      #pragma unroll
      for (int k0 = 0; k0 < 2; k0++) {
        bf16x8 bu = *(const bf16x8*)&Bu[(size_t)k0 * 512];
        bf16x8 bv = *(const bf16x8*)&Bv[(size_t)k0 * 512];
        au0 = mfma16(ap0[k0], bu, au0);
        au1 = mfma16(ap1[k0], bu, au1);
        av0 = mfma16(ap0[k0], bv, av0);
        av1 = mfma16(ap1[k0], bv, av1);
      }
      #pragma unroll
      for (int i = 0; i < 4; i++) {
        qpsb[m0 + i][nt * 16 + cn] = f2bf(au0[i]);
        qpsb[16 + m0 + i][nt * 16 + cn] = f2bf(au1[i]);
        kpsb[m0 + i][nt * 16 + cn] = f2bf(av0[i]);
        kpsb[16 + m0 + i][nt * 16 + cn] = f2bf(av1[i]);
      }
    }
  }
  __syncthreads();

  // ---- gate eval; exp(g) stored in Psh row padding ----
  #pragma unroll
  for (int rr = 0; rr < 8; rr++) {
    const int r = wvv * 8 + rr;
    ushort4 uu = *(const ushort4*)&qpsb[r][lane * 4];
    ushort4 vv = *(const ushort4*)&kpsb[r][lane * 4];
    float g = ftanh_(bf2f(uu.x) + ba4.x) * fsig_(bf2f(vv.x) + bb4.x) * wc4.x
            + ftanh_(bf2f(uu.y) + ba4.y) * fsig_(bf2f(vv.y) + bb4.y) * wc4.y
            + ftanh_(bf2f(uu.z) + ba4.z) * fsig_(bf2f(vv.z) + bb4.z) * wc4.z
            + ftanh_(bf2f(uu.w) + ba4.w) * fsig_(bf2f(vv.w) + bb4.w) * wc4.w;
    g = waveAllSum(g);
    if (lane == 0) *(float*)&Psh[r][64] = __expf(g + bcv);
  }
  __syncthreads();
  if (tid < 64) {
    float s = 0.f;
    #pragma unroll
    for (int r = 0; r < 32; r++) s += *(const float*)&Psh[r][64] * bf2f(Psh[r][tid]);
    atomicAdd(&w50p[part * 64 + tid], s);
  }
  if (tid == 0) {
    float es = 0.f;
    #pragma unroll
    for (int r = 0; r < 32; r++) es += *(const float*)&Psh[r][64];
    atomicAdd(&edenp[part], es);
  }
}

// ---------- kv + occnum merged: grid (5, 64) ----------
// cb<4:  P[cb] partials = klh[:,cb*64..]^T @ vph  (+ klsum via ones)
// cb==4: occraw += Eh^T @ vph (atomics; rows<50)
// Each block handles 1024 rows (32 steps). PP (8MB) is disjoint from Eh (8MB).
__global__ void __launch_bounds__(256) k_kv(const unsigned short* __restrict__ klh,
                                            const unsigned short* __restrict__ Eh,
                                            const unsigned short* __restrict__ vph,
                                            unsigned short* __restrict__ PP,
                                            float* __restrict__ klsump,
                                            float* __restrict__ occraw){
  __shared__ __align__(16) unsigned short AT[2608];
  __shared__ __align__(16) unsigned short BvpT[10480];
  const int tid = threadIdx.x;
  const int lane = tid & 63;
  const int wvv = tid >> 6;
  const int cn = lane & 15;
  const int m0 = (lane >> 4) * 4;
  const int kq = (lane >> 4) * 8;
  const int cb = blockIdx.x;
  const int z  = blockIdx.y;
  const int jj = tid >> 3;
  const int c8 = (tid & 7) * 8;
  const bool isOcc = (cb == 4);

  f32x4 acc[4][4];
  f32x4 acc1[4];
  #pragma unroll
  for (int mt = 0; mt < 4; mt++) {
    acc1[mt] = (f32x4){0.f,0.f,0.f,0.f};
    #pragma unroll
    for (int tl = 0; tl < 4; tl++) acc[mt][tl] = (f32x4){0.f,0.f,0.f,0.f};
  }
  bf16x8 ones;
  #pragma unroll
  for (int i = 0; i < 8; i++) ones[i] = (short)0x3F80;

  const int jbase = z * 1024;
  #pragma unroll 1
  for (int step = 0; step < 32; step++) {
    const int j0 = jbase + step * 32;
    {
      bf16x8 av;
      if (isOcc) av = *(const bf16x8*)&Eh[(size_t)(j0 + jj) * 64 + c8];
      else       av = *(const bf16x8*)&klh[(size_t)(j0 + jj) * 256 + cb * 64 + c8];
      #pragma unroll
      for (int i = 0; i < 8; i++) AT[kvOff(c8 + i, jj)] = (unsigned short)av[i];
      #pragma unroll
      for (int rep = 0; rep < 4; rep++) {
        bf16x8 bv = *(const bf16x8*)&vph[(size_t)(j0 + jj) * 256 + rep * 64 + c8];
        #pragma unroll
        for (int i = 0; i < 8; i++) BvpT[kvOff(rep * 64 + c8 + i, jj)] = (unsigned short)bv[i];
      }
    }
    __syncthreads();
    bf16x8 afr[4], bfr[4];
    #pragma unroll
    for (int mt = 0; mt < 4; mt++)
      afr[mt] = *(const bf16x8*)&AT[kvOff(cn + mt * 16, kq)];
    #pragma unroll
    for (int tl = 0; tl < 4; tl++)
      bfr[tl] = *(const bf16x8*)&BvpT[kvOff(wvv * 64 + tl * 16 + cn, kq)];
    if (!isOcc) {
      #pragma unroll
      for (int mt = 0; mt < 4; mt++) acc1[mt] = mfma16(afr[mt], ones, acc1[mt]);
    }
    #pragma unroll
    for (int mt = 0; mt < 4; mt++)
      #pragma unroll
      for (int tl = 0; tl < 4; tl++) acc[mt][tl] = mfma16(afr[mt], bfr[tl], acc[mt][tl]);
    __syncthreads();
  }
  if (isOcc) {
    #pragma unroll
    for (int mt = 0; mt < 4; mt++)
      #pragma unroll
      for (int i = 0; i < 4; i++) {
        const int ri = mt * 16 + m0 + i;
        if (ri < 50) {
          #pragma unroll
          for (int tl = 0; tl < 4; tl++) {
            const int d = wvv * 64 + tl * 16 + cn;
            atomicAdd(&occraw[ri * DD + d], acc[mt][tl][i]);
          }
        }
      }
    return;
  }
  unsigned short* P = PP + ((size_t)(cb * 64 + z)) * 16384;
  #pragma unroll
  for (int mt = 0; mt < 4; mt++)
    #pragma unroll
    for (int tl = 0; tl < 4; tl++) {
      const int n = (wvv * 4 + tl) * 16 + cn;
      #pragma unroll
      for (int i = 0; i < 4; i++)
        P[(size_t)(mt * 16 + m0 + i) * 256 + n] = f2bf(acc[mt][tl][i]);
    }
  if (wvv == 0 && cn == 0) {
    #pragma unroll
    for (int mt = 0; mt < 4; mt++)
      #pragma unroll
      for (int i = 0; i < 4; i++)
        atomicAdd(&klsump[(z & 7) * 256 + cb * 64 + mt * 16 + m0 + i], acc1[mt][i]);
  }
}

// ---------- merged: kvred (0..31, ushort8) + occfin+gated (32..81) + klsum (82) ----------
__global__ void __launch_bounds__(256) k_fin2(const unsigned short* __restrict__ PP,
                                              unsigned short* __restrict__ kvTf,
                                              const float* __restrict__ occraw,
                                              const float* __restrict__ occdenp,
                                              float* __restrict__ occ,
                                              const float* __restrict__ klsump,
                                              float* __restrict__ klsum,
                                              const float* __restrict__ Wa, const float* __restrict__ Wb,
                                              const float* __restrict__ ba, const float* __restrict__ bb,
                                              const float* __restrict__ Wc, const float* __restrict__ bc,
                                              float* __restrict__ A){
  __shared__ float ts[256];
  __shared__ float red[4];
  const int b = blockIdx.x, tid = threadIdx.x;
  if (b < 32) {
    const int gm = b * 8 + (tid >> 5);          // 0..255: cb*64+m
    const int cb = gm >> 6, m = gm & 63;
    const int d8 = (tid & 31) * 8;
    float s[8];
    #pragma unroll
    for (int e = 0; e < 8; e++) s[e] = 0.f;
    for (int z = 0; z < 64; z++) {
      bf16x8 v = *(const bf16x8*)&PP[((size_t)(cb * 64 + z)) * 16384 + (size_t)m * 256 + d8];
      #pragma unroll
      for (int e = 0; e < 8; e++) s[e] += bf2f((unsigned short)v[e]);
    }
    #pragma unroll
    for (int e = 0; e < 8; e++)
      kvTf[fragIdx(d8 + e, gm, 8)] = f2bf(s[e]);
  } else if (b < 82) {
    const int i = b - 32, j = tid;
    float den = 0.f;
    #pragma unroll
    for (int p = 0; p < 8; p++) den += occdenp[p * 64 + i];
    float t = occraw[i * DD + j] / den;
    occ[i * DD + j] = t;
    ts[j] = t;
    __syncthreads();
    float u = 0.f, v = 0.f;
    for (int k = 0; k < DD; k++) { float tv = ts[k]; u += tv * Wa[k * DD + j]; v += tv * Wb[k * DD + j]; }
    float g = ftanh_(u + ba[j]) * fsig_(v + bb[j]) * Wc[j];
    g = waveAllSum(g);
    const int lane = j & 63, wv = j >> 6;
    if (lane == 0) red[wv] = g;
    __syncthreads();
    if (j == 0) A[i] = red[0] + red[1] + red[2] + red[3] + bc[0];
  } else {
    const int d = tid;
    float s = 0.f;
    #pragma unroll
    for (int p = 0; p < 8; p++) s += klsump[p * 256 + d];
    klsum[d] = s;
  }
}

// ---------- fused tail: 32 rows/block (R12 form) ----------
__global__ void __launch_bounds__(256) k_tail(const unsigned short* __restrict__ qlh,
                                              const unsigned short* __restrict__ kvTf,
                                              const float* __restrict__ klsum,
                                              const unsigned short* __restrict__ vph,
                                              const float* __restrict__ dwcw, const float* __restrict__ dwcb,
                                              const unsigned short* __restrict__ WfaTf,
                                              const unsigned short* __restrict__ WfbTf,
                                              const float* __restrict__ bfa, const float* __restrict__ bfb,
                                              const float* __restrict__ Wc, const float* __restrict__ bc,
                                              float* __restrict__ h2tp, float* __restrict__ h2denp){
  __shared__ unsigned short Tsh[32][264];
  __shared__ unsigned short OSb[32][264];
  __shared__ unsigned short aVb[32][264];
  __shared__ float zf[32];
  __shared__ float ev[32];
  const int tid = threadIdx.x;
  const int i0 = blockIdx.x * 32;
  const int part = blockIdx.x & 7;
  const int lane = tid & 63;
  const int wvv = tid >> 6;
  const int cn = lane & 15;
  const int m0 = (lane >> 4) * 4;
  const int kq = (lane >> 4) * 8;
  for (int l = tid; l < 2048; l += 256) {
    int r = l >> 6, c4 = (l & 63) * 4;
    *(ushort4*)&Tsh[r][c4] = *(const ushort4*)&qlh[(size_t)(i0 + r) * DD + c4];
  }
  __syncthreads();
  // ---- OS = ql @ kv (each B fragment feeds 2 MFMAs) ----
  {
    bf16x8 afq0[8], afq1[8];
    #pragma unroll
    for (int k0 = 0; k0 < 8; k0++) {
      afq0[k0] = *(const bf16x8*)&Tsh[cn][k0 * 32 + kq];
      afq1[k0] = *(const bf16x8*)&Tsh[16 + cn][k0 * 32 + kq];
    }
    #pragma unroll 1
    for (int tt = 0; tt < 4; tt++) {
      const int nt = wvv * 4 + tt;
      const unsigned short* Bt = kvTf + (((size_t)nt * 8) * 64 + lane) * 8;
      f32x4 acc0 = {0.f,0.f,0.f,0.f};
      f32x4 acc1 = {0.f,0.f,0.f,0.f};
      #pragma unroll
      for (int k0 = 0; k0 < 8; k0++) {
        bf16x8 b = *(const bf16x8*)&Bt[(size_t)k0 * 512];
        acc0 = mfma16(afq0[k0], b, acc0);
        acc1 = mfma16(afq1[k0], b, acc1);
      }
      #pragma unroll
      for (int i = 0; i < 4; i++) {
        OSb[m0 + i][nt * 16 + cn] = f2bf(acc0[i]);
        OSb[16 + m0 + i][nt * 16 + cn] = f2bf(acc1[i]);
      }
    }
  }
  // ---- zf (8 rows per wave) ----
  {
    float4 ks4 = ((const float4*)klsum)[lane];
    #pragma unroll
    for (int rr = 0; rr < 8; rr++) {
      const int r = wvv * 8 + rr;
      ushort4 q4 = *(const ushort4*)&Tsh[r][lane * 4];
      float s = bf2f(q4.x)*ks4.x + bf2f(q4.y)*ks4.y + bf2f(q4.z)*ks4.z + bf2f(q4.w)*ks4.w;
      s = waveAllSum(s);
      if (lane == 0) zf[r] = rcpf_(s + 1e-6f);
    }
  }
  __syncthreads();
  // ---- depthwise conv, 32 rows; Tf stored in-place into fm[] ----
  const int j = tid;
  float w[25];
  #pragma unroll
  for (int t = 0; t < 25; t++) w[t] = dwcw[j * 25 + t];
  const float bias = dwcb[j];
  const int y = i0 >> 8, x0 = i0 & 255;
  float fm[32];
  #pragma unroll
  for (int r = 0; r < 32; r++) fm[r] = bias;
  #pragma unroll
  for (int dy = -2; dy <= 2; dy++) {
    const int yy = y + dy;
    if ((unsigned)yy > 255u) continue;
    float buf[36];
    #pragma unroll
    for (int i = 0; i < 36; i++) {
      const int xx = x0 - 2 + i;
      buf[i] = ((unsigned)xx <= 255u) ? bf2f(vph[(size_t)((yy << 8) + xx) * DD + j]) : 0.f;
    }
    const float* wr = &w[(dy + 2) * 5];
    #pragma unroll
    for (int r = 0; r < 32; r++)
      fm[r] += buf[r] * wr[0] + buf[r+1] * wr[1] + buf[r+2] * wr[2]
             + buf[r+3] * wr[3] + buf[r+4] * wr[4];
  }
  #pragma unroll
  for (int r = 0; r < 32; r++) {
    fm[r] = bf2f(OSb[r][j]) * zf[r] + fm[r];   // Tf in place
    Tsh[r][j] = f2bf(fm[r]);
  }
  __syncthreads();
  // ---- u = T@Wfa, v = T@Wfb (each B fragment feeds 2 MFMAs) ----
  {
    bf16x8 aft0[8], aft1[8];
    #pragma unroll
    for (int k0 = 0; k0 < 8; k0++) {
      aft0[k0] = *(const bf16x8*)&Tsh[cn][k0 * 32 + kq];
      aft1[k0] = *(const bf16x8*)&Tsh[16 + cn][k0 * 32 + kq];
    }
    #pragma unroll 1
    for (int jb = 0; jb < 8; jb++) {
      const int nt = wvv * 4 + (jb & 3);
      const unsigned short* Bt = ((jb < 4) ? WfaTf : WfbTf) + (((size_t)nt * 8) * 64 + lane) * 8;
      f32x4 acc0 = {0.f,0.f,0.f,0.f};
      f32x4 acc1 = {0.f,0.f,0.f,0.f};
      #pragma unroll
      for (int k0 = 0; k0 < 8; k0++) {
        bf16x8 b = *(const bf16x8*)&Bt[(size_t)k0 * 512];
        acc0 = mfma16(aft0[k0], b, acc0);
        acc1 = mfma16(aft1[k0], b, acc1);
      }
      unsigned short (*dst)[264] = (jb < 4) ? OSb : aVb;
      #pragma unroll
      for (int i = 0; i < 4; i++) {
        dst[m0 + i][nt * 16 + cn] = f2bf(acc0[i]);
        dst[16 + m0 + i][nt * 16 + cn] = f2bf(acc1[i]);
      }
    }
  }
  __syncthreads();
  // ---- gate eval (8 rows per wave) ----
  {
    float4 bfa4 = ((const float4*)bfa)[lane];
    float4 bfb4 = ((const float4*)bfb)[lane];
    float4 wc4 = ((const float4*)Wc)[lane];
    const float bcv = bc[0];
    #pragma unroll
    for (int rr = 0; rr < 8; rr++) {
      const int r = wvv * 8 + rr;
      ushort4 uu = *(const ushort4*)&OSb[r][lane * 4];
      ushort4 vv = *(const ushort4*)&aVb[r][lane * 4];
      float g = ftanh_(bf2f(uu.x) + bfa4.x) * fsig_(bf2f(vv.x) + bfb4.x) * wc4.x
              + ftanh_(bf2f(uu.y) + bfa4.y) * fsig_(bf2f(vv.y) + bfb4.y) * wc4.y
              + ftanh_(bf2f(uu.z) + bfa4.z) * fsig_(bf2f(vv.z) + bfb4.z) * wc4.z
              + ftanh_(bf2f(uu.w) + bfa4.w) * fsig_(bf2f(vv.w) + bfb4.w) * wc4.w;
      g = waveAllSum(g);
      if (lane == 0) ev[r] = __expf(g + bcv);
    }
  }
  __syncthreads();
  float hp = 0.f;
  #pragma unroll
  for (int r = 0; r < 32; r++) hp += ev[r] * fm[r];
  atomicAdd(&h2tp[part * 256 + j], hp);
  if (tid == 0) {
    float es = 0.f;
    #pragma unroll
    for (int r = 0; r < 32; r++) es += ev[r];
    atomicAdd(&h2denp[part], es);
  }
}

// ---------- final tiny MLPs ----------
__global__ void __launch_bounds__(256) k_final(
    const float* __restrict__ A_cc, const float* __restrict__ occ,
    const float* __restrict__ A_sc, const float* __restrict__ osc,
    const float* __restrict__ w50p, const float* __restrict__ edenp,
    const float* __restrict__ h2tp, const float* __restrict__ h2denp,
    const float* __restrict__ vc, const float* __restrict__ Wf, const float* __restrict__ bf,
    const float* __restrict__ W1, const float* __restrict__ b1,
    const float* __restrict__ W2, const float* __restrict__ b2,
    const float* __restrict__ W3a, const float* __restrict__ b3a,
    const float* __restrict__ W3b, const float* __restrict__ b3b,
    float* __restrict__ out){
  int j = threadIdx.x;
  __shared__ float pw[64];
  __shared__ float w50t[64];
  __shared__ float t1[256], t2[256], h1[256], h2[256], fz[512], z1[256];
  if (j < 64) {
    float s = 0.f;
    #pragma unroll
    for (int p = 0; p < 8; p++) s += w50p[p * 64 + j];
    w50t[j] = s;
  }
  float edentot = 0.f, h2dentot = 0.f;
  #pragma unroll
  for (int p = 0; p < 8; p++) { edentot += edenp[p]; h2dentot += h2denp[p]; }
  // ===== CROSS =====
  if (j < 64) pw[j] = (j < 50) ? expf(A_cc[j]) : 0.f;
  __syncthreads();
  float den = 0.f;
  for (int i = 0; i < 50; i++) den += pw[i];
  float raw = 0.f;
  for (int i = 0; i < 50; i++) raw += pw[i] * occ[i * DD + j];
  t1[j] = raw / den;
  float r2 = 0.f;
  for (int i = 0; i < 50; i++) r2 += w50t[i] * vc[i * DD + j];
  t2[j] = r2 / edentot;
  __syncthreads();
  float a1 = 0.f, a2 = 0.f;
  for (int k = 0; k < DD; k++) { a1 += t1[k] * W1[k * DD + j]; a2 += t2[k] * W2[k * DD + j]; }
  h1[j] = fmaxf(a1 + b1[j], 0.f);
  h2[j] = fmaxf(a2 + b2[j], 0.f);
  __syncthreads();
  fz[j] = h1[j]; fz[256 + j] = h2[j];
  __syncthreads();
  float z = 0.f;
  for (int k = 0; k < 512; k++) z += fz[k] * W3a[k * DD + j];
  z1[j] = fmaxf(z + b3a[j], 0.f);
  __syncthreads();
  float o = 0.f;
  for (int k = 0; k < DD; k++) o += z1[k] * W3b[k * DD + j];
  out[j] = fmaxf(o + b3b[j], 0.f);
  __syncthreads();
  // ===== SELF =====
  if (j < 64) pw[j] = (j < 50) ? expf(A_sc[j]) : 0.f;
  __syncthreads();
  den = 0.f;
  for (int i = 0; i < 50; i++) den += pw[i];
  raw = 0.f;
  for (int i = 0; i < 50; i++) raw += pw[i] * osc[i * DD + j];
  t1[j] = raw / den;
  {
    float s = 0.f;
    #pragma unroll
    for (int p = 0; p < 8; p++) s += h2tp[p * 256 + j];
    t2[j] = s / h2dentot;
  }
  __syncthreads();
  float hs = 0.f;
  for (int k = 0; k < DD; k++) hs += t2[k] * Wf[k * DD + j];
  __syncthreads();
  t2[j] = hs + bf[j];
  __syncthreads();
  a1 = 0.f; a2 = 0.f;
  for (int k = 0; k < DD; k++) { a1 += t1[k] * W1[k * DD + j]; a2 += t2[k] * W2[k * DD + j]; }
  h1[j] = fmaxf(a1 + b1[j], 0.f);
  h2[j] = fmaxf(a2 + b2[j], 0.f);
  __syncthreads();
  fz[j] = h1[j]; fz[256 + j] = h2[j];
  __syncthreads();
  z = 0.f;
  for (int k = 0; k < 512; k++) z += fz[k] * W3a[k * DD + j];
  z1[j] = fmaxf(z + b3a[j], 0.f);
  __syncthreads();
  o = 0.f;
  for (int k = 0; k < DD; k++) o += z1[k] * W3b[k * DD + j];
  out[256 + j] = fmaxf(o + b3b[j], 0.f);
}

extern "C" void kernel_launch(void* const* d_in, const int* in_sizes, int n_in,
                              void* d_out, int out_size, void* d_ws, size_t ws_size,
                              hipStream_t stream) {
  if (ws_size < WS_NEEDED) return;
  const float* x   = (const float*)d_in[0];
  const float* Wqkv= (const float*)d_in[1];
  const float* sln = (const float*)d_in[2];
  const float* dwcw= (const float*)d_in[3];
  const float* dwcb= (const float*)d_in[4];
  const float* Wa  = (const float*)d_in[5];
  const float* ba  = (const float*)d_in[6];
  const float* Wb  = (const float*)d_in[7];
  const float* bb  = (const float*)d_in[8];
  const float* Wc  = (const float*)d_in[9];
  const float* bc  = (const float*)d_in[10];
  const float* W1  = (const float*)d_in[11];
  const float* b1  = (const float*)d_in[12];
  const float* W2  = (const float*)d_in[13];
  const float* b2  = (const float*)d_in[14];
  const float* W3a = (const float*)d_in[15];
  const float* b3a = (const float*)d_in[16];
  const float* W3b = (const float*)d_in[17];
  const float* b3b = (const float*)d_in[18];
  const float* Wf  = (const float*)d_in[19];
  const float* bf  = (const float*)d_in[20];

  char* wsb = (char*)d_ws;
  unsigned short* VPH = (unsigned short*)(wsb + B_VPH);
  unsigned short* QLH = (unsigned short*)(wsb + B_QLH);
  unsigned short* KLH = (unsigned short*)(wsb + B_KLH);
  unsigned short* EHB = (unsigned short*)(wsb + B_E);
  unsigned short* PPB = EHB + PP_OFF;
  float* SM = (float*)(wsb + B_SM);
  unsigned short* XT = (unsigned short*)(wsb + B_X);
  float* outp = (float*)d_out;

  hipMemsetAsync((void*)SM, 0, ZEND * sizeof(float), stream);

  k_prep0<<<612, 256, 0, stream>>>(x, Wqkv, SM + QC, SM + KC, SM + VC,
                                   XT + XT_QCH, XT + XT_KCH, XT + XT_WQKV,
                                   Wa, Wb, ba, bb, Wf, bf,
                                   SM + WFA, SM + WFB, SM + BFA, SM + BFB,
                                   XT + XT_WFAT, XT + XT_WFBT);
  k_prep1<<<50, 256, 0, stream>>>(SM + VC, Wa, Wb,
                                  SM + VCA, SM + VCB, XT + XT_VCAT, XT + XT_VCBT);
  k_oscg<<<50, 256, 0, stream>>>(SM + QC, SM + KC, SM + VC, Wa, Wb, ba, bb, Wc, bc,
                                 SM + OSCB, SM + ASC);

  k_path1<<<2048, 256, 0, stream>>>(x, XT + XT_WQKV, sln, XT + XT_KCH, XT + XT_QCH,
                                    XT + XT_VCAT, XT + XT_VCBT, ba, bb, Wc, bc,
                                    VPH, QLH, KLH, EHB, SM + W50P, SM + EDENP, SM + OCCDENP);
  k_kv<<<dim3(5, 64), 256, 0, stream>>>(KLH, EHB, VPH, PPB, SM + KLSUMP, SM + OCCRAW);
  k_fin2<<<83, 256, 0, stream>>>(PPB, XT + XT_KVT,
                                 SM + OCCRAW, SM + OCCDENP, SM + OCCB,
                                 SM + KLSUMP, SM + KLSUMR,
                                 Wa, Wb, ba, bb, Wc, bc, SM + ACC50);

  k_tail<<<2048, 256, 0, stream>>>(QLH, XT + XT_KVT, SM + KLSUMR, VPH, dwcw, dwcb,
                                   XT + XT_WFAT, XT + XT_WFBT, SM + BFA, SM + BFB,
                                   Wc, bc, SM + H2TP, SM + H2DENP);

  k_final<<<1, 256, 0, stream>>>(SM + ACC50, SM + OCCB, SM + ASC, SM + OSCB,
                                 SM + W50P, SM + EDENP, SM + H2TP, SM + H2DENP,
                                 SM + VC, Wf, bf, W1, b1, W2, b2, W3a, b3a, W3b, b3b, outp);
}

// Round 10
// 469.687 us; speedup vs baseline: 1.2457x; 1.0917x over previous
//
#include <hip/hip_runtime.h>
#include <hip/hip_bf16.h>
#include <math.h>

// MixedAttentionLayer — R18:
//  - k_kv: double-buffered LDS staging, ONE barrier per step (was 2) —
//    step s reads buf[s&1] while regs for s+1 load and buf[(s+1)&1] is
//    written; global-load latency now hides under MFMA.
//  - k_final split into 2 independent blocks (CROSS / SELF output halves).
//  - prep1 + oscg fused into one 100-block launch (both depend only on prep0).
//  - k_path1 / k_tail / fin2 unchanged.

constexpr int DD = 256;
constexpr int MM = 50;
constexpr float SCL = 0.0625f; // 256^-0.5

// ---- byte offsets in d_ws ----
constexpr size_t B_VPH = 0;
constexpr size_t B_QLH = (size_t)32 << 20;
constexpr size_t B_KLH = (size_t)64 << 20;
constexpr size_t B_E   = (size_t)96 << 20;
constexpr size_t B_SM  = (size_t)112 << 20;
constexpr size_t B_X   = B_SM + ((size_t)2 << 20);

constexpr size_t PP_OFF = (size_t)4 << 20;   // shorts: PP in upper 8MB of B_E

// ---- float offsets within SM region (zeroed part first) ----
constexpr size_t KLSUMR = 0;
constexpr size_t KLSUMP = 256;
constexpr size_t OCCDENP= 2304;
constexpr size_t W50P   = 2816;
constexpr size_t EDENP  = 3328;
constexpr size_t H2TP   = 3336;
constexpr size_t H2DENP = 5384;
constexpr size_t OCCRAW = 5392;
constexpr size_t ZEND   = 18192;
constexpr size_t QC     = ZEND;
constexpr size_t KC     = QC + 12800;
constexpr size_t VC     = KC + 12800;
constexpr size_t VCA    = VC + 12800;
constexpr size_t VCB    = VCA + 12800;
constexpr size_t WFA    = VCB + 12800;
constexpr size_t WFB    = WFA + 65536;
constexpr size_t BFA    = WFB + 65536;
constexpr size_t BFB    = BFA + 256;
constexpr size_t OSCB   = BFB + 256;
constexpr size_t OCCB   = OSCB + 12800;
constexpr size_t ASC    = OCCB + 12800;
constexpr size_t ACC50  = ASC + 64;
constexpr size_t SMEND  = ACC50 + 64;

// ---- short offsets within X region (all fragment-major) ----
constexpr size_t XT_WQKV = 0;
constexpr size_t XT_WFAT = 196608;
constexpr size_t XT_WFBT = 262144;
constexpr size_t XT_KVT  = 327680;
constexpr size_t XT_QCH  = 393216;
constexpr size_t XT_KCH  = 409600;
constexpr size_t XT_VCAT = 425984;
constexpr size_t XT_VCBT = 442368;
constexpr size_t XT_END  = 458752;
constexpr size_t WS_NEEDED = B_X + XT_END * 2;

typedef short bf16x8 __attribute__((ext_vector_type(8)));
typedef float f32x4 __attribute__((ext_vector_type(4)));

__device__ __forceinline__ float rcpf_(float x){ return __builtin_amdgcn_rcpf(x); }
__device__ __forceinline__ float fsig_(float x){ return rcpf_(1.0f + __expf(-x)); }
__device__ __forceinline__ float ftanh_(float x){ return 1.0f - 2.0f * rcpf_(__expf(2.0f * x) + 1.0f); }

__device__ __forceinline__ float bf2f(unsigned short u){
  return __uint_as_float(((unsigned int)u) << 16);
}
__device__ __forceinline__ unsigned short f2bf(float f){
  union { __hip_bfloat16 h; unsigned short u; } c;
  c.h = __float2bfloat16(f);
  return c.u;
}
__device__ __forceinline__ f32x4 mfma16(bf16x8 a, bf16x8 b, f32x4 c){
  return __builtin_amdgcn_mfma_f32_16x16x32_bf16(a, b, c, 0, 0, 0);
}

__device__ __forceinline__ float waveAllSum(float v){
  #pragma unroll
  for (int m = 1; m < 64; m <<= 1) v += __shfl_xor(v, m, 64);
  return v;
}

__device__ __forceinline__ size_t fragIdx(int n, int k, int K8){
  const int tile = n >> 4, cn = n & 15;
  const int k0 = k >> 5, kqi = (k >> 3) & 3, e = k & 7;
  return (((size_t)tile * K8 + k0) * 64 + (kqi * 16 + cn)) * 8 + e;
}

__device__ __forceinline__ int kvOff(int c, int k){
  return c * 40 + (c >> 3) * 8 + k;
}

// ---------- prep0: Wqkv^T frags (0..47) + qc/kc/vc (48..97) + Wf-weight part (98..611) ----------
__global__ void __launch_bounds__(256) k_prep0(const float* __restrict__ x, const float* __restrict__ Wqkv,
                                               float* qc, float* kc, float* vc,
                                               unsigned short* qch, unsigned short* kch,
                                               unsigned short* __restrict__ WT,
                                               const float* __restrict__ Wa, const float* __restrict__ Wb,
                                               const float* __restrict__ ba, const float* __restrict__ bb,
                                               const float* __restrict__ Wf, const float* __restrict__ bf,
                                               float* Wfa, float* Wfb, float* bfa, float* bfb,
                                               unsigned short* WfaTh, unsigned short* WfbTh){
  const int b = blockIdx.x, t = threadIdx.x;
  if (b < 48) {
    __shared__ unsigned short Tt[64][72];
    const int bn = b % 12, bk = b / 12;
    const int n0 = bn * 64, k0g = bk * 64;
    #pragma unroll
    for (int i = 0; i < 16; i++) {
      const int k_l = (t >> 6) + i * 4;
      const int n_l = t & 63;
      Tt[n_l][k_l] = f2bf(Wqkv[(size_t)(k0g + k_l) * 768 + n0 + n_l]);
    }
    __syncthreads();
    #pragma unroll
    for (int i = 0; i < 2; i++) {
      const int fr = t * 2 + i;
      const int t_l = fr >> 7;
      const int k0_l = (fr >> 6) & 1;
      const int lane_f = fr & 63;
      const int n_l = t_l * 16 + (lane_f & 15);
      const int k_l = k0_l * 32 + (lane_f >> 4) * 8;
      const int tg = (n0 >> 4) + t_l;
      const int k0gl = (k0g >> 5) + k0_l;
      bf16x8 v = *(const bf16x8*)&Tt[n_l][k_l];
      *(bf16x8*)&WT[(((size_t)tg * 8 + k0gl) * 64 + lane_f) * 8] = v;
    }
    return;
  }
  __shared__ float xs[256];
  const int j = t;
  if (b < 98) {
    const int r = b - 48;
    xs[j] = x[r * DD + j];
    __syncthreads();
    float aq = 0.f, ak = 0.f, av = 0.f;
    for (int k = 0; k < DD; k++) {
      float xv = xs[k];
      aq += xv * Wqkv[k * 768 + j];
      ak += xv * Wqkv[k * 768 + 256 + j];
      av += xv * Wqkv[k * 768 + 512 + j];
    }
    qc[r * DD + j] = aq; kc[r * DD + j] = ak; vc[r * DD + j] = av;
    qch[fragIdx(r, j, 8)] = f2bf(aq);
    kch[fragIdx(r, j, 8)] = f2bf(ak);
    if (r == 0) {
      for (int c = 50; c < 64; c++) {
        qch[fragIdx(c, j, 8)] = 0;
        kch[fragIdx(c, j, 8)] = 0;
      }
    }
    return;
  }
  const int bb2 = b - 98;
  const float* src; const float* Wm;
  if (bb2 < 256)      { src = Wf + bb2 * DD;         Wm = Wa; }
  else if (bb2 < 512) { src = Wf + (bb2 - 256) * DD; Wm = Wb; }
  else if (bb2 == 512){ src = bf;                    Wm = Wa; }
  else                { src = bf;                    Wm = Wb; }
  xs[j] = src[j];
  __syncthreads();
  float a = 0.f;
  for (int k = 0; k < DD; k++) a += xs[k] * Wm[k * DD + j];
  if (bb2 < 256)      { Wfa[bb2 * DD + j] = a; WfaTh[fragIdx(j, bb2, 8)] = f2bf(a); }
  else if (bb2 < 512) { Wfb[(bb2 - 256) * DD + j] = a; WfbTh[fragIdx(j, bb2 - 256, 8)] = f2bf(a); }
  else if (bb2 == 512) bfa[j] = a + ba[j];
  else bfb[j] = a + bb[j];
}

// ---------- fused prep1 (0..49: Vca/Vcb) + oscg (50..99: osc row + gate) ----------
__global__ void __launch_bounds__(256) k_prep1g(const float* __restrict__ vc,
                                                const float* __restrict__ qc, const float* __restrict__ kc,
                                                const float* __restrict__ Wa, const float* __restrict__ Wb,
                                                const float* __restrict__ ba, const float* __restrict__ bb,
                                                const float* __restrict__ Wc, const float* __restrict__ bc,
                                                float* Vca, float* Vcb,
                                                unsigned short* VcaTh, unsigned short* VcbTh,
                                                float* __restrict__ osc, float* __restrict__ A){
  const int b = blockIdx.x, t = threadIdx.x;
  if (b < 50) {
    __shared__ float rs[256];
    const int r = b, j = t;
    rs[j] = vc[r * DD + j];
    __syncthreads();
    float a = 0.f, bv = 0.f;
    for (int k = 0; k < DD; k++) { float v = rs[k]; a += v * Wa[k * DD + j]; bv += v * Wb[k * DD + j]; }
    Vca[r * DD + j] = a; Vcb[r * DD + j] = bv;
    VcaTh[fragIdx(j, r, 2)] = f2bf(a);
    VcbTh[fragIdx(j, r, 2)] = f2bf(bv);
    if (r == 0) {
      for (int c = 50; c < 64; c++) {
        VcaTh[fragIdx(j, c, 2)] = 0;
        VcbTh[fragIdx(j, c, 2)] = 0;
      }
    }
    return;
  }
  const int i = b - 50;
  __shared__ float qs[256];
  __shared__ float P[64];
  __shared__ float red[4];
  qs[t] = qc[i * DD + t];
  __syncthreads();
  if (t < 64) {
    float s = -1e30f;
    if (t < 50) {
      float acc = 0.f;
      const float4* kr = (const float4*)&kc[t * DD];
      #pragma unroll 8
      for (int k = 0; k < 64; k++) {
        float4 kv = kr[k];
        float4 qv = *(const float4*)&qs[k * 4];
        acc += qv.x * kv.x + qv.y * kv.y + qv.z * kv.z + qv.w * kv.w;
      }
      s = acc * SCL;
    }
    float mx = s;
    #pragma unroll
    for (int m = 1; m < 64; m <<= 1) mx = fmaxf(mx, __shfl_xor(mx, m, 64));
    float e = (t < 50) ? __expf(s - mx) : 0.f;
    float den = waveAllSum(e);
    P[t] = e * rcpf_(den);
  }
  __syncthreads();
  float a = 0.f;
  for (int jj = 0; jj < 50; jj++) a += P[jj] * vc[jj * DD + t];
  osc[i * DD + t] = a;
  __syncthreads();
  qs[t] = a;
  __syncthreads();
  float u = 0.f, v = 0.f;
  for (int k = 0; k < DD; k++) { float tv = qs[k]; u += tv * Wa[k * DD + t]; v += tv * Wb[k * DD + t]; }
  float g = ftanh_(u + ba[t]) * fsig_(v + bb[t]) * Wc[t];
  g = waveAllSum(g);
  const int lane = t & 63, wv = t >> 6;
  if (lane == 0) red[wv] = g;
  __syncthreads();
  if (t == 0) A[i] = red[0] + red[1] + red[2] + red[3] + bc[0];
}

// ---------- fused path kernel: 32 rows/block, 38912 B arena ----------
__global__ void __launch_bounds__(256) k_path1(
    const float* __restrict__ x, const unsigned short* __restrict__ WTf,
    const float* __restrict__ sln,
    const unsigned short* __restrict__ kchf, const unsigned short* __restrict__ qchf,
    const unsigned short* __restrict__ VcaTf, const unsigned short* __restrict__ VcbTf,
    const float* __restrict__ ba, const float* __restrict__ bb,
    const float* __restrict__ Wc, const float* __restrict__ bc,
    unsigned short* __restrict__ vph, unsigned short* __restrict__ qlh, unsigned short* __restrict__ klh,
    unsigned short* __restrict__ Eh, float* __restrict__ w50p, float* __restrict__ edenp, float* __restrict__ occdenp){
  __shared__ __align__(16) char arena[38912];
  unsigned short (*Psh)[72]   = (unsigned short (*)[72])arena;
  float (*denp)[4]            = (float (*)[4])(arena + 4608);
  unsigned short (*qpsb)[264] = (unsigned short (*)[264])(arena + 5120);
  unsigned short (*kpsb)[264] = (unsigned short (*)[264])(arena + 22016);

  const int tid = threadIdx.x;
  const int i0 = blockIdx.x * 32;
  const int part = blockIdx.x & 7;
  const int lane = tid & 63;
  const int wvv = tid >> 6;
  const int cn = lane & 15;
  const int m0 = (lane >> 4) * 4;
  const int kq = (lane >> 4) * 8;

  for (int l = tid; l < 2048; l += 256) {
    const int r = l >> 6, c4 = (l & 63) * 4;
    const float4 xv = *(const float4*)&x[(size_t)(MM + i0 + r) * DD + c4];
    ushort4 o; o.x = f2bf(xv.x); o.y = f2bf(xv.y); o.z = f2bf(xv.z); o.w = f2bf(xv.w);
    *(ushort4*)&qpsb[r][c4] = o;
  }
  __syncthreads();

  bf16x8 af0[8], af1[8];
  #pragma unroll
  for (int k0 = 0; k0 < 8; k0++) {
    af0[k0] = *(const bf16x8*)&qpsb[cn][k0 * 32 + kq];
    af1[k0] = *(const bf16x8*)&qpsb[16 + cn][k0 * 32 + kq];
  }
  __syncthreads();

  bf16x8 b0[8], b1[8];
  {
    const unsigned short* Bt = WTf + ((size_t)wvv * 8 * 64 + lane) * 8;
    #pragma unroll
    for (int k0 = 0; k0 < 8; k0++) b0[k0] = *(const bf16x8*)&Bt[(size_t)k0 * 512];
  }
  #pragma unroll 1
  for (int tt = 0; tt < 12; tt++) {
    const int t = wvv + 4 * tt;
    if (tt + 1 < 12) {
      const unsigned short* Bt = WTf + (((size_t)(t + 4) * 8) * 64 + lane) * 8;
      #pragma unroll
      for (int k0 = 0; k0 < 8; k0++) b1[k0] = *(const bf16x8*)&Bt[(size_t)k0 * 512];
    }
    f32x4 acc0 = {0.f, 0.f, 0.f, 0.f};
    f32x4 acc1 = {0.f, 0.f, 0.f, 0.f};
    #pragma unroll
    for (int k0 = 0; k0 < 8; k0++) {
      acc0 = mfma16(af0[k0], b0[k0], acc0);
      acc1 = mfma16(af1[k0], b0[k0], acc1);
    }
    if (t < 16) {
      int c = t * 16 + cn;
      #pragma unroll
      for (int i = 0; i < 4; i++) {
        qpsb[m0 + i][c] = f2bf(acc0[i]);
        qpsb[16 + m0 + i][c] = f2bf(acc1[i]);
      }
    } else if (t < 32) {
      int c = (t - 16) * 16 + cn;
      #pragma unroll
      for (int i = 0; i < 4; i++) {
        kpsb[m0 + i][c] = f2bf(acc0[i]);
        kpsb[16 + m0 + i][c] = f2bf(acc1[i]);
      }
    } else {
      int c = (t - 32) * 16 + cn;
      #pragma unroll
      for (int i = 0; i < 4; i++) {
        vph[(size_t)(i0 + m0 + i) * DD + c] = f2bf(acc0[i]);
        vph[(size_t)(i0 + 16 + m0 + i) * DD + c] = f2bf(acc1[i]);
      }
    }
    #pragma unroll
    for (int k0 = 0; k0 < 8; k0++) b0[k0] = b1[k0];
  }
  __syncthreads();

  float ep0[4], ep1[4];
  {
    f32x4 accp0 = {0.f,0.f,0.f,0.f}, accp1 = {0.f,0.f,0.f,0.f};
    f32x4 accc0 = {0.f,0.f,0.f,0.f}, accc1 = {0.f,0.f,0.f,0.f};
    const unsigned short* Bk = kchf + ((size_t)wvv * 8 * 64 + lane) * 8;
    const unsigned short* Bq = qchf + ((size_t)wvv * 8 * 64 + lane) * 8;
    #pragma unroll
    for (int k0 = 0; k0 < 8; k0++) {
      bf16x8 aq0 = *(const bf16x8*)&qpsb[cn][k0 * 32 + kq];
      bf16x8 aq1 = *(const bf16x8*)&qpsb[16 + cn][k0 * 32 + kq];
      bf16x8 ak0 = *(const bf16x8*)&kpsb[cn][k0 * 32 + kq];
      bf16x8 ak1 = *(const bf16x8*)&kpsb[16 + cn][k0 * 32 + kq];
      bf16x8 bk = *(const bf16x8*)&Bk[(size_t)k0 * 512];
      bf16x8 bq = *(const bf16x8*)&Bq[(size_t)k0 * 512];
      accp0 = mfma16(aq0, bk, accp0);
      accp1 = mfma16(aq1, bk, accp1);
      accc0 = mfma16(ak0, bq, accc0);
      accc1 = mfma16(ak1, bq, accc1);
    }
    const int col = wvv * 16 + cn;
    const bool ok = (col < 50);
    #pragma unroll
    for (int i = 0; i < 4; i++) {
      ep0[i] = ok ? __expf(accp0[i] * SCL) : 0.f;
      ep1[i] = ok ? __expf(accp1[i] * SCL) : 0.f;
    }
    float osum = 0.f;
    #pragma unroll
    for (int i = 0; i < 4; i++) {
      unsigned short h0 = ok ? f2bf(__expf(accc0[i] * SCL)) : (unsigned short)0;
      unsigned short h1 = ok ? f2bf(__expf(accc1[i] * SCL)) : (unsigned short)0;
      Eh[(size_t)(i0 + m0 + i) * 64 + col] = h0;
      Eh[(size_t)(i0 + 16 + m0 + i) * 64 + col] = h1;
      if (ok) osum += bf2f(h0) + bf2f(h1);
    }
    osum += __shfl_xor(osum, 16, 64);
    osum += __shfl_xor(osum, 32, 64);
    if (lane < 16 && ok) atomicAdd(&occdenp[part * 64 + col], osum);
    float d0[4], d1[4];
    #pragma unroll
    for (int i = 0; i < 4; i++) { d0[i] = ep0[i]; d1[i] = ep1[i]; }
    #pragma unroll
    for (int m = 1; m < 16; m <<= 1) {
      #pragma unroll
      for (int i = 0; i < 4; i++) {
        d0[i] += __shfl_xor(d0[i], m, 64);
        d1[i] += __shfl_xor(d1[i], m, 64);
      }
    }
    if (cn == 0) {
      #pragma unroll
      for (int i = 0; i < 4; i++) {
        denp[m0 + i][wvv] = d0[i];
        denp[16 + m0 + i][wvv] = d1[i];
      }
    }
  }
  __syncthreads();

  {
    const int col = wvv * 16 + cn;
    #pragma unroll
    for (int i = 0; i < 4; i++) {
      float4 dp = *(const float4*)&denp[m0 + i][0];
      Psh[m0 + i][col] = f2bf(ep0[i] * rcpf_(dp.x + dp.y + dp.z + dp.w));
      float4 dq = *(const float4*)&denp[16 + m0 + i][0];
      Psh[16 + m0 + i][col] = f2bf(ep1[i] * rcpf_(dq.x + dq.y + dq.z + dq.w));
    }
  }

  float4 sl4 = ((const float4*)sln)[lane];
  float4 rsp;
  rsp.x = rcpf_(log1pf(expf(sl4.x))); rsp.y = rcpf_(log1pf(expf(sl4.y)));
  rsp.z = rcpf_(log1pf(expf(sl4.z))); rsp.w = rcpf_(log1pf(expf(sl4.w)));
  float4 ba4 = ((const float4*)ba)[lane];
  float4 bb4 = ((const float4*)bb)[lane];
  float4 wc4 = ((const float4*)Wc)[lane];
  float bcv = bc[0];
  for (int rr = 0; rr < 8; rr++) {
    const int r = wvv * 8 + rr;
    const int row = i0 + r;
    ushort4 qu = *(const ushort4*)&qpsb[r][lane * 4];
    ushort4 ku = *(const ushort4*)&kpsb[r][lane * 4];
    float4 q4 = {bf2f(qu.x), bf2f(qu.y), bf2f(qu.z), bf2f(qu.w)};
    float4 k4 = {bf2f(ku.x), bf2f(ku.y), bf2f(ku.z), bf2f(ku.w)};
    float4 lq, lk;
    lq.x = (fmaxf(q4.x, 0.f) + 1e-6f) * rsp.x; lq.y = (fmaxf(q4.y, 0.f) + 1e-6f) * rsp.y;
    lq.z = (fmaxf(q4.z, 0.f) + 1e-6f) * rsp.z; lq.w = (fmaxf(q4.w, 0.f) + 1e-6f) * rsp.w;
    lk.x = (fmaxf(k4.x, 0.f) + 1e-6f) * rsp.x; lk.y = (fmaxf(k4.y, 0.f) + 1e-6f) * rsp.y;
    lk.z = (fmaxf(k4.z, 0.f) + 1e-6f) * rsp.z; lk.w = (fmaxf(k4.w, 0.f) + 1e-6f) * rsp.w;
    float4 q3, k3;
    q3.x = lq.x*lq.x*lq.x; q3.y = lq.y*lq.y*lq.y; q3.z = lq.z*lq.z*lq.z; q3.w = lq.w*lq.w*lq.w;
    k3.x = lk.x*lk.x*lk.x; k3.y = lk.y*lk.y*lk.y; k3.z = lk.z*lk.z*lk.z; k3.w = lk.w*lk.w*lk.w;
    float n1q = lq.x*lq.x + lq.y*lq.y + lq.z*lq.z + lq.w*lq.w;
    float n3q = q3.x*q3.x + q3.y*q3.y + q3.z*q3.z + q3.w*q3.w;
    float n1k = lk.x*lk.x + lk.y*lk.y + lk.z*lk.z + lk.w*lk.w;
    float n3k = k3.x*k3.x + k3.y*k3.y + k3.z*k3.z + k3.w*k3.w;
    n1q = waveAllSum(n1q); n3q = waveAllSum(n3q);
    n1k = waveAllSum(n1k); n3k = waveAllSum(n3k);
    float fq = sqrtf(n1q * rcpf_(n3q));
    float fk = sqrtf(n1k * rcpf_(n3k));
    ushort4 qo, ko;
    qo.x = f2bf(q3.x * fq); qo.y = f2bf(q3.y * fq); qo.z = f2bf(q3.z * fq); qo.w = f2bf(q3.w * fq);
    ko.x = f2bf(k3.x * fk); ko.y = f2bf(k3.y * fk); ko.z = f2bf(k3.z * fk); ko.w = f2bf(k3.w * fk);
    *(ushort4*)&qlh[(size_t)row * DD + lane * 4] = qo;
    *(ushort4*)&klh[(size_t)row * DD + lane * 4] = ko;
  }
  __syncthreads();

  {
    bf16x8 ap0[2], ap1[2];
    #pragma unroll
    for (int k0 = 0; k0 < 2; k0++) {
      ap0[k0] = *(const bf16x8*)&Psh[cn][k0 * 32 + kq];
      ap1[k0] = *(const bf16x8*)&Psh[16 + cn][k0 * 32 + kq];
    }
    #pragma unroll 1
    for (int tt = 0; tt < 4; tt++) {
      const int nt = wvv * 4 + tt;
      const unsigned short* Bu = VcaTf + (((size_t)nt * 2) * 64 + lane) * 8;
      const unsigned short* Bv = VcbTf + (((size_t)nt * 2) * 64 + lane) * 8;
      f32x4 au0 = {0.f,0.f,0.f,0.f}, au1 = {0.f,0.f,0.f,0.f};
      f32x4 av0 = {0.f,0.f,0.f,0.f}, av1 = {0.f,0.f,0.f,0.f};
      #pragma unroll
      for (int k0 = 0; k0 < 2; k0++) {
        bf16x8 bu = *(const bf16x8*)&Bu[(size_t)k0 * 512];
        bf16x8 bv = *(const bf16x8*)&Bv[(size_t)k0 * 512];
        au0 = mfma16(ap0[k0], bu, au0);
        au1 = mfma16(ap1[k0], bu, au1);
        av0 = mfma16(ap0[k0], bv, av0);
        av1 = mfma16(ap1[k0], bv, av1);
      }
      #pragma unroll
      for (int i = 0; i < 4; i++) {
        qpsb[m0 + i][nt * 16 + cn] = f2bf(au0[i]);
        qpsb[16 + m0 + i][nt * 16 + cn] = f2bf(au1[i]);
        kpsb[m0 + i][nt * 16 + cn] = f2bf(av0[i]);
        kpsb[16 + m0 + i][nt * 16 + cn] = f2bf(av1[i]);
      }
    }
  }
  __syncthreads();

  #pragma unroll
  for (int rr = 0; rr < 8; rr++) {
    const int r = wvv * 8 + rr;
    ushort4 uu = *(const ushort4*)&qpsb[r][lane * 4];
    ushort4 vv = *(const ushort4*)&kpsb[r][lane * 4];
    float g = ftanh_(bf2f(uu.x) + ba4.x) * fsig_(bf2f(vv.x) + bb4.x) * wc4.x
            + ftanh_(bf2f(uu.y) + ba4.y) * fsig_(bf2f(vv.y) + bb4.y) * wc4.y
            + ftanh_(bf2f(uu.z) + ba4.z) * fsig_(bf2f(vv.z) + bb4.z) * wc4.z
            + ftanh_(bf2f(uu.w) + ba4.w) * fsig_(bf2f(vv.w) + bb4.w) * wc4.w;
    g = waveAllSum(g);
    if (lane == 0) *(float*)&Psh[r][64] = __expf(g + bcv);
  }
  __syncthreads();
  if (tid < 64) {
    float s = 0.f;
    #pragma unroll
    for (int r = 0; r < 32; r++) s += *(const float*)&Psh[r][64] * bf2f(Psh[r][tid]);
    atomicAdd(&w50p[part * 64 + tid], s);
  }
  if (tid == 0) {
    float es = 0.f;
    #pragma unroll
    for (int r = 0; r < 32; r++) es += *(const float*)&Psh[r][64];
    atomicAdd(&edenp[part], es);
  }
}

// ---------- kv + occnum merged, double-buffered LDS (1 barrier/step) ----------
__global__ void __launch_bounds__(256) k_kv(const unsigned short* __restrict__ klh,
                                            const unsigned short* __restrict__ Eh,
                                            const unsigned short* __restrict__ vph,
                                            unsigned short* __restrict__ PP,
                                            float* __restrict__ klsump,
                                            float* __restrict__ occraw){
  __shared__ __align__(16) unsigned short AT[2][2608];
  __shared__ __align__(16) unsigned short BvpT[2][10480];
  const int tid = threadIdx.x;
  const int lane = tid & 63;
  const int wvv = tid >> 6;
  const int cn = lane & 15;
  const int m0 = (lane >> 4) * 4;
  const int kq = (lane >> 4) * 8;
  const int cb = blockIdx.x;
  const int z  = blockIdx.y;
  const int jj = tid >> 3;
  const int c8 = (tid & 7) * 8;
  const bool isOcc = (cb == 4);

  f32x4 acc[4][4];
  f32x4 acc1[4];
  #pragma unroll
  for (int mt = 0; mt < 4; mt++) {
    acc1[mt] = (f32x4){0.f,0.f,0.f,0.f};
    #pragma unroll
    for (int tl = 0; tl < 4; tl++) acc[mt][tl] = (f32x4){0.f,0.f,0.f,0.f};
  }
  bf16x8 ones;
  #pragma unroll
  for (int i = 0; i < 8; i++) ones[i] = (short)0x3F80;

  const int jbase = z * 1024;
  // prologue: load + stage step 0 into buf 0
  {
    const int j0 = jbase;
    bf16x8 av;
    if (isOcc) av = *(const bf16x8*)&Eh[(size_t)(j0 + jj) * 64 + c8];
    else       av = *(const bf16x8*)&klh[(size_t)(j0 + jj) * 256 + cb * 64 + c8];
    #pragma unroll
    for (int i = 0; i < 8; i++) AT[0][kvOff(c8 + i, jj)] = (unsigned short)av[i];
    #pragma unroll
    for (int rep = 0; rep < 4; rep++) {
      bf16x8 bv = *(const bf16x8*)&vph[(size_t)(j0 + jj) * 256 + rep * 64 + c8];
      #pragma unroll
      for (int i = 0; i < 8; i++) BvpT[0][kvOff(rep * 64 + c8 + i, jj)] = (unsigned short)bv[i];
    }
  }
  __syncthreads();

  #pragma unroll 1
  for (int step = 0; step < 32; step++) {
    const int cur = step & 1;
    bf16x8 avn, bvn[4];
    if (step + 1 < 32) {
      const int j0 = jbase + (step + 1) * 32;
      if (isOcc) avn = *(const bf16x8*)&Eh[(size_t)(j0 + jj) * 64 + c8];
      else       avn = *(const bf16x8*)&klh[(size_t)(j0 + jj) * 256 + cb * 64 + c8];
      #pragma unroll
      for (int rep = 0; rep < 4; rep++)
        bvn[rep] = *(const bf16x8*)&vph[(size_t)(j0 + jj) * 256 + rep * 64 + c8];
    }
    // compute from buf[cur]
    bf16x8 afr[4], bfr[4];
    #pragma unroll
    for (int mt = 0; mt < 4; mt++)
      afr[mt] = *(const bf16x8*)&AT[cur][kvOff(cn + mt * 16, kq)];
    #pragma unroll
    for (int tl = 0; tl < 4; tl++)
      bfr[tl] = *(const bf16x8*)&BvpT[cur][kvOff(wvv * 64 + tl * 16 + cn, kq)];
    if (!isOcc) {
      #pragma unroll
      for (int mt = 0; mt < 4; mt++) acc1[mt] = mfma16(afr[mt], ones, acc1[mt]);
    }
    #pragma unroll
    for (int mt = 0; mt < 4; mt++)
      #pragma unroll
      for (int tl = 0; tl < 4; tl++) acc[mt][tl] = mfma16(afr[mt], bfr[tl], acc[mt][tl]);
    // stage step+1 into the other buffer
    if (step + 1 < 32) {
      const int nb = cur ^ 1;
      #pragma unroll
      for (int i = 0; i < 8; i++) AT[nb][kvOff(c8 + i, jj)] = (unsigned short)avn[i];
      #pragma unroll
      for (int rep = 0; rep < 4; rep++)
        #pragma unroll
        for (int i = 0; i < 8; i++) BvpT[nb][kvOff(rep * 64 + c8 + i, jj)] = (unsigned short)bvn[rep][i];
    }
    __syncthreads();
  }
  if (isOcc) {
    #pragma unroll
    for (int mt = 0; mt < 4; mt++)
      #pragma unroll
      for (int i = 0; i < 4; i++) {
        const int ri = mt * 16 + m0 + i;
        if (ri < 50) {
          #pragma unroll
          for (int tl = 0; tl < 4; tl++) {
            const int d = wvv * 64 + tl * 16 + cn;
            atomicAdd(&occraw[ri * DD + d], acc[mt][tl][i]);
          }
        }
      }
    return;
  }
  unsigned short* P = PP + ((size_t)(cb * 64 + z)) * 16384;
  #pragma unroll
  for (int mt = 0; mt < 4; mt++)
    #pragma unroll
    for (int tl = 0; tl < 4; tl++) {
      const int n = (wvv * 4 + tl) * 16 + cn;
      #pragma unroll
      for (int i = 0; i < 4; i++)
        P[(size_t)(mt * 16 + m0 + i) * 256 + n] = f2bf(acc[mt][tl][i]);
    }
  if (wvv == 0 && cn == 0) {
    #pragma unroll
    for (int mt = 0; mt < 4; mt++)
      #pragma unroll
      for (int i = 0; i < 4; i++)
        atomicAdd(&klsump[(z & 7) * 256 + cb * 64 + mt * 16 + m0 + i], acc1[mt][i]);
  }
}

// ---------- merged: kvred (0..31, ushort8) + occfin+gated (32..81) + klsum (82) ----------
__global__ void __launch_bounds__(256) k_fin2(const unsigned short* __restrict__ PP,
                                              unsigned short* __restrict__ kvTf,
                                              const float* __restrict__ occraw,
                                              const float* __restrict__ occdenp,
                                              float* __restrict__ occ,
                                              const float* __restrict__ klsump,
                                              float* __restrict__ klsum,
                                              const float* __restrict__ Wa, const float* __restrict__ Wb,
                                              const float* __restrict__ ba, const float* __restrict__ bb,
                                              const float* __restrict__ Wc, const float* __restrict__ bc,
                                              float* __restrict__ A){
  __shared__ float ts[256];
  __shared__ float red[4];
  const int b = blockIdx.x, tid = threadIdx.x;
  if (b < 32) {
    const int gm = b * 8 + (tid >> 5);
    const int cb = gm >> 6, m = gm & 63;
    const int d8 = (tid & 31) * 8;
    float s[8];
    #pragma unroll
    for (int e = 0; e < 8; e++) s[e] = 0.f;
    for (int z = 0; z < 64; z++) {
      bf16x8 v = *(const bf16x8*)&PP[((size_t)(cb * 64 + z)) * 16384 + (size_t)m * 256 + d8];
      #pragma unroll
      for (int e = 0; e < 8; e++) s[e] += bf2f((unsigned short)v[e]);
    }
    #pragma unroll
    for (int e = 0; e < 8; e++)
      kvTf[fragIdx(d8 + e, gm, 8)] = f2bf(s[e]);
  } else if (b < 82) {
    const int i = b - 32, j = tid;
    float den = 0.f;
    #pragma unroll
    for (int p = 0; p < 8; p++) den += occdenp[p * 64 + i];
    float t = occraw[i * DD + j] / den;
    occ[i * DD + j] = t;
    ts[j] = t;
    __syncthreads();
    float u = 0.f, v = 0.f;
    for (int k = 0; k < DD; k++) { float tv = ts[k]; u += tv * Wa[k * DD + j]; v += tv * Wb[k * DD + j]; }
    float g = ftanh_(u + ba[j]) * fsig_(v + bb[j]) * Wc[j];
    g = waveAllSum(g);
    const int lane = j & 63, wv = j >> 6;
    if (lane == 0) red[wv] = g;
    __syncthreads();
    if (j == 0) A[i] = red[0] + red[1] + red[2] + red[3] + bc[0];
  } else {
    const int d = tid;
    float s = 0.f;
    #pragma unroll
    for (int p = 0; p < 8; p++) s += klsump[p * 256 + d];
    klsum[d] = s;
  }
}

// ---------- fused tail: 32 rows/block (R12 form) ----------
__global__ void __launch_bounds__(256) k_tail(const unsigned short* __restrict__ qlh,
                                              const unsigned short* __restrict__ kvTf,
                                              const float* __restrict__ klsum,
                                              const unsigned short* __restrict__ vph,
                                              const float* __restrict__ dwcw, const float* __restrict__ dwcb,
                                              const unsigned short* __restrict__ WfaTf,
                                              const unsigned short* __restrict__ WfbTf,
                                              const float* __restrict__ bfa, const float* __restrict__ bfb,
                                              const float* __restrict__ Wc, const float* __restrict__ bc,
                                              float* __restrict__ h2tp, float* __restrict__ h2denp){
  __shared__ unsigned short Tsh[32][264];
  __shared__ unsigned short OSb[32][264];
  __shared__ unsigned short aVb[32][264];
  __shared__ float zf[32];
  __shared__ float ev[32];
  const int tid = threadIdx.x;
  const int i0 = blockIdx.x * 32;
  const int part = blockIdx.x & 7;
  const int lane = tid & 63;
  const int wvv = tid >> 6;
  const int cn = lane & 15;
  const int m0 = (lane >> 4) * 4;
  const int kq = (lane >> 4) * 8;
  for (int l = tid; l < 2048; l += 256) {
    int r = l >> 6, c4 = (l & 63) * 4;
    *(ushort4*)&Tsh[r][c4] = *(const ushort4*)&qlh[(size_t)(i0 + r) * DD + c4];
  }
  __syncthreads();
  {
    bf16x8 afq0[8], afq1[8];
    #pragma unroll
    for (int k0 = 0; k0 < 8; k0++) {
      afq0[k0] = *(const bf16x8*)&Tsh[cn][k0 * 32 + kq];
      afq1[k0] = *(const bf16x8*)&Tsh[16 + cn][k0 * 32 + kq];
    }
    #pragma unroll 1
    for (int tt = 0; tt < 4; tt++) {
      const int nt = wvv * 4 + tt;
      const unsigned short* Bt = kvTf + (((size_t)nt * 8) * 64 + lane) * 8;
      f32x4 acc0 = {0.f,0.f,0.f,0.f};
      f32x4 acc1 = {0.f,0.f,0.f,0.f};
      #pragma unroll
      for (int k0 = 0; k0 < 8; k0++) {
        bf16x8 b = *(const bf16x8*)&Bt[(size_t)k0 * 512];
        acc0 = mfma16(afq0[k0], b, acc0);
        acc1 = mfma16(afq1[k0], b, acc1);
      }
      #pragma unroll
      for (int i = 0; i < 4; i++) {
        OSb[m0 + i][nt * 16 + cn] = f2bf(acc0[i]);
        OSb[16 + m0 + i][nt * 16 + cn] = f2bf(acc1[i]);
      }
    }
  }
  {
    float4 ks4 = ((const float4*)klsum)[lane];
    #pragma unroll
    for (int rr = 0; rr < 8; rr++) {
      const int r = wvv * 8 + rr;
      ushort4 q4 = *(const ushort4*)&Tsh[r][lane * 4];
      float s = bf2f(q4.x)*ks4.x + bf2f(q4.y)*ks4.y + bf2f(q4.z)*ks4.z + bf2f(q4.w)*ks4.w;
      s = waveAllSum(s);
      if (lane == 0) zf[r] = rcpf_(s + 1e-6f);
    }
  }
  __syncthreads();
  const int j = tid;
  float w[25];
  #pragma unroll
  for (int t = 0; t < 25; t++) w[t] = dwcw[j * 25 + t];
  const float bias = dwcb[j];
  const int y = i0 >> 8, x0 = i0 & 255;
  float fm[32];
  #pragma unroll
  for (int r = 0; r < 32; r++) fm[r] = bias;
  #pragma unroll
  for (int dy = -2; dy <= 2; dy++) {
    const int yy = y + dy;
    if ((unsigned)yy > 255u) continue;
    float buf[36];
    #pragma unroll
    for (int i = 0; i < 36; i++) {
      const int xx = x0 - 2 + i;
      buf[i] = ((unsigned)xx <= 255u) ? bf2f(vph[(size_t)((yy << 8) + xx) * DD + j]) : 0.f;
    }
    const float* wr = &w[(dy + 2) * 5];
    #pragma unroll
    for (int r = 0; r < 32; r++)
      fm[r] += buf[r] * wr[0] + buf[r+1] * wr[1] + buf[r+2] * wr[2]
             + buf[r+3] * wr[3] + buf[r+4] * wr[4];
  }
  #pragma unroll
  for (int r = 0; r < 32; r++) {
    fm[r] = bf2f(OSb[r][j]) * zf[r] + fm[r];
    Tsh[r][j] = f2bf(fm[r]);
  }
  __syncthreads();
  {
    bf16x8 aft0[8], aft1[8];
    #pragma unroll
    for (int k0 = 0; k0 < 8; k0++) {
      aft0[k0] = *(const bf16x8*)&Tsh[cn][k0 * 32 + kq];
      aft1[k0] = *(const bf16x8*)&Tsh[16 + cn][k0 * 32 + kq];
    }
    #pragma unroll 1
    for (int jb = 0; jb < 8; jb++) {
      const int nt = wvv * 4 + (jb & 3);
      const unsigned short* Bt = ((jb < 4) ? WfaTf : WfbTf) + (((size_t)nt * 8) * 64 + lane) * 8;
      f32x4 acc0 = {0.f,0.f,0.f,0.f};
      f32x4 acc1 = {0.f,0.f,0.f,0.f};
      #pragma unroll
      for (int k0 = 0; k0 < 8; k0++) {
        bf16x8 b = *(const bf16x8*)&Bt[(size_t)k0 * 512];
        acc0 = mfma16(aft0[k0], b, acc0);
        acc1 = mfma16(aft1[k0], b, acc1);
      }
      unsigned short (*dst)[264] = (jb < 4) ? OSb : aVb;
      #pragma unroll
      for (int i = 0; i < 4; i++) {
        dst[m0 + i][nt * 16 + cn] = f2bf(acc0[i]);
        dst[16 + m0 + i][nt * 16 + cn] = f2bf(acc1[i]);
      }
    }
  }
  __syncthreads();
  {
    float4 bfa4 = ((const float4*)bfa)[lane];
    float4 bfb4 = ((const float4*)bfb)[lane];
    float4 wc4 = ((const float4*)Wc)[lane];
    const float bcv = bc[0];
    #pragma unroll
    for (int rr = 0; rr < 8; rr++) {
      const int r = wvv * 8 + rr;
      ushort4 uu = *(const ushort4*)&OSb[r][lane * 4];
      ushort4 vv = *(const ushort4*)&aVb[r][lane * 4];
      float g = ftanh_(bf2f(uu.x) + bfa4.x) * fsig_(bf2f(vv.x) + bfb4.x) * wc4.x
              + ftanh_(bf2f(uu.y) + bfa4.y) * fsig_(bf2f(vv.y) + bfb4.y) * wc4.y
              + ftanh_(bf2f(uu.z) + bfa4.z) * fsig_(bf2f(vv.z) + bfb4.z) * wc4.z
              + ftanh_(bf2f(uu.w) + bfa4.w) * fsig_(bf2f(vv.w) + bfb4.w) * wc4.w;
      g = waveAllSum(g);
      if (lane == 0) ev[r] = __expf(g + bcv);
    }
  }
  __syncthreads();
  float hp = 0.f;
  #pragma unroll
  for (int r = 0; r < 32; r++) hp += ev[r] * fm[r];
  atomicAdd(&h2tp[part * 256 + j], hp);
  if (tid == 0) {
    float es = 0.f;
    #pragma unroll
    for (int r = 0; r < 32; r++) es += ev[r];
    atomicAdd(&h2denp[part], es);
  }
}

// ---------- final tiny MLPs: 2 independent blocks (CROSS / SELF) ----------
__global__ void __launch_bounds__(256) k_final(
    const float* __restrict__ A_cc, const float* __restrict__ occ,
    const float* __restrict__ A_sc, const float* __restrict__ osc,
    const float* __restrict__ w50p, const float* __restrict__ edenp,
    const float* __restrict__ h2tp, const float* __restrict__ h2denp,
    const float* __restrict__ vc, const float* __restrict__ Wf, const float* __restrict__ bf,
    const float* __restrict__ W1, const float* __restrict__ b1,
    const float* __restrict__ W2, const float* __restrict__ b2,
    const float* __restrict__ W3a, const float* __restrict__ b3a,
    const float* __restrict__ W3b, const float* __restrict__ b3b,
    float* __restrict__ out){
  int j = threadIdx.x;
  __shared__ float pw[64];
  __shared__ float w50t[64];
  __shared__ float t1[256], t2[256], fz[512], z1[256];
  if (blockIdx.x == 0) {
    // ===== CROSS =====
    if (j < 64) {
      float s = 0.f;
      #pragma unroll
      for (int p = 0; p < 8; p++) s += w50p[p * 64 + j];
      w50t[j] = s;
    }
    float edentot = 0.f;
    #pragma unroll
    for (int p = 0; p < 8; p++) edentot += edenp[p];
    if (j < 64) pw[j] = (j < 50) ? expf(A_cc[j]) : 0.f;
    __syncthreads();
    float den = 0.f;
    for (int i = 0; i < 50; i++) den += pw[i];
    float raw = 0.f;
    for (int i = 0; i < 50; i++) raw += pw[i] * occ[i * DD + j];
    t1[j] = raw / den;
    float r2 = 0.f;
    for (int i = 0; i < 50; i++) r2 += w50t[i] * vc[i * DD + j];
    t2[j] = r2 / edentot;
    __syncthreads();
    float a1 = 0.f, a2 = 0.f;
    for (int k = 0; k < DD; k++) { a1 += t1[k] * W1[k * DD + j]; a2 += t2[k] * W2[k * DD + j]; }
    fz[j] = fmaxf(a1 + b1[j], 0.f);
    fz[256 + j] = fmaxf(a2 + b2[j], 0.f);
    __syncthreads();
    float z = 0.f;
    for (int k = 0; k < 512; k++) z += fz[k] * W3a[k * DD + j];
    z1[j] = fmaxf(z + b3a[j], 0.f);
    __syncthreads();
    float o = 0.f;
    for (int k = 0; k < DD; k++) o += z1[k] * W3b[k * DD + j];
    out[j] = fmaxf(o + b3b[j], 0.f);
  } else {
    // ===== SELF =====
    float h2dentot = 0.f;
    #pragma unroll
    for (int p = 0; p < 8; p++) h2dentot += h2denp[p];
    if (j < 64) pw[j] = (j < 50) ? expf(A_sc[j]) : 0.f;
    {
      float s = 0.f;
      #pragma unroll
      for (int p = 0; p < 8; p++) s += h2tp[p * 256 + j];
      t2[j] = s / h2dentot;
    }
    __syncthreads();
    float den = 0.f;
    for (int i = 0; i < 50; i++) den += pw[i];
    float raw = 0.f;
    for (int i = 0; i < 50; i++) raw += pw[i] * osc[i * DD + j];
    t1[j] = raw / den;
    float hs = 0.f;
    for (int k = 0; k < DD; k++) hs += t2[k] * Wf[k * DD + j];
    __syncthreads();
    t2[j] = hs + bf[j];
    __syncthreads();
    float a1 = 0.f, a2 = 0.f;
    for (int k = 0; k < DD; k++) { a1 += t1[k] * W1[k * DD + j]; a2 += t2[k] * W2[k * DD + j]; }
    fz[j] = fmaxf(a1 + b1[j], 0.f);
    fz[256 + j] = fmaxf(a2 + b2[j], 0.f);
    __syncthreads();
    float z = 0.f;
    for (int k = 0; k < 512; k++) z += fz[k] * W3a[k * DD + j];
    z1[j] = fmaxf(z + b3a[j], 0.f);
    __syncthreads();
    float o = 0.f;
    for (int k = 0; k < DD; k++) o += z1[k] * W3b[k * DD + j];
    out[256 + j] = fmaxf(o + b3b[j], 0.f);
  }
}

extern "C" void kernel_launch(void* const* d_in, const int* in_sizes, int n_in,
                              void* d_out, int out_size, void* d_ws, size_t ws_size,
                              hipStream_t stream) {
  if (ws_size < WS_NEEDED) return;
  const float* x   = (const float*)d_in[0];
  const float* Wqkv= (const float*)d_in[1];
  const float* sln = (const float*)d_in[2];
  const float* dwcw= (const float*)d_in[3];
  const float* dwcb= (const float*)d_in[4];
  const float* Wa  = (const float*)d_in[5];
  const float* ba  = (const float*)d_in[6];
  const float* Wb  = (const float*)d_in[7];
  const float* bb  = (const float*)d_in[8];
  const float* Wc  = (const float*)d_in[9];
  const float* bc  = (const float*)d_in[10];
  const float* W1  = (const float*)d_in[11];
  const float* b1  = (const float*)d_in[12];
  const float* W2  = (const float*)d_in[13];
  const float* b2  = (const float*)d_in[14];
  const float* W3a = (const float*)d_in[15];
  const float* b3a = (const float*)d_in[16];
  const float* W3b = (const float*)d_in[17];
  const float* b3b = (const float*)d_in[18];
  const float* Wf  = (const float*)d_in[19];
  const float* bf  = (const float*)d_in[20];

  char* wsb = (char*)d_ws;
  unsigned short* VPH = (unsigned short*)(wsb + B_VPH);
  unsigned short* QLH = (unsigned short*)(wsb + B_QLH);
  unsigned short* KLH = (unsigned short*)(wsb + B_KLH);
  unsigned short* EHB = (unsigned short*)(wsb + B_E);
  unsigned short* PPB = EHB + PP_OFF;
  float* SM = (float*)(wsb + B_SM);
  unsigned short* XT = (unsigned short*)(wsb + B_X);
  float* outp = (float*)d_out;

  hipMemsetAsync((void*)SM, 0, ZEND * sizeof(float), stream);

  k_prep0<<<612, 256, 0, stream>>>(x, Wqkv, SM + QC, SM + KC, SM + VC,
                                   XT + XT_QCH, XT + XT_KCH, XT + XT_WQKV,
                                   Wa, Wb, ba, bb, Wf, bf,
                                   SM + WFA, SM + WFB, SM + BFA, SM + BFB,
                                   XT + XT_WFAT, XT + XT_WFBT);
  k_prep1g<<<100, 256, 0, stream>>>(SM + VC, SM + QC, SM + KC,
                                    Wa, Wb, ba, bb, Wc, bc,
                                    SM + VCA, SM + VCB, XT + XT_VCAT, XT + XT_VCBT,
                                    SM + OSCB, SM + ASC);

  k_path1<<<2048, 256, 0, stream>>>(x, XT + XT_WQKV, sln, XT + XT_KCH, XT + XT_QCH,
                                    XT + XT_VCAT, XT + XT_VCBT, ba, bb, Wc, bc,
                                    VPH, QLH, KLH, EHB, SM + W50P, SM + EDENP, SM + OCCDENP);
  k_kv<<<dim3(5, 64), 256, 0, stream>>>(KLH, EHB, VPH, PPB, SM + KLSUMP, SM + OCCRAW);
  k_fin2<<<83, 256, 0, stream>>>(PPB, XT + XT_KVT,
                                 SM + OCCRAW, SM + OCCDENP, SM + OCCB,
                                 SM + KLSUMP, SM + KLSUMR,
                                 Wa, Wb, ba, bb, Wc, bc, SM + ACC50);

  k_tail<<<2048, 256, 0, stream>>>(QLH, XT + XT_KVT, SM + KLSUMR, VPH, dwcw, dwcb,
                                   XT + XT_WFAT, XT + XT_WFBT, SM + BFA, SM + BFB,
                                   Wc, bc, SM + H2TP, SM + H2DENP);

  k_final<<<2, 256, 0, stream>>>(SM + ACC50, SM + OCCB, SM + ASC, SM + OSCB,
                                 SM + W50P, SM + EDENP, SM + H2TP, SM + H2DENP,
                                 SM + VC, Wf, bf, W1, b1, W2, b2, W3a, b3a, W3b, b3b, outp);
}